// Round 1
// baseline (1686.325 us; speedup 1.0000x reference)
//
#include <hip/hip_runtime.h>

// GNN: N=50000 nodes, E=800000 edges, H=64, L=2.
// fp32 everywhere (no fp32 MFMA on CDNA4 -> vector ALU register-tiled GEMMs).
// Key trick: edge-MLP layer-1 over concat([e, x_src, x_dst]) is split:
//   t = e@W1e + Ps[src] + Pd[dst] + b1,  Ps = x_h@W1s, Pd = x_h@W1d  (per-node!)

#define NN 50000
#define EE 800000
#define HH 64
#define LDA 68   // padded leading dim: keeps 16B alignment, <=2-way LDS bank aliasing (free)

// ---------------- helpers ----------------

__device__ __forceinline__ void copy_w64(float* dst, const float* __restrict__ src, int t) {
    // copy 64x64 fp32 weight (4096 floats) global -> LDS, 256 threads
    float4* d4 = (float4*)dst;
    const float4* s4 = (const float4*)src;
#pragma unroll
    for (int i = 0; i < 4; ++i) d4[t + 256 * i] = s4[t + 256 * i];
}

template <int KLEN>
__device__ __forceinline__ void gemm_tile(const float* A, const float* W,
                                          int r0, int c0, float (&acc)[4][4]) {
    // acc[4][4] += sum_k A^T[k][r0..r0+3] * W[k][c0..c0+3]
#pragma unroll 16
    for (int k = 0; k < KLEN; ++k) {
        const float4 a4 = *(const float4*)(A + k * LDA + r0);
        const float4 b4 = *(const float4*)(W + k * HH + c0);
        const float a[4] = {a4.x, a4.y, a4.z, a4.w};
        const float b[4] = {b4.x, b4.y, b4.z, b4.w};
#pragma unroll
        for (int i = 0; i < 4; ++i)
#pragma unroll
            for (int j = 0; j < 4; ++j)
                acc[i][j] = fmaf(a[i], b[j], acc[i][j]);
    }
}

__device__ __forceinline__ void init_acc_bias(float (&acc)[4][4], const float* __restrict__ b, int c0) {
    const float4 b4 = *(const float4*)(b + c0);
    const float bv[4] = {b4.x, b4.y, b4.z, b4.w};
#pragma unroll
    for (int i = 0; i < 4; ++i)
#pragma unroll
        for (int j = 0; j < 4; ++j) acc[i][j] = bv[j];
}

__device__ __forceinline__ void init_acc_zero(float (&acc)[4][4]) {
#pragma unroll
    for (int i = 0; i < 4; ++i)
#pragma unroll
        for (int j = 0; j < 4; ++j) acc[i][j] = 0.f;
}

__device__ __forceinline__ void relu_acc(float (&acc)[4][4]) {
#pragma unroll
    for (int i = 0; i < 4; ++i)
#pragma unroll
        for (int j = 0; j < 4; ++j) acc[i][j] = fmaxf(acc[i][j], 0.f);
}

__device__ __forceinline__ void store_T(float* lds, int r0, int c0, const float (&acc)[4][4]) {
    // lds[k=c][r] = acc[r][c]  (transposed store, b128, 16B aligned via LDA=68)
#pragma unroll
    for (int j = 0; j < 4; ++j) {
        float4 v = make_float4(acc[0][j], acc[1][j], acc[2][j], acc[3][j]);
        *(float4*)(lds + (c0 + j) * LDA + r0) = v;
    }
}

__device__ __forceinline__ void stage_T64(float* lds, const float* __restrict__ g,
                                          long rowBase, int t, int nValid) {
    // stage 64 rows x 64 cols from global into LDS transposed: lds[col][row]
    const int row = t >> 2, q = t & 3;
    const bool valid = row < nValid;
#pragma unroll
    for (int i = 0; i < 4; ++i) {
        const int col = i * 16 + q * 4;
        float4 v = make_float4(0.f, 0.f, 0.f, 0.f);
        if (valid) v = *(const float4*)(g + (size_t)(rowBase + row) * HH + col);
        lds[(col + 0) * LDA + row] = v.x;
        lds[(col + 1) * LDA + row] = v.y;
        lds[(col + 2) * LDA + row] = v.z;
        lds[(col + 3) * LDA + row] = v.w;
    }
}

// ---------------- K1: node encoder + layer-0 edge projections ----------------
// x_h = MLP(x);  Ps = x_h @ W1s(l0);  Pd = x_h @ W1d(l0)

__global__ __launch_bounds__(256, 3) void k_encode_nodes(
    const float* __restrict__ x,
    const float* __restrict__ wn1, const float* __restrict__ bn1,
    const float* __restrict__ wn2, const float* __restrict__ bn2,
    const float* __restrict__ w1s, const float* __restrict__ w1d,
    float* __restrict__ x_h, float* __restrict__ Ps, float* __restrict__ Pd)
{
    __shared__ float ldsA[HH * LDA];
    __shared__ float ldsT[HH * LDA];
    __shared__ float Wbuf[HH * HH];
    __shared__ float Wn1s[8 * HH];

    const int t = threadIdx.x;
    const int tc = t & 15, tr = t >> 4;
    const int r0 = tr * 4, c0 = tc * 4;
    const int nodeBase = blockIdx.x * 64;

    if (t < 64) {
        const int row = nodeBase + t;
        float4 a0 = make_float4(0.f, 0.f, 0.f, 0.f), a1 = a0;
        if (row < NN) {
            a0 = *(const float4*)(x + (size_t)row * 8);
            a1 = *(const float4*)(x + (size_t)row * 8 + 4);
        }
        ldsA[0 * LDA + t] = a0.x; ldsA[1 * LDA + t] = a0.y;
        ldsA[2 * LDA + t] = a0.z; ldsA[3 * LDA + t] = a0.w;
        ldsA[4 * LDA + t] = a1.x; ldsA[5 * LDA + t] = a1.y;
        ldsA[6 * LDA + t] = a1.z; ldsA[7 * LDA + t] = a1.w;
    }
    Wn1s[t] = wn1[t];
    Wn1s[t + 256] = wn1[t + 256];
    copy_w64(Wbuf, wn2, t);
    __syncthreads();

    float acc[4][4];
    // h1 = relu(x @ Wn1 + bn1)
    init_acc_bias(acc, bn1, c0);
    gemm_tile<8>(ldsA, Wn1s, r0, c0, acc);
    relu_acc(acc);
    store_T(ldsT, r0, c0, acc);
    __syncthreads();

    // x_h = h1 @ Wn2 + bn2
    init_acc_bias(acc, bn2, c0);
    gemm_tile<64>(ldsT, Wbuf, r0, c0, acc);
#pragma unroll
    for (int i = 0; i < 4; ++i) {
        if (nodeBase + r0 + i < NN) {
            float4 v = make_float4(acc[i][0], acc[i][1], acc[i][2], acc[i][3]);
            *(float4*)(x_h + (size_t)(nodeBase + r0 + i) * HH + c0) = v;
        }
    }
    store_T(ldsA, r0, c0, acc);   // x_h^T for projection GEMMs (ldsA readers done)
    __syncthreads();
    copy_w64(Wbuf, w1s, t);
    __syncthreads();

    // Ps = x_h @ W1s  (no bias)
    init_acc_zero(acc);
    gemm_tile<64>(ldsA, Wbuf, r0, c0, acc);
#pragma unroll
    for (int i = 0; i < 4; ++i) {
        if (nodeBase + r0 + i < NN) {
            float4 v = make_float4(acc[i][0], acc[i][1], acc[i][2], acc[i][3]);
            *(float4*)(Ps + (size_t)(nodeBase + r0 + i) * HH + c0) = v;
        }
    }
    __syncthreads();
    copy_w64(Wbuf, w1d, t);
    __syncthreads();

    // Pd = x_h @ W1d
    init_acc_zero(acc);
    gemm_tile<64>(ldsA, Wbuf, r0, c0, acc);
#pragma unroll
    for (int i = 0; i < 4; ++i) {
        if (nodeBase + r0 + i < NN) {
            float4 v = make_float4(acc[i][0], acc[i][1], acc[i][2], acc[i][3]);
            *(float4*)(Pd + (size_t)(nodeBase + r0 + i) * HH + c0) = v;
        }
    }
}

// ---------------- K2: edge encoder + layer-0 edge MLP + scatter ----------------
// e0 = MLP_enc(edge_attr); e1 = e0 + (relu(e0@W1e + Ps[src]+Pd[dst]+b1) @ W2 + b2)
// write e1 to e_h; atomicAdd e1 into agg[dst]

__global__ __launch_bounds__(256, 3) void k_edge_l0(
    const float* __restrict__ eattr, const int* __restrict__ eidx,
    const float* __restrict__ Ps, const float* __restrict__ Pd,
    const float* __restrict__ we1, const float* __restrict__ be1,
    const float* __restrict__ we2, const float* __restrict__ be2,
    const float* __restrict__ w1e, const float* __restrict__ pb1,
    const float* __restrict__ w2e, const float* __restrict__ pb2,
    float* __restrict__ e_h, float* __restrict__ agg)
{
    __shared__ float ldsA[HH * LDA];
    __shared__ float ldsT[HH * LDA];
    __shared__ float Wbuf[HH * HH];
    __shared__ float We1s[4 * HH];

    const int t = threadIdx.x;
    const int tc = t & 15, tr = t >> 4;
    const int r0 = tr * 4, c0 = tc * 4;
    const long eBase = (long)blockIdx.x * 64;

    if (t < 64) {
        float4 a = *(const float4*)(eattr + (size_t)(eBase + t) * 4);
        ldsA[0 * LDA + t] = a.x; ldsA[1 * LDA + t] = a.y;
        ldsA[2 * LDA + t] = a.z; ldsA[3 * LDA + t] = a.w;
    }
    We1s[t] = we1[t];
    copy_w64(Wbuf, we2, t);
    __syncthreads();

    float acc[4][4];
    // h0 = relu(edge_attr @ We1 + be1)
    init_acc_bias(acc, be1, c0);
    gemm_tile<4>(ldsA, We1s, r0, c0, acc);
    relu_acc(acc);
    store_T(ldsT, r0, c0, acc);
    __syncthreads();

    // e0 = h0 @ We2 + be2   -> e0^T into ldsA
    init_acc_bias(acc, be2, c0);
    gemm_tile<64>(ldsT, Wbuf, r0, c0, acc);
    store_T(ldsA, r0, c0, acc);
    __syncthreads();
    copy_w64(Wbuf, w1e, t);
    __syncthreads();

    // t1 = relu(e0 @ W1e + Ps[src] + Pd[dst] + b1)
    int srcs[4], dsts[4];
#pragma unroll
    for (int i = 0; i < 4; ++i) {
        srcs[i] = eidx[eBase + r0 + i];
        dsts[i] = eidx[EE + eBase + r0 + i];
    }
    {
        const float4 b4 = *(const float4*)(pb1 + c0);
        const float bv[4] = {b4.x, b4.y, b4.z, b4.w};
#pragma unroll
        for (int i = 0; i < 4; ++i) {
            const float4 ps = *(const float4*)(Ps + (size_t)srcs[i] * HH + c0);
            const float4 pd = *(const float4*)(Pd + (size_t)dsts[i] * HH + c0);
            acc[i][0] = ps.x + pd.x + bv[0];
            acc[i][1] = ps.y + pd.y + bv[1];
            acc[i][2] = ps.z + pd.z + bv[2];
            acc[i][3] = ps.w + pd.w + bv[3];
        }
    }
    gemm_tile<64>(ldsA, Wbuf, r0, c0, acc);
    relu_acc(acc);
    store_T(ldsT, r0, c0, acc);   // ldsT readers finished before W1e reload barrier
    __syncthreads();
    copy_w64(Wbuf, w2e, t);
    __syncthreads();

    // e1 = e0 + (t1 @ W2 + b2); write + scatter-add
    {
        const float4 b4 = *(const float4*)(pb2 + c0);
        const float bv[4] = {b4.x, b4.y, b4.z, b4.w};
#pragma unroll
        for (int j = 0; j < 4; ++j) {
            const float4 e0c = *(const float4*)(ldsA + (c0 + j) * LDA + r0);
            acc[0][j] = e0c.x + bv[j];
            acc[1][j] = e0c.y + bv[j];
            acc[2][j] = e0c.z + bv[j];
            acc[3][j] = e0c.w + bv[j];
        }
    }
    gemm_tile<64>(ldsT, Wbuf, r0, c0, acc);
#pragma unroll
    for (int i = 0; i < 4; ++i) {
        float4 v = make_float4(acc[i][0], acc[i][1], acc[i][2], acc[i][3]);
        *(float4*)(e_h + (size_t)(eBase + r0 + i) * HH + c0) = v;
        float* ap = agg + (size_t)dsts[i] * HH + c0;
        atomicAdd(ap + 0, acc[i][0]);
        atomicAdd(ap + 1, acc[i][1]);
        atomicAdd(ap + 2, acc[i][2]);
        atomicAdd(ap + 3, acc[i][3]);
    }
}

// ---------------- K4: layer-1 edge MLP + scatter (no e_h writeback) ----------------

__global__ __launch_bounds__(256, 3) void k_edge_l1(
    const float* __restrict__ e_h, const int* __restrict__ eidx,
    const float* __restrict__ Ps, const float* __restrict__ Pd,
    const float* __restrict__ w1e, const float* __restrict__ pb1,
    const float* __restrict__ w2e, const float* __restrict__ pb2,
    float* __restrict__ agg)
{
    __shared__ float ldsA[HH * LDA];
    __shared__ float ldsT[HH * LDA];
    __shared__ float Wbuf[HH * HH];

    const int t = threadIdx.x;
    const int tc = t & 15, tr = t >> 4;
    const int r0 = tr * 4, c0 = tc * 4;
    const long eBase = (long)blockIdx.x * 64;

    stage_T64(ldsA, e_h, eBase, t, 64);
    copy_w64(Wbuf, w1e, t);
    __syncthreads();

    float acc[4][4];
    int srcs[4], dsts[4];
#pragma unroll
    for (int i = 0; i < 4; ++i) {
        srcs[i] = eidx[eBase + r0 + i];
        dsts[i] = eidx[EE + eBase + r0 + i];
    }
    {
        const float4 b4 = *(const float4*)(pb1 + c0);
        const float bv[4] = {b4.x, b4.y, b4.z, b4.w};
#pragma unroll
        for (int i = 0; i < 4; ++i) {
            const float4 ps = *(const float4*)(Ps + (size_t)srcs[i] * HH + c0);
            const float4 pd = *(const float4*)(Pd + (size_t)dsts[i] * HH + c0);
            acc[i][0] = ps.x + pd.x + bv[0];
            acc[i][1] = ps.y + pd.y + bv[1];
            acc[i][2] = ps.z + pd.z + bv[2];
            acc[i][3] = ps.w + pd.w + bv[3];
        }
    }
    gemm_tile<64>(ldsA, Wbuf, r0, c0, acc);
    relu_acc(acc);
    store_T(ldsT, r0, c0, acc);
    __syncthreads();
    copy_w64(Wbuf, w2e, t);
    __syncthreads();

    {
        const float4 b4 = *(const float4*)(pb2 + c0);
        const float bv[4] = {b4.x, b4.y, b4.z, b4.w};
#pragma unroll
        for (int j = 0; j < 4; ++j) {
            const float4 e0c = *(const float4*)(ldsA + (c0 + j) * LDA + r0);
            acc[0][j] = e0c.x + bv[j];
            acc[1][j] = e0c.y + bv[j];
            acc[2][j] = e0c.z + bv[j];
            acc[3][j] = e0c.w + bv[j];
        }
    }
    gemm_tile<64>(ldsT, Wbuf, r0, c0, acc);
#pragma unroll
    for (int i = 0; i < 4; ++i) {
        float* ap = agg + (size_t)dsts[i] * HH + c0;
        atomicAdd(ap + 0, acc[i][0]);
        atomicAdd(ap + 1, acc[i][1]);
        atomicAdd(ap + 2, acc[i][2]);
        atomicAdd(ap + 3, acc[i][3]);
    }
}

// ---------------- K3: node update (layer 0) + layer-1 projections ----------------
// x_h += relu(x_h@W1nx + agg@W1na + b1) @ W2 + b2;  Ps1 = x_h@W1s(l1); Pd1 = x_h@W1d(l1)

__global__ __launch_bounds__(256, 3) void k_node_l0(
    const float* __restrict__ agg,
    const float* __restrict__ w1nx, const float* __restrict__ w1na,
    const float* __restrict__ nb1,
    const float* __restrict__ w2n, const float* __restrict__ nb2,
    const float* __restrict__ w1s_next, const float* __restrict__ w1d_next,
    float* __restrict__ x_h, float* __restrict__ Ps, float* __restrict__ Pd)
{
    __shared__ float ldsA[HH * LDA];
    __shared__ float ldsB[HH * LDA];
    __shared__ float Wbuf[HH * HH];

    const int t = threadIdx.x;
    const int tc = t & 15, tr = t >> 4;
    const int r0 = tr * 4, c0 = tc * 4;
    const int nodeBase = blockIdx.x * 64;
    const int nValid = min(64, NN - nodeBase);

    stage_T64(ldsA, x_h, nodeBase, t, nValid);
    stage_T64(ldsB, agg, nodeBase, t, nValid);
    copy_w64(Wbuf, w1nx, t);
    __syncthreads();

    float acc[4][4];
    init_acc_bias(acc, nb1, c0);
    gemm_tile<64>(ldsA, Wbuf, r0, c0, acc);
    __syncthreads();
    copy_w64(Wbuf, w1na, t);
    __syncthreads();
    gemm_tile<64>(ldsB, Wbuf, r0, c0, acc);
    relu_acc(acc);
    __syncthreads();                  // everyone done reading ldsB & Wbuf
    store_T(ldsB, r0, c0, acc);       // T^T
    copy_w64(Wbuf, w2n, t);
    __syncthreads();

    // x_h1 = x_h + T @ W2 + b2
    {
        const float4 b4 = *(const float4*)(nb2 + c0);
        const float bv[4] = {b4.x, b4.y, b4.z, b4.w};
#pragma unroll
        for (int j = 0; j < 4; ++j) {
            const float4 xc = *(const float4*)(ldsA + (c0 + j) * LDA + r0);
            acc[0][j] = xc.x + bv[j];
            acc[1][j] = xc.y + bv[j];
            acc[2][j] = xc.z + bv[j];
            acc[3][j] = xc.w + bv[j];
        }
    }
    gemm_tile<64>(ldsB, Wbuf, r0, c0, acc);
#pragma unroll
    for (int i = 0; i < 4; ++i) {
        if (r0 + i < nValid) {
            float4 v = make_float4(acc[i][0], acc[i][1], acc[i][2], acc[i][3]);
            *(float4*)(x_h + (size_t)(nodeBase + r0 + i) * HH + c0) = v;
        }
    }
    __syncthreads();
    store_T(ldsA, r0, c0, acc);       // x_h1^T
    copy_w64(Wbuf, w1s_next, t);
    __syncthreads();

    init_acc_zero(acc);
    gemm_tile<64>(ldsA, Wbuf, r0, c0, acc);
#pragma unroll
    for (int i = 0; i < 4; ++i) {
        if (r0 + i < nValid) {
            float4 v = make_float4(acc[i][0], acc[i][1], acc[i][2], acc[i][3]);
            *(float4*)(Ps + (size_t)(nodeBase + r0 + i) * HH + c0) = v;
        }
    }
    __syncthreads();
    copy_w64(Wbuf, w1d_next, t);
    __syncthreads();

    init_acc_zero(acc);
    gemm_tile<64>(ldsA, Wbuf, r0, c0, acc);
#pragma unroll
    for (int i = 0; i < 4; ++i) {
        if (r0 + i < nValid) {
            float4 v = make_float4(acc[i][0], acc[i][1], acc[i][2], acc[i][3]);
            *(float4*)(Pd + (size_t)(nodeBase + r0 + i) * HH + c0) = v;
        }
    }
}

// ---------------- K5: node update (layer 1) + decoder ----------------

__global__ __launch_bounds__(256, 3) void k_node_l1_dec(
    const float* __restrict__ agg,
    const float* __restrict__ w1nx, const float* __restrict__ w1na,
    const float* __restrict__ nb1,
    const float* __restrict__ w2n, const float* __restrict__ nb2,
    const float* __restrict__ dw1, const float* __restrict__ db1,
    const float* __restrict__ dw2, const float* __restrict__ db2,
    const float* __restrict__ x_h, float* __restrict__ out)
{
    __shared__ float ldsA[HH * LDA];
    __shared__ float ldsB[HH * LDA];
    __shared__ float Wbuf[HH * HH];

    const int t = threadIdx.x;
    const int tc = t & 15, tr = t >> 4;
    const int r0 = tr * 4, c0 = tc * 4;
    const int nodeBase = blockIdx.x * 64;
    const int nValid = min(64, NN - nodeBase);

    stage_T64(ldsA, x_h, nodeBase, t, nValid);
    stage_T64(ldsB, agg, nodeBase, t, nValid);
    copy_w64(Wbuf, w1nx, t);
    __syncthreads();

    float acc[4][4];
    init_acc_bias(acc, nb1, c0);
    gemm_tile<64>(ldsA, Wbuf, r0, c0, acc);
    __syncthreads();
    copy_w64(Wbuf, w1na, t);
    __syncthreads();
    gemm_tile<64>(ldsB, Wbuf, r0, c0, acc);
    relu_acc(acc);
    __syncthreads();
    store_T(ldsB, r0, c0, acc);
    copy_w64(Wbuf, w2n, t);
    __syncthreads();

    // x_h2 = x_h + T @ W2 + b2   (registers only; not written back)
    {
        const float4 b4 = *(const float4*)(nb2 + c0);
        const float bv[4] = {b4.x, b4.y, b4.z, b4.w};
#pragma unroll
        for (int j = 0; j < 4; ++j) {
            const float4 xc = *(const float4*)(ldsA + (c0 + j) * LDA + r0);
            acc[0][j] = xc.x + bv[j];
            acc[1][j] = xc.y + bv[j];
            acc[2][j] = xc.z + bv[j];
            acc[3][j] = xc.w + bv[j];
        }
    }
    gemm_tile<64>(ldsB, Wbuf, r0, c0, acc);
    __syncthreads();
    store_T(ldsA, r0, c0, acc);       // x_h2^T
    copy_w64(Wbuf, dw1, t);
    __syncthreads();

    // d1 = relu(x_h2 @ dec_w1 + db1)
    init_acc_bias(acc, db1, c0);
    gemm_tile<64>(ldsA, Wbuf, r0, c0, acc);
    relu_acc(acc);
    __syncthreads();                  // dec_w1 readers done; ldsB free
    store_T(ldsB, r0, c0, acc);
    if (t < 192) {                    // dec_w2: [64,6] = 384 floats into Wbuf
        Wbuf[t] = dw2[t];
        Wbuf[t + 192] = dw2[t + 192];
    }
    __syncthreads();

    // out = d1 @ dec_w2 + db2   (64 rows x 6 cols; threads 0..63, one row each)
    if (t < 64) {
        float o[6];
#pragma unroll
        for (int c = 0; c < 6; ++c) o[c] = db2[c];
#pragma unroll 8
        for (int k = 0; k < 64; ++k) {
            const float a = ldsB[k * LDA + t];
#pragma unroll
            for (int c = 0; c < 6; ++c) o[c] = fmaf(a, Wbuf[k * 6 + c], o[c]);
        }
        if (t < nValid) {
            float* op = out + (size_t)(nodeBase + t) * 6;
#pragma unroll
            for (int c = 0; c < 6; ++c) op[c] = o[c];
        }
    }
}

// ---------------- launcher ----------------

extern "C" void kernel_launch(void* const* d_in, const int* in_sizes, int n_in,
                              void* d_out, int out_size, void* d_ws, size_t ws_size,
                              hipStream_t stream) {
    const float* x        = (const float*)d_in[0];
    const float* eattr    = (const float*)d_in[1];
    const int*   eidx     = (const int*)d_in[2];
    const float* enc_n_w1 = (const float*)d_in[3];
    const float* enc_n_b1 = (const float*)d_in[4];
    const float* enc_n_w2 = (const float*)d_in[5];
    const float* enc_n_b2 = (const float*)d_in[6];
    const float* enc_e_w1 = (const float*)d_in[7];
    const float* enc_e_b1 = (const float*)d_in[8];
    const float* enc_e_w2 = (const float*)d_in[9];
    const float* enc_e_b2 = (const float*)d_in[10];
    const float* pe_w1    = (const float*)d_in[11];  // [2,192,64]
    const float* pe_b1    = (const float*)d_in[12];  // [2,64]
    const float* pe_w2    = (const float*)d_in[13];  // [2,64,64]
    const float* pe_b2    = (const float*)d_in[14];  // [2,64]
    const float* pn_w1    = (const float*)d_in[15];  // [2,128,64]
    const float* pn_b1    = (const float*)d_in[16];
    const float* pn_w2    = (const float*)d_in[17];  // [2,64,64]
    const float* pn_b2    = (const float*)d_in[18];
    const float* dw1      = (const float*)d_in[19];
    const float* db1      = (const float*)d_in[20];
    const float* dw2      = (const float*)d_in[21];
    const float* db2      = (const float*)d_in[22];
    float* out = (float*)d_out;

    // workspace layout (floats): x_h | Ps | Pd | agg | e_h   = 64M floats = 256 MB
    float* ws  = (float*)d_ws;
    float* x_h = ws;                         // N*64
    float* Ps  = ws + (size_t)NN * HH;       // N*64
    float* Pd  = ws + (size_t)NN * HH * 2;   // N*64
    float* agg = ws + (size_t)NN * HH * 3;   // N*64 (reused both layers)
    float* e_h = ws + (size_t)NN * HH * 4;   // E*64

    const int nodeBlocks = (NN + 63) / 64;   // 782
    const int edgeBlocks = EE / 64;          // 12500

    hipMemsetAsync(agg, 0, (size_t)NN * HH * sizeof(float), stream);

    k_encode_nodes<<<nodeBlocks, 256, 0, stream>>>(
        x, enc_n_w1, enc_n_b1, enc_n_w2, enc_n_b2,
        pe_w1 + 64 * 64,        // W1s (rows 64..127 of layer-0 W1)
        pe_w1 + 128 * 64,       // W1d (rows 128..191)
        x_h, Ps, Pd);

    k_edge_l0<<<edgeBlocks, 256, 0, stream>>>(
        eattr, eidx, Ps, Pd,
        enc_e_w1, enc_e_b1, enc_e_w2, enc_e_b2,
        pe_w1 /* W1e rows 0..63 */, pe_b1, pe_w2, pe_b2,
        e_h, agg);

    k_node_l0<<<nodeBlocks, 256, 0, stream>>>(
        agg,
        pn_w1 /* x-block */, pn_w1 + 64 * 64 /* agg-block */, pn_b1,
        pn_w2, pn_b2,
        pe_w1 + 192 * 64 + 64 * 64,   // layer-1 W1s
        pe_w1 + 192 * 64 + 128 * 64,  // layer-1 W1d
        x_h, Ps, Pd);

    hipMemsetAsync(agg, 0, (size_t)NN * HH * sizeof(float), stream);

    k_edge_l1<<<edgeBlocks, 256, 0, stream>>>(
        e_h, eidx, Ps, Pd,
        pe_w1 + 192 * 64, pe_b1 + 64, pe_w2 + 64 * 64, pe_b2 + 64,
        agg);

    k_node_l1_dec<<<nodeBlocks, 256, 0, stream>>>(
        agg,
        pn_w1 + 128 * 64, pn_w1 + 128 * 64 + 64 * 64, pn_b1 + 64,
        pn_w2 + 64 * 64, pn_b2 + 64,
        dw1, db1, dw2, db2,
        x_h, out);
}

// Round 2
// 1603.339 us; speedup vs baseline: 1.0518x; 1.0518x over previous
//
#include <hip/hip_runtime.h>

// GNN: N=50000 nodes, E=800000 edges, H=64, L=2.
// R2: edge-path GEMMs on MFMA (mfma_f32_16x16x32_bf16) with split-bf16 (bf16x3)
// for fp32-class accuracy. Transposed orientation D[f][e] = W^T * act^T:
//   A-operand = weights (VGPR-resident, pre-split by k_conv_w into d_out scratch)
//   B-operand = activations, LDS planes [edge][k] bf16 hi/lo, pad 72
//   C/D: col = lane&15 = edge, row = quad*4+reg = feature  -> float4 gathers,
//   b64 plane writes, direct atomic indexing.
// Node kernels remain fp32 VALU register-tiled (round-3 target).

#define NN 50000
#define EE 800000
#define HH 64
#define LDA 68   // fp32 node-kernel LDS pad
#define LDK 72   // bf16 plane leading dim (144 B row: 16B-aligned, 2-way banks = free)
#define EPB 128  // edges per block in MFMA edge kernels

typedef short short8 __attribute__((ext_vector_type(8)));
typedef short short4v __attribute__((ext_vector_type(4)));
typedef float f32x4 __attribute__((ext_vector_type(4)));

#define MFMA __builtin_amdgcn_mfma_f32_16x16x32_bf16

// ---------------- bf16 split helpers ----------------

__device__ __forceinline__ void split2(float x, unsigned short& h, unsigned short& l) {
    union { float f; unsigned u; } a, hf, b;
    a.f = x;
    const unsigned hb = (a.u + 0x7FFFu + ((a.u >> 16) & 1u)) >> 16;  // RNE to bf16
    hf.u = hb << 16;
    b.f = x - hf.f;
    const unsigned lb = (b.u + 0x7FFFu + ((b.u >> 16) & 1u)) >> 16;
    h = (unsigned short)hb; l = (unsigned short)lb;
}

__device__ __forceinline__ float bf2f(unsigned short s) {
    union { unsigned u; float f; } a; a.u = ((unsigned)s) << 16; return a.f;
}

// A-frags for one 64x64 weight: [ft][c][p] (f-tile, k-chunk, hi/lo)
__device__ __forceinline__ void load_wf64(const unsigned short* __restrict__ wm,
                                          int fh, int l15, int quad,
                                          short8 (&w)[2][2][2]) {
#pragma unroll
    for (int ft = 0; ft < 2; ++ft)
#pragma unroll
        for (int c = 0; c < 2; ++c) {
            const int el = (fh * 32 + ft * 16 + l15) * 64 + c * 32 + quad * 8;
            w[ft][c][0] = *(const short8*)(wm + el);
            w[ft][c][1] = *(const short8*)(wm + 4096 + el);
        }
}

// D += Ah*Bh + Al*Bh + Ah*Bl over K=64 (2 chunks)
__device__ __forceinline__ f32x4 chain6(const short8 (&wf)[2][2],
                                        short8 bh0, short8 bh1,
                                        short8 bl0, short8 bl1, f32x4 a) {
    a = MFMA(wf[0][0], bh0, a, 0, 0, 0);
    a = MFMA(wf[1][0], bh1, a, 0, 0, 0);
    a = MFMA(wf[0][1], bh0, a, 0, 0, 0);
    a = MFMA(wf[1][1], bh1, a, 0, 0, 0);
    a = MFMA(wf[0][0], bl0, a, 0, 0, 0);
    a = MFMA(wf[1][0], bl1, a, 0, 0, 0);
    return a;
}

// ---------------- setup: split weights into bf16 hi/lo, transposed [f][k] ----------------
// wt layout (ushort): m in 0..4: 64x64 mats at m*8192 (hi 4096 | lo 4096), layout [f][k].
// m=5: We1 padded to [f][32] at 5*8192 (hi 2048 | lo 2048).

__global__ void k_conv_w(const float* __restrict__ w0, const float* __restrict__ w1,
                         const float* __restrict__ w2, const float* __restrict__ w3,
                         const float* __restrict__ w4, const float* __restrict__ we1,
                         unsigned short* __restrict__ wt)
{
    const int i = blockIdx.x * 256 + threadIdx.x;
    if (i < 5 * 4096) {
        const int m = i >> 12, r = i & 4095, f = r & 63;
        const int k = r >> 6;
        const float* W = m == 0 ? w0 : m == 1 ? w1 : m == 2 ? w2 : m == 3 ? w3 : w4;
        unsigned short h, l; split2(W[r], h, l);    // W[k*64+f]
        wt[m * 8192 + f * 64 + k] = h;
        wt[m * 8192 + 4096 + f * 64 + k] = l;
    } else if (i < 5 * 4096 + 2048) {
        const int r = i - 5 * 4096, f = r >> 5, k = r & 31;
        const float v = (k < 4) ? we1[k * 64 + f] : 0.f;
        unsigned short h, l; split2(v, h, l);
        wt[5 * 8192 + f * 32 + k] = h;
        wt[5 * 8192 + 2048 + f * 32 + k] = l;
    }
}

// ---------------- K2: edge encoder + layer-0 edge MLP + scatter (MFMA) ----------------

__global__ __launch_bounds__(256, 2) void k_edge_l0(
    const float* __restrict__ eattr, const int* __restrict__ eidx,
    const float* __restrict__ Ps, const float* __restrict__ Pd,
    const float* __restrict__ be1, const float* __restrict__ be2,
    const unsigned short* __restrict__ wt,
    const float* __restrict__ pb1, const float* __restrict__ pb2,
    unsigned short* __restrict__ ehi, unsigned short* __restrict__ elo,
    float* __restrict__ agg)
{
    __shared__ unsigned short pHhi[EPB * LDK], pHlo[EPB * LDK];
    __shared__ unsigned short pEhi[EPB * LDK], pElo[EPB * LDK];

    const int t = threadIdx.x;
    const int lane = t & 63, wv = t >> 6;
    const int quad = lane >> 4, l15 = lane & 15;
    const int fh = wv >> 1, eg = wv & 1;       // f-half, edge-group
    const long eBase = (long)blockIdx.x * EPB;

    int srcs[4], dsts[4];
#pragma unroll
    for (int et = 0; et < 4; ++et) {
        const long e = eBase + eg * 64 + et * 16 + l15;
        srcs[et] = eidx[e];
        dsts[et] = eidx[EE + e];
    }

    f32x4 acc[2][4];
    const f32x4 zz = {0.f, 0.f, 0.f, 0.f};

    // ===== h0 = relu(eattr @ We1 + be1)  (K padded to 32; quads 1..3 carry zeros)
    {
        short8 wa[2][2];
#pragma unroll
        for (int ft = 0; ft < 2; ++ft) {
            const int el = (fh * 32 + ft * 16 + l15) * 32 + quad * 8;
            wa[ft][0] = *(const short8*)(wt + 5 * 8192 + el);
            wa[ft][1] = *(const short8*)(wt + 5 * 8192 + 2048 + el);
        }
#pragma unroll
        for (int ft = 0; ft < 2; ++ft) {
            const int f0 = fh * 32 + ft * 16 + quad * 4;
            const float4 b4 = *(const float4*)(be1 + f0);
#pragma unroll
            for (int et = 0; et < 4; ++et) {
                acc[ft][et][0] = b4.x; acc[ft][et][1] = b4.y;
                acc[ft][et][2] = b4.z; acc[ft][et][3] = b4.w;
            }
        }
        const short8 z8 = {0, 0, 0, 0, 0, 0, 0, 0};
#pragma unroll
        for (int et = 0; et < 4; ++et) {
            const long e = eBase + eg * 64 + et * 16 + l15;
            const float4 ea = *(const float4*)(eattr + e * 4);
            union { unsigned short u[8]; short8 v; } bh, bl;
            split2(ea.x, bh.u[0], bl.u[0]); split2(ea.y, bh.u[1], bl.u[1]);
            split2(ea.z, bh.u[2], bl.u[2]); split2(ea.w, bh.u[3], bl.u[3]);
#pragma unroll
            for (int j = 4; j < 8; ++j) { bh.u[j] = 0; bl.u[j] = 0; }
            const short8 Bh = (quad == 0) ? bh.v : z8;
            const short8 Bl = (quad == 0) ? bl.v : z8;
#pragma unroll
            for (int ft = 0; ft < 2; ++ft) {
                f32x4 a = acc[ft][et];
                a = MFMA(wa[ft][0], Bh, a, 0, 0, 0);
                a = MFMA(wa[ft][1], Bh, a, 0, 0, 0);
                a = MFMA(wa[ft][0], Bl, a, 0, 0, 0);
                acc[ft][et] = a;
            }
        }
#pragma unroll
        for (int ft = 0; ft < 2; ++ft) {
            const int f0 = fh * 32 + ft * 16 + quad * 4;
#pragma unroll
            for (int et = 0; et < 4; ++et) {
                const int e = eg * 64 + et * 16 + l15;
                union { unsigned short u[4]; short4v v; } h, l;
#pragma unroll
                for (int r = 0; r < 4; ++r)
                    split2(fmaxf(acc[ft][et][r], 0.f), h.u[r], l.u[r]);
                *(short4v*)(pHhi + e * LDK + f0) = h.v;
                *(short4v*)(pHlo + e * LDK + f0) = l.v;
            }
        }
    }
    __syncthreads();

    // ===== e0 = h0 @ We2 + be2  -> pE planes
    {
        short8 w[2][2][2];
        load_wf64(wt + 0 * 8192, fh, l15, quad, w);
#pragma unroll
        for (int ft = 0; ft < 2; ++ft) {
            const int f0 = fh * 32 + ft * 16 + quad * 4;
            const float4 b4 = *(const float4*)(be2 + f0);
#pragma unroll
            for (int et = 0; et < 4; ++et) {
                acc[ft][et][0] = b4.x; acc[ft][et][1] = b4.y;
                acc[ft][et][2] = b4.z; acc[ft][et][3] = b4.w;
            }
        }
#pragma unroll
        for (int et = 0; et < 4; ++et) {
            const int e = eg * 64 + et * 16 + l15;
            const short8 bh0 = *(const short8*)(pHhi + e * LDK + quad * 8);
            const short8 bh1 = *(const short8*)(pHhi + e * LDK + 32 + quad * 8);
            const short8 bl0 = *(const short8*)(pHlo + e * LDK + quad * 8);
            const short8 bl1 = *(const short8*)(pHlo + e * LDK + 32 + quad * 8);
#pragma unroll
            for (int ft = 0; ft < 2; ++ft)
                acc[ft][et] = chain6(w[ft], bh0, bh1, bl0, bl1, acc[ft][et]);
        }
#pragma unroll
        for (int ft = 0; ft < 2; ++ft) {
            const int f0 = fh * 32 + ft * 16 + quad * 4;
#pragma unroll
            for (int et = 0; et < 4; ++et) {
                const int e = eg * 64 + et * 16 + l15;
                union { unsigned short u[4]; short4v v; } h, l;
#pragma unroll
                for (int r = 0; r < 4; ++r) split2(acc[ft][et][r], h.u[r], l.u[r]);
                *(short4v*)(pEhi + e * LDK + f0) = h.v;
                *(short4v*)(pElo + e * LDK + f0) = l.v;
            }
        }
    }
    __syncthreads();

    // ===== t1 = relu(e0 @ W1e + Ps[src] + Pd[dst] + pb1)  -> pH planes
    {
        float4 gp[2][4], gq[2][4];
#pragma unroll
        for (int ft = 0; ft < 2; ++ft) {
            const int f0 = fh * 32 + ft * 16 + quad * 4;
#pragma unroll
            for (int et = 0; et < 4; ++et) {
                gp[ft][et] = *(const float4*)(Ps + (size_t)srcs[et] * HH + f0);
                gq[ft][et] = *(const float4*)(Pd + (size_t)dsts[et] * HH + f0);
            }
        }
        short8 w[2][2][2];
        load_wf64(wt + 1 * 8192, fh, l15, quad, w);
#pragma unroll
        for (int ft = 0; ft < 2; ++ft)
#pragma unroll
            for (int et = 0; et < 4; ++et) acc[ft][et] = zz;
#pragma unroll
        for (int et = 0; et < 4; ++et) {
            const int e = eg * 64 + et * 16 + l15;
            const short8 bh0 = *(const short8*)(pEhi + e * LDK + quad * 8);
            const short8 bh1 = *(const short8*)(pEhi + e * LDK + 32 + quad * 8);
            const short8 bl0 = *(const short8*)(pElo + e * LDK + quad * 8);
            const short8 bl1 = *(const short8*)(pElo + e * LDK + 32 + quad * 8);
#pragma unroll
            for (int ft = 0; ft < 2; ++ft)
                acc[ft][et] = chain6(w[ft], bh0, bh1, bl0, bl1, acc[ft][et]);
        }
    }
    __syncthreads();      // pE reads done everywhere before next phase's pH overwrite races? (pH written below)
    {
        // add gathers + bias, relu, split -> pH  (pH readers all hit the barrier above)
#pragma unroll
        for (int ft = 0; ft < 2; ++ft) {
            const int f0 = fh * 32 + ft * 16 + quad * 4;
            const float4 b4 = *(const float4*)(pb1 + f0);
            // note: gp/gq were consumed into acc pre-barrier? -> no: do it here
        }
    }
    // (gather add happens below, kept in one block for register liveness)
    {
        // re-load biases (cheap, L2) and finish t1
#pragma unroll
        for (int ft = 0; ft < 2; ++ft) {
            const int f0 = fh * 32 + ft * 16 + quad * 4;
            const float4 b4 = *(const float4*)(pb1 + f0);
#pragma unroll
            for (int et = 0; et < 4; ++et) {
                const int e = eg * 64 + et * 16 + l15;
                const float4 ps = *(const float4*)(Ps + (size_t)srcs[et] * HH + f0);
                const float4 pd = *(const float4*)(Pd + (size_t)dsts[et] * HH + f0);
                union { unsigned short u[4]; short4v v; } h, l;
                float v0 = fmaxf(acc[ft][et][0] + ps.x + pd.x + b4.x, 0.f);
                float v1 = fmaxf(acc[ft][et][1] + ps.y + pd.y + b4.y, 0.f);
                float v2 = fmaxf(acc[ft][et][2] + ps.z + pd.z + b4.z, 0.f);
                float v3 = fmaxf(acc[ft][et][3] + ps.w + pd.w + b4.w, 0.f);
                split2(v0, h.u[0], l.u[0]); split2(v1, h.u[1], l.u[1]);
                split2(v2, h.u[2], l.u[2]); split2(v3, h.u[3], l.u[3]);
                *(short4v*)(pHhi + e * LDK + f0) = h.v;
                *(short4v*)(pHlo + e * LDK + f0) = l.v;
            }
        }
    }
    __syncthreads();

    // ===== e1 = e0 + t1 @ W2e + pb2 ; atomic scatter; planes -> global
    {
        short8 w[2][2][2];
        load_wf64(wt + 2 * 8192, fh, l15, quad, w);
#pragma unroll
        for (int ft = 0; ft < 2; ++ft)
#pragma unroll
            for (int et = 0; et < 4; ++et) acc[ft][et] = zz;
#pragma unroll
        for (int et = 0; et < 4; ++et) {
            const int e = eg * 64 + et * 16 + l15;
            const short8 bh0 = *(const short8*)(pHhi + e * LDK + quad * 8);
            const short8 bh1 = *(const short8*)(pHhi + e * LDK + 32 + quad * 8);
            const short8 bl0 = *(const short8*)(pHlo + e * LDK + quad * 8);
            const short8 bl1 = *(const short8*)(pHlo + e * LDK + 32 + quad * 8);
#pragma unroll
            for (int ft = 0; ft < 2; ++ft)
                acc[ft][et] = chain6(w[ft], bh0, bh1, bl0, bl1, acc[ft][et]);
        }
#pragma unroll
        for (int ft = 0; ft < 2; ++ft) {
            const int f0 = fh * 32 + ft * 16 + quad * 4;
            const float4 b4 = *(const float4*)(pb2 + f0);
#pragma unroll
            for (int et = 0; et < 4; ++et) {
                const int e = eg * 64 + et * 16 + l15;
                const short4v hv = *(const short4v*)(pEhi + e * LDK + f0);
                const short4v lv = *(const short4v*)(pElo + e * LDK + f0);
                float v[4];
                v[0] = acc[ft][et][0] + bf2f((unsigned short)hv[0]) + bf2f((unsigned short)lv[0]) + b4.x;
                v[1] = acc[ft][et][1] + bf2f((unsigned short)hv[1]) + bf2f((unsigned short)lv[1]) + b4.y;
                v[2] = acc[ft][et][2] + bf2f((unsigned short)hv[2]) + bf2f((unsigned short)lv[2]) + b4.z;
                v[3] = acc[ft][et][3] + bf2f((unsigned short)hv[3]) + bf2f((unsigned short)lv[3]) + b4.w;
                float* ap = agg + (size_t)dsts[et] * HH + f0;
                atomicAdd(ap + 0, v[0]); atomicAdd(ap + 1, v[1]);
                atomicAdd(ap + 2, v[2]); atomicAdd(ap + 3, v[3]);
                union { unsigned short u[4]; short4v v4; } h, l;
#pragma unroll
                for (int r = 0; r < 4; ++r) split2(v[r], h.u[r], l.u[r]);
                *(short4v*)(pEhi + e * LDK + f0) = h.v4;
                *(short4v*)(pElo + e * LDK + f0) = l.v4;
            }
        }
    }
    __syncthreads();
    {
        const int row = t >> 1, ch = t & 1;
#pragma unroll
        for (int i = 0; i < 4; ++i) {
            const int lo_off = row * LDK + ch * 32 + i * 8;
            const long go = (eBase + row) * HH + ch * 32 + i * 8;
            *(uint4*)(ehi + go) = *(const uint4*)(pEhi + lo_off);
            *(uint4*)(elo + go) = *(const uint4*)(pElo + lo_off);
        }
    }
}

// ---------------- K4: layer-1 edge MLP + scatter (MFMA, no e_h writeback) ----------------

__global__ __launch_bounds__(256, 2) void k_edge_l1(
    const int* __restrict__ eidx,
    const float* __restrict__ Ps, const float* __restrict__ Pd,
    const unsigned short* __restrict__ wt,
    const float* __restrict__ pb1, const float* __restrict__ pb2,
    const unsigned short* __restrict__ ehi, const unsigned short* __restrict__ elo,
    float* __restrict__ agg)
{
    __shared__ unsigned short pEhi[EPB * LDK], pElo[EPB * LDK];
    __shared__ unsigned short pHhi[EPB * LDK], pHlo[EPB * LDK];

    const int t = threadIdx.x;
    const int lane = t & 63, wv = t >> 6;
    const int quad = lane >> 4, l15 = lane & 15;
    const int fh = wv >> 1, eg = wv & 1;
    const long eBase = (long)blockIdx.x * EPB;

    {
        const int row = t >> 1, ch = t & 1;
#pragma unroll
        for (int i = 0; i < 4; ++i) {
            const int lo_off = row * LDK + ch * 32 + i * 8;
            const long go = (eBase + row) * HH + ch * 32 + i * 8;
            *(uint4*)(pEhi + lo_off) = *(const uint4*)(ehi + go);
            *(uint4*)(pElo + lo_off) = *(const uint4*)(elo + go);
        }
    }

    int srcs[4], dsts[4];
#pragma unroll
    for (int et = 0; et < 4; ++et) {
        const long e = eBase + eg * 64 + et * 16 + l15;
        srcs[et] = eidx[e];
        dsts[et] = eidx[EE + e];
    }
    __syncthreads();

    f32x4 acc[2][4];
    const f32x4 zz = {0.f, 0.f, 0.f, 0.f};

    // ===== t1 = relu(e1 @ W1e + Ps[src] + Pd[dst] + pb1) -> pH
    {
        short8 w[2][2][2];
        load_wf64(wt + 3 * 8192, fh, l15, quad, w);
#pragma unroll
        for (int ft = 0; ft < 2; ++ft)
#pragma unroll
            for (int et = 0; et < 4; ++et) acc[ft][et] = zz;
#pragma unroll
        for (int et = 0; et < 4; ++et) {
            const int e = eg * 64 + et * 16 + l15;
            const short8 bh0 = *(const short8*)(pEhi + e * LDK + quad * 8);
            const short8 bh1 = *(const short8*)(pEhi + e * LDK + 32 + quad * 8);
            const short8 bl0 = *(const short8*)(pElo + e * LDK + quad * 8);
            const short8 bl1 = *(const short8*)(pElo + e * LDK + 32 + quad * 8);
#pragma unroll
            for (int ft = 0; ft < 2; ++ft)
                acc[ft][et] = chain6(w[ft], bh0, bh1, bl0, bl1, acc[ft][et]);
        }
#pragma unroll
        for (int ft = 0; ft < 2; ++ft) {
            const int f0 = fh * 32 + ft * 16 + quad * 4;
            const float4 b4 = *(const float4*)(pb1 + f0);
#pragma unroll
            for (int et = 0; et < 4; ++et) {
                const int e = eg * 64 + et * 16 + l15;
                const float4 ps = *(const float4*)(Ps + (size_t)srcs[et] * HH + f0);
                const float4 pd = *(const float4*)(Pd + (size_t)dsts[et] * HH + f0);
                union { unsigned short u[4]; short4v v; } h, l;
                float v0 = fmaxf(acc[ft][et][0] + ps.x + pd.x + b4.x, 0.f);
                float v1 = fmaxf(acc[ft][et][1] + ps.y + pd.y + b4.y, 0.f);
                float v2 = fmaxf(acc[ft][et][2] + ps.z + pd.z + b4.z, 0.f);
                float v3 = fmaxf(acc[ft][et][3] + ps.w + pd.w + b4.w, 0.f);
                split2(v0, h.u[0], l.u[0]); split2(v1, h.u[1], l.u[1]);
                split2(v2, h.u[2], l.u[2]); split2(v3, h.u[3], l.u[3]);
                *(short4v*)(pHhi + e * LDK + f0) = h.v;
                *(short4v*)(pHlo + e * LDK + f0) = l.v;
            }
        }
    }
    __syncthreads();

    // ===== e2 = e1 + t1 @ W2e + pb2 ; atomic scatter only
    {
        short8 w[2][2][2];
        load_wf64(wt + 4 * 8192, fh, l15, quad, w);
#pragma unroll
        for (int ft = 0; ft < 2; ++ft)
#pragma unroll
            for (int et = 0; et < 4; ++et) acc[ft][et] = zz;
#pragma unroll
        for (int et = 0; et < 4; ++et) {
            const int e = eg * 64 + et * 16 + l15;
            const short8 bh0 = *(const short8*)(pHhi + e * LDK + quad * 8);
            const short8 bh1 = *(const short8*)(pHhi + e * LDK + 32 + quad * 8);
            const short8 bl0 = *(const short8*)(pHlo + e * LDK + quad * 8);
            const short8 bl1 = *(const short8*)(pHlo + e * LDK + 32 + quad * 8);
#pragma unroll
            for (int ft = 0; ft < 2; ++ft)
                acc[ft][et] = chain6(w[ft], bh0, bh1, bl0, bl1, acc[ft][et]);
        }
#pragma unroll
        for (int ft = 0; ft < 2; ++ft) {
            const int f0 = fh * 32 + ft * 16 + quad * 4;
            const float4 b4 = *(const float4*)(pb2 + f0);
#pragma unroll
            for (int et = 0; et < 4; ++et) {
                const int e = eg * 64 + et * 16 + l15;
                const short4v hv = *(const short4v*)(pEhi + e * LDK + f0);
                const short4v lv = *(const short4v*)(pElo + e * LDK + f0);
                float* ap = agg + (size_t)dsts[et] * HH + f0;
                atomicAdd(ap + 0, acc[ft][et][0] + bf2f((unsigned short)hv[0]) + bf2f((unsigned short)lv[0]) + b4.x);
                atomicAdd(ap + 1, acc[ft][et][1] + bf2f((unsigned short)hv[1]) + bf2f((unsigned short)lv[1]) + b4.y);
                atomicAdd(ap + 2, acc[ft][et][2] + bf2f((unsigned short)hv[2]) + bf2f((unsigned short)lv[2]) + b4.z);
                atomicAdd(ap + 3, acc[ft][et][3] + bf2f((unsigned short)hv[3]) + bf2f((unsigned short)lv[3]) + b4.w);
            }
        }
    }
}

// ================= fp32 VALU node-side kernels (unchanged from R1) =================

__device__ __forceinline__ void copy_w64(float* dst, const float* __restrict__ src, int t) {
    float4* d4 = (float4*)dst;
    const float4* s4 = (const float4*)src;
#pragma unroll
    for (int i = 0; i < 4; ++i) d4[t + 256 * i] = s4[t + 256 * i];
}

template <int KLEN>
__device__ __forceinline__ void gemm_tile(const float* A, const float* W,
                                          int r0, int c0, float (&acc)[4][4]) {
#pragma unroll 16
    for (int k = 0; k < KLEN; ++k) {
        const float4 a4 = *(const float4*)(A + k * LDA + r0);
        const float4 b4 = *(const float4*)(W + k * HH + c0);
        const float a[4] = {a4.x, a4.y, a4.z, a4.w};
        const float b[4] = {b4.x, b4.y, b4.z, b4.w};
#pragma unroll
        for (int i = 0; i < 4; ++i)
#pragma unroll
            for (int j = 0; j < 4; ++j)
                acc[i][j] = fmaf(a[i], b[j], acc[i][j]);
    }
}

__device__ __forceinline__ void init_acc_bias(float (&acc)[4][4], const float* __restrict__ b, int c0) {
    const float4 b4 = *(const float4*)(b + c0);
    const float bv[4] = {b4.x, b4.y, b4.z, b4.w};
#pragma unroll
    for (int i = 0; i < 4; ++i)
#pragma unroll
        for (int j = 0; j < 4; ++j) acc[i][j] = bv[j];
}

__device__ __forceinline__ void init_acc_zero(float (&acc)[4][4]) {
#pragma unroll
    for (int i = 0; i < 4; ++i)
#pragma unroll
        for (int j = 0; j < 4; ++j) acc[i][j] = 0.f;
}

__device__ __forceinline__ void relu_acc(float (&acc)[4][4]) {
#pragma unroll
    for (int i = 0; i < 4; ++i)
#pragma unroll
        for (int j = 0; j < 4; ++j) acc[i][j] = fmaxf(acc[i][j], 0.f);
}

__device__ __forceinline__ void store_T(float* lds, int r0, int c0, const float (&acc)[4][4]) {
#pragma unroll
    for (int j = 0; j < 4; ++j) {
        float4 v = make_float4(acc[0][j], acc[1][j], acc[2][j], acc[3][j]);
        *(float4*)(lds + (c0 + j) * LDA + r0) = v;
    }
}

__device__ __forceinline__ void stage_T64(float* lds, const float* __restrict__ g,
                                          long rowBase, int t, int nValid) {
    const int row = t >> 2, q = t & 3;
    const bool valid = row < nValid;
#pragma unroll
    for (int i = 0; i < 4; ++i) {
        const int col = i * 16 + q * 4;
        float4 v = make_float4(0.f, 0.f, 0.f, 0.f);
        if (valid) v = *(const float4*)(g + (size_t)(rowBase + row) * HH + col);
        lds[(col + 0) * LDA + row] = v.x;
        lds[(col + 1) * LDA + row] = v.y;
        lds[(col + 2) * LDA + row] = v.z;
        lds[(col + 3) * LDA + row] = v.w;
    }
}

__global__ __launch_bounds__(256, 3) void k_encode_nodes(
    const float* __restrict__ x,
    const float* __restrict__ wn1, const float* __restrict__ bn1,
    const float* __restrict__ wn2, const float* __restrict__ bn2,
    const float* __restrict__ w1s, const float* __restrict__ w1d,
    float* __restrict__ x_h, float* __restrict__ Ps, float* __restrict__ Pd)
{
    __shared__ float ldsA[HH * LDA];
    __shared__ float ldsT[HH * LDA];
    __shared__ float Wbuf[HH * HH];
    __shared__ float Wn1s[8 * HH];

    const int t = threadIdx.x;
    const int tc = t & 15, tr = t >> 4;
    const int r0 = tr * 4, c0 = tc * 4;
    const int nodeBase = blockIdx.x * 64;

    if (t < 64) {
        const int row = nodeBase + t;
        float4 a0 = make_float4(0.f, 0.f, 0.f, 0.f), a1 = a0;
        if (row < NN) {
            a0 = *(const float4*)(x + (size_t)row * 8);
            a1 = *(const float4*)(x + (size_t)row * 8 + 4);
        }
        ldsA[0 * LDA + t] = a0.x; ldsA[1 * LDA + t] = a0.y;
        ldsA[2 * LDA + t] = a0.z; ldsA[3 * LDA + t] = a0.w;
        ldsA[4 * LDA + t] = a1.x; ldsA[5 * LDA + t] = a1.y;
        ldsA[6 * LDA + t] = a1.z; ldsA[7 * LDA + t] = a1.w;
    }
    Wn1s[t] = wn1[t];
    Wn1s[t + 256] = wn1[t + 256];
    copy_w64(Wbuf, wn2, t);
    __syncthreads();

    float acc[4][4];
    init_acc_bias(acc, bn1, c0);
    gemm_tile<8>(ldsA, Wn1s, r0, c0, acc);
    relu_acc(acc);
    store_T(ldsT, r0, c0, acc);
    __syncthreads();

    init_acc_bias(acc, bn2, c0);
    gemm_tile<64>(ldsT, Wbuf, r0, c0, acc);
#pragma unroll
    for (int i = 0; i < 4; ++i) {
        if (nodeBase + r0 + i < NN) {
            float4 v = make_float4(acc[i][0], acc[i][1], acc[i][2], acc[i][3]);
            *(float4*)(x_h + (size_t)(nodeBase + r0 + i) * HH + c0) = v;
        }
    }
    store_T(ldsA, r0, c0, acc);
    __syncthreads();
    copy_w64(Wbuf, w1s, t);
    __syncthreads();

    init_acc_zero(acc);
    gemm_tile<64>(ldsA, Wbuf, r0, c0, acc);
#pragma unroll
    for (int i = 0; i < 4; ++i) {
        if (nodeBase + r0 + i < NN) {
            float4 v = make_float4(acc[i][0], acc[i][1], acc[i][2], acc[i][3]);
            *(float4*)(Ps + (size_t)(nodeBase + r0 + i) * HH + c0) = v;
        }
    }
    __syncthreads();
    copy_w64(Wbuf, w1d, t);
    __syncthreads();

    init_acc_zero(acc);
    gemm_tile<64>(ldsA, Wbuf, r0, c0, acc);
#pragma unroll
    for (int i = 0; i < 4; ++i) {
        if (nodeBase + r0 + i < NN) {
            float4 v = make_float4(acc[i][0], acc[i][1], acc[i][2], acc[i][3]);
            *(float4*)(Pd + (size_t)(nodeBase + r0 + i) * HH + c0) = v;
        }
    }
}

__global__ __launch_bounds__(256, 3) void k_node_l0(
    const float* __restrict__ agg,
    const float* __restrict__ w1nx, const float* __restrict__ w1na,
    const float* __restrict__ nb1,
    const float* __restrict__ w2n, const float* __restrict__ nb2,
    const float* __restrict__ w1s_next, const float* __restrict__ w1d_next,
    float* __restrict__ x_h, float* __restrict__ Ps, float* __restrict__ Pd)
{
    __shared__ float ldsA[HH * LDA];
    __shared__ float ldsB[HH * LDA];
    __shared__ float Wbuf[HH * HH];

    const int t = threadIdx.x;
    const int tc = t & 15, tr = t >> 4;
    const int r0 = tr * 4, c0 = tc * 4;
    const int nodeBase = blockIdx.x * 64;
    const int nValid = min(64, NN - nodeBase);

    stage_T64(ldsA, x_h, nodeBase, t, nValid);
    stage_T64(ldsB, agg, nodeBase, t, nValid);
    copy_w64(Wbuf, w1nx, t);
    __syncthreads();

    float acc[4][4];
    init_acc_bias(acc, nb1, c0);
    gemm_tile<64>(ldsA, Wbuf, r0, c0, acc);
    __syncthreads();
    copy_w64(Wbuf, w1na, t);
    __syncthreads();
    gemm_tile<64>(ldsB, Wbuf, r0, c0, acc);
    relu_acc(acc);
    __syncthreads();
    store_T(ldsB, r0, c0, acc);
    copy_w64(Wbuf, w2n, t);
    __syncthreads();

    {
        const float4 b4 = *(const float4*)(nb2 + c0);
        const float bv[4] = {b4.x, b4.y, b4.z, b4.w};
#pragma unroll
        for (int j = 0; j < 4; ++j) {
            const float4 xc = *(const float4*)(ldsA + (c0 + j) * LDA + r0);
            acc[0][j] = xc.x + bv[j];
            acc[1][j] = xc.y + bv[j];
            acc[2][j] = xc.z + bv[j];
            acc[3][j] = xc.w + bv[j];
        }
    }
    gemm_tile<64>(ldsB, Wbuf, r0, c0, acc);
#pragma unroll
    for (int i = 0; i < 4; ++i) {
        if (r0 + i < nValid) {
            float4 v = make_float4(acc[i][0], acc[i][1], acc[i][2], acc[i][3]);
            *(float4*)(x_h + (size_t)(nodeBase + r0 + i) * HH + c0) = v;
        }
    }
    __syncthreads();
    store_T(ldsA, r0, c0, acc);
    copy_w64(Wbuf, w1s_next, t);
    __syncthreads();

    init_acc_zero(acc);
    gemm_tile<64>(ldsA, Wbuf, r0, c0, acc);
#pragma unroll
    for (int i = 0; i < 4; ++i) {
        if (r0 + i < nValid) {
            float4 v = make_float4(acc[i][0], acc[i][1], acc[i][2], acc[i][3]);
            *(float4*)(Ps + (size_t)(nodeBase + r0 + i) * HH + c0) = v;
        }
    }
    __syncthreads();
    copy_w64(Wbuf, w1d_next, t);
    __syncthreads();

    init_acc_zero(acc);
    gemm_tile<64>(ldsA, Wbuf, r0, c0, acc);
#pragma unroll
    for (int i = 0; i < 4; ++i) {
        if (r0 + i < nValid) {
            float4 v = make_float4(acc[i][0], acc[i][1], acc[i][2], acc[i][3]);
            *(float4*)(Pd + (size_t)(nodeBase + r0 + i) * HH + c0) = v;
        }
    }
}

__global__ __launch_bounds__(256, 3) void k_node_l1_dec(
    const float* __restrict__ agg,
    const float* __restrict__ w1nx, const float* __restrict__ w1na,
    const float* __restrict__ nb1,
    const float* __restrict__ w2n, const float* __restrict__ nb2,
    const float* __restrict__ dw1, const float* __restrict__ db1,
    const float* __restrict__ dw2, const float* __restrict__ db2,
    const float* __restrict__ x_h, float* __restrict__ out)
{
    __shared__ float ldsA[HH * LDA];
    __shared__ float ldsB[HH * LDA];
    __shared__ float Wbuf[HH * HH];

    const int t = threadIdx.x;
    const int tc = t & 15, tr = t >> 4;
    const int r0 = tr * 4, c0 = tc * 4;
    const int nodeBase = blockIdx.x * 64;
    const int nValid = min(64, NN - nodeBase);

    stage_T64(ldsA, x_h, nodeBase, t, nValid);
    stage_T64(ldsB, agg, nodeBase, t, nValid);
    copy_w64(Wbuf, w1nx, t);
    __syncthreads();

    float acc[4][4];
    init_acc_bias(acc, nb1, c0);
    gemm_tile<64>(ldsA, Wbuf, r0, c0, acc);
    __syncthreads();
    copy_w64(Wbuf, w1na, t);
    __syncthreads();
    gemm_tile<64>(ldsB, Wbuf, r0, c0, acc);
    relu_acc(acc);
    __syncthreads();
    store_T(ldsB, r0, c0, acc);
    copy_w64(Wbuf, w2n, t);
    __syncthreads();

    {
        const float4 b4 = *(const float4*)(nb2 + c0);
        const float bv[4] = {b4.x, b4.y, b4.z, b4.w};
#pragma unroll
        for (int j = 0; j < 4; ++j) {
            const float4 xc = *(const float4*)(ldsA + (c0 + j) * LDA + r0);
            acc[0][j] = xc.x + bv[j];
            acc[1][j] = xc.y + bv[j];
            acc[2][j] = xc.z + bv[j];
            acc[3][j] = xc.w + bv[j];
        }
    }
    gemm_tile<64>(ldsB, Wbuf, r0, c0, acc);
    __syncthreads();
    store_T(ldsA, r0, c0, acc);
    copy_w64(Wbuf, dw1, t);
    __syncthreads();

    init_acc_bias(acc, db1, c0);
    gemm_tile<64>(ldsA, Wbuf, r0, c0, acc);
    relu_acc(acc);
    __syncthreads();
    store_T(ldsB, r0, c0, acc);
    if (t < 192) {
        Wbuf[t] = dw2[t];
        Wbuf[t + 192] = dw2[t + 192];
    }
    __syncthreads();

    if (t < 64) {
        float o[6];
#pragma unroll
        for (int c = 0; c < 6; ++c) o[c] = db2[c];
#pragma unroll 8
        for (int k = 0; k < 64; ++k) {
            const float a = ldsB[k * LDA + t];
#pragma unroll
            for (int c = 0; c < 6; ++c) o[c] = fmaf(a, Wbuf[k * 6 + c], o[c]);
        }
        if (t < nValid) {
            float* op = out + (size_t)(nodeBase + t) * 6;
#pragma unroll
            for (int c = 0; c < 6; ++c) op[c] = o[c];
        }
    }
}

// ---------------- launcher ----------------

extern "C" void kernel_launch(void* const* d_in, const int* in_sizes, int n_in,
                              void* d_out, int out_size, void* d_ws, size_t ws_size,
                              hipStream_t stream) {
    const float* x        = (const float*)d_in[0];
    const float* eattr    = (const float*)d_in[1];
    const int*   eidx     = (const int*)d_in[2];
    const float* enc_n_w1 = (const float*)d_in[3];
    const float* enc_n_b1 = (const float*)d_in[4];
    const float* enc_n_w2 = (const float*)d_in[5];
    const float* enc_n_b2 = (const float*)d_in[6];
    const float* enc_e_w1 = (const float*)d_in[7];
    const float* enc_e_b1 = (const float*)d_in[8];
    const float* enc_e_w2 = (const float*)d_in[9];
    const float* enc_e_b2 = (const float*)d_in[10];
    const float* pe_w1    = (const float*)d_in[11];  // [2,192,64]
    const float* pe_b1    = (const float*)d_in[12];  // [2,64]
    const float* pe_w2    = (const float*)d_in[13];  // [2,64,64]
    const float* pe_b2    = (const float*)d_in[14];  // [2,64]
    const float* pn_w1    = (const float*)d_in[15];  // [2,128,64]
    const float* pn_b1    = (const float*)d_in[16];
    const float* pn_w2    = (const float*)d_in[17];  // [2,64,64]
    const float* pn_b2    = (const float*)d_in[18];
    const float* dw1      = (const float*)d_in[19];
    const float* db1      = (const float*)d_in[20];
    const float* dw2      = (const float*)d_in[21];
    const float* db2      = (const float*)d_in[22];
    float* out = (float*)d_out;

    // ws layout (floats): x_h | Ps | Pd | agg (fp32) | e_h planes (bf16 hi, lo)
    float* ws  = (float*)d_ws;
    float* x_h = ws;
    float* Ps  = ws + (size_t)NN * HH;
    float* Pd  = ws + (size_t)NN * HH * 2;
    float* agg = ws + (size_t)NN * HH * 3;
    unsigned short* ehi = (unsigned short*)(ws + (size_t)NN * HH * 4);
    unsigned short* elo = ehi + (size_t)EE * HH;

    // converted-weight scratch lives in d_out (fully overwritten by decoder at the end)
    unsigned short* wt = (unsigned short*)d_out;

    const int nodeBlocks = (NN + 63) / 64;   // 782
    const int edgeBlocks = EE / EPB;         // 6250

    k_conv_w<<<88, 256, 0, stream>>>(
        enc_e_w2,                 // m0: We2
        pe_w1,                    // m1: W1e (l0)
        pe_w2,                    // m2: W2e (l0)
        pe_w1 + 192 * 64,         // m3: W1e (l1)
        pe_w2 + 64 * 64,          // m4: W2e (l1)
        enc_e_w1,                 // m5: We1 (K padded to 32)
        wt);

    hipMemsetAsync(agg, 0, (size_t)NN * HH * sizeof(float), stream);

    k_encode_nodes<<<nodeBlocks, 256, 0, stream>>>(
        x, enc_n_w1, enc_n_b1, enc_n_w2, enc_n_b2,
        pe_w1 + 64 * 64,        // W1s (l0)
        pe_w1 + 128 * 64,       // W1d (l0)
        x_h, Ps, Pd);

    k_edge_l0<<<edgeBlocks, 256, 0, stream>>>(
        eattr, eidx, Ps, Pd,
        enc_e_b1, enc_e_b2,
        wt, pe_b1, pe_b2,
        ehi, elo, agg);

    k_node_l0<<<nodeBlocks, 256, 0, stream>>>(
        agg,
        pn_w1, pn_w1 + 64 * 64, pn_b1,
        pn_w2, pn_b2,
        pe_w1 + 192 * 64 + 64 * 64,   // layer-1 W1s
        pe_w1 + 192 * 64 + 128 * 64,  // layer-1 W1d
        x_h, Ps, Pd);

    hipMemsetAsync(agg, 0, (size_t)NN * HH * sizeof(float), stream);

    k_edge_l1<<<edgeBlocks, 256, 0, stream>>>(
        eidx, Ps, Pd,
        wt, pe_b1 + 64, pe_b2 + 64,
        ehi, elo, agg);

    k_node_l1_dec<<<nodeBlocks, 256, 0, stream>>>(
        agg,
        pn_w1 + 128 * 64, pn_w1 + 128 * 64 + 64 * 64, pn_b1 + 64,
        pn_w2 + 64 * 64, pn_b2 + 64,
        dw1, db1, dw2, db2,
        x_h, out);
}

// Round 3
// 890.057 us; speedup vs baseline: 1.8946x; 1.8014x over previous
//
#include <hip/hip_runtime.h>

// GNN: N=50000 nodes, E=800000 edges, H=64, L=2.
// R3: atomics were the bottleneck (R1+R2 edge kernels both ~72G atomics/s).
// Replace fp32 scatter-atomics with CSR build (int atomics, 1.6M ops) +
// gather-based aggregation (wave per node, lane per feature).
// Edge GEMMs stay on MFMA split-bf16 (bf16x3). agg aliases Ps (disjoint live
// ranges; k_node_l0 reads agg rows before writing Ps rows within each block).

#define NN 50000
#define EE 800000
#define HH 64
#define LDA 68   // fp32 node-kernel LDS pad
#define LDK 72   // bf16 plane leading dim (144 B row: 16B-aligned, 2-way banks = free)
#define EPB 128  // edges per block in MFMA edge kernels

typedef short short8 __attribute__((ext_vector_type(8)));
typedef short short4v __attribute__((ext_vector_type(4)));
typedef float f32x4 __attribute__((ext_vector_type(4)));

#define MFMA __builtin_amdgcn_mfma_f32_16x16x32_bf16

// ---------------- bf16 split helpers ----------------

__device__ __forceinline__ void split2(float x, unsigned short& h, unsigned short& l) {
    union { float f; unsigned u; } a, hf, b;
    a.f = x;
    const unsigned hb = (a.u + 0x7FFFu + ((a.u >> 16) & 1u)) >> 16;  // RNE to bf16
    hf.u = hb << 16;
    b.f = x - hf.f;
    const unsigned lb = (b.u + 0x7FFFu + ((b.u >> 16) & 1u)) >> 16;
    h = (unsigned short)hb; l = (unsigned short)lb;
}

__device__ __forceinline__ float bf2f(unsigned short s) {
    union { unsigned u; float f; } a; a.u = ((unsigned)s) << 16; return a.f;
}

// A-frags for one 64x64 weight: [ft][c][p] (f-tile, k-chunk, hi/lo)
__device__ __forceinline__ void load_wf64(const unsigned short* __restrict__ wm,
                                          int fh, int l15, int quad,
                                          short8 (&w)[2][2][2]) {
#pragma unroll
    for (int ft = 0; ft < 2; ++ft)
#pragma unroll
        for (int c = 0; c < 2; ++c) {
            const int el = (fh * 32 + ft * 16 + l15) * 64 + c * 32 + quad * 8;
            w[ft][c][0] = *(const short8*)(wm + el);
            w[ft][c][1] = *(const short8*)(wm + 4096 + el);
        }
}

// D += Ah*Bh + Al*Bh + Ah*Bl over K=64 (2 chunks)
__device__ __forceinline__ f32x4 chain6(const short8 (&wf)[2][2],
                                        short8 bh0, short8 bh1,
                                        short8 bl0, short8 bl1, f32x4 a) {
    a = MFMA(wf[0][0], bh0, a, 0, 0, 0);
    a = MFMA(wf[1][0], bh1, a, 0, 0, 0);
    a = MFMA(wf[0][1], bh0, a, 0, 0, 0);
    a = MFMA(wf[1][1], bh1, a, 0, 0, 0);
    a = MFMA(wf[0][0], bl0, a, 0, 0, 0);
    a = MFMA(wf[1][0], bl1, a, 0, 0, 0);
    return a;
}

// ---------------- setup: split weights into bf16 hi/lo, transposed [f][k] ----------------

__global__ void k_conv_w(const float* __restrict__ w0, const float* __restrict__ w1,
                         const float* __restrict__ w2, const float* __restrict__ w3,
                         const float* __restrict__ w4, const float* __restrict__ we1,
                         unsigned short* __restrict__ wt)
{
    const int i = blockIdx.x * 256 + threadIdx.x;
    if (i < 5 * 4096) {
        const int m = i >> 12, r = i & 4095, f = r & 63;
        const int k = r >> 6;
        const float* W = m == 0 ? w0 : m == 1 ? w1 : m == 2 ? w2 : m == 3 ? w3 : w4;
        unsigned short h, l; split2(W[r], h, l);    // W[k*64+f]
        wt[m * 8192 + f * 64 + k] = h;
        wt[m * 8192 + 4096 + f * 64 + k] = l;
    } else if (i < 5 * 4096 + 2048) {
        const int r = i - 5 * 4096, f = r >> 5, k = r & 31;
        const float v = (k < 4) ? we1[k * 64 + f] : 0.f;
        unsigned short h, l; split2(v, h, l);
        wt[5 * 8192 + f * 32 + k] = h;
        wt[5 * 8192 + 2048 + f * 32 + k] = l;
    }
}

// ---------------- CSR build: deg -> scan -> fill ----------------

__global__ void k_deg(const int* __restrict__ eidx, unsigned* __restrict__ deg) {
    const int e = blockIdx.x * 256 + threadIdx.x;
    if (e < EE) atomicAdd(&deg[eidx[EE + e]], 1u);
}

__global__ __launch_bounds__(1024) void k_scan(unsigned* deg /* becomes cursor */,
                                               unsigned* __restrict__ off) {
    __shared__ unsigned part[1024];
    const int t = threadIdx.x;
    const int CH = (NN + 1023) / 1024;           // 49
    const int s = t * CH, e = s + CH < NN ? s + CH : NN;
    unsigned sum = 0;
    for (int i = s; i < e; ++i) sum += deg[i];
    part[t] = sum;
    __syncthreads();
    for (int d = 1; d < 1024; d <<= 1) {
        unsigned v = (t >= d) ? part[t - d] : 0u;
        __syncthreads();
        if (t >= d) part[t] += v;
        __syncthreads();
    }
    unsigned base = (t > 0) ? part[t - 1] : 0u;
    for (int i = s; i < e; ++i) {
        const unsigned d = deg[i];
        off[i] = base;
        deg[i] = base;          // reuse as fill cursor
        base += d;
    }
    if (t == 1023) off[NN] = part[1023];
}

__global__ void k_fill(const int* __restrict__ eidx, unsigned* __restrict__ cur,
                       int* __restrict__ csr) {
    const int e = blockIdx.x * 256 + threadIdx.x;
    if (e < EE) {
        const unsigned p = atomicAdd(&cur[eidx[EE + e]], 1u);
        csr[p] = e;
    }
}

// ---------------- aggregation: wave per node, lane per feature ----------------

__global__ __launch_bounds__(256, 8) void k_agg(
    const unsigned* __restrict__ off, const int* __restrict__ csr,
    const unsigned short* __restrict__ ehi, const unsigned short* __restrict__ elo,
    float* __restrict__ agg)
{
    const int wv = threadIdx.x >> 6, f = threadIdx.x & 63;
    const int n = blockIdx.x * 4 + wv;
    if (n >= NN) return;
    const unsigned s = off[n], e = off[n + 1];
    float acc = 0.f;
    unsigned j = s;
    if (j < e) {
        long eb = (long)csr[j] * HH + f;
        while (++j < e) {
            const long ebn = (long)csr[j] * HH + f;   // prefetch next row addr
            acc += bf2f(ehi[eb]) + bf2f(elo[eb]);
            eb = ebn;
        }
        acc += bf2f(ehi[eb]) + bf2f(elo[eb]);
    }
    agg[(size_t)n * HH + f] = acc;
}

// ---------------- K2: edge encoder + layer-0 edge MLP (MFMA, atomic-free) ----------------

__global__ __launch_bounds__(256, 2) void k_edge_l0(
    const float* __restrict__ eattr, const int* __restrict__ eidx,
    const float* __restrict__ Ps, const float* __restrict__ Pd,
    const float* __restrict__ be1, const float* __restrict__ be2,
    const unsigned short* __restrict__ wt,
    const float* __restrict__ pb1, const float* __restrict__ pb2,
    unsigned short* __restrict__ ehi, unsigned short* __restrict__ elo)
{
    __shared__ unsigned short pHhi[EPB * LDK], pHlo[EPB * LDK];
    __shared__ unsigned short pEhi[EPB * LDK], pElo[EPB * LDK];

    const int t = threadIdx.x;
    const int lane = t & 63, wv = t >> 6;
    const int quad = lane >> 4, l15 = lane & 15;
    const int fh = wv >> 1, eg = wv & 1;       // f-half, edge-group
    const long eBase = (long)blockIdx.x * EPB;

    int srcs[4], dsts[4];
#pragma unroll
    for (int et = 0; et < 4; ++et) {
        const long e = eBase + eg * 64 + et * 16 + l15;
        srcs[et] = eidx[e];
        dsts[et] = eidx[EE + e];
    }

    f32x4 acc[2][4];
    const f32x4 zz = {0.f, 0.f, 0.f, 0.f};

    // ===== h0 = relu(eattr @ We1 + be1)  (K padded to 32; quads 1..3 carry zeros)
    {
        short8 wa[2][2];
#pragma unroll
        for (int ft = 0; ft < 2; ++ft) {
            const int el = (fh * 32 + ft * 16 + l15) * 32 + quad * 8;
            wa[ft][0] = *(const short8*)(wt + 5 * 8192 + el);
            wa[ft][1] = *(const short8*)(wt + 5 * 8192 + 2048 + el);
        }
#pragma unroll
        for (int ft = 0; ft < 2; ++ft) {
            const int f0 = fh * 32 + ft * 16 + quad * 4;
            const float4 b4 = *(const float4*)(be1 + f0);
#pragma unroll
            for (int et = 0; et < 4; ++et) {
                acc[ft][et][0] = b4.x; acc[ft][et][1] = b4.y;
                acc[ft][et][2] = b4.z; acc[ft][et][3] = b4.w;
            }
        }
        const short8 z8 = {0, 0, 0, 0, 0, 0, 0, 0};
#pragma unroll
        for (int et = 0; et < 4; ++et) {
            const long e = eBase + eg * 64 + et * 16 + l15;
            const float4 ea = *(const float4*)(eattr + e * 4);
            union { unsigned short u[8]; short8 v; } bh, bl;
            split2(ea.x, bh.u[0], bl.u[0]); split2(ea.y, bh.u[1], bl.u[1]);
            split2(ea.z, bh.u[2], bl.u[2]); split2(ea.w, bh.u[3], bl.u[3]);
#pragma unroll
            for (int j = 4; j < 8; ++j) { bh.u[j] = 0; bl.u[j] = 0; }
            const short8 Bh = (quad == 0) ? bh.v : z8;
            const short8 Bl = (quad == 0) ? bl.v : z8;
#pragma unroll
            for (int ft = 0; ft < 2; ++ft) {
                f32x4 a = acc[ft][et];
                a = MFMA(wa[ft][0], Bh, a, 0, 0, 0);
                a = MFMA(wa[ft][1], Bh, a, 0, 0, 0);
                a = MFMA(wa[ft][0], Bl, a, 0, 0, 0);
                acc[ft][et] = a;
            }
        }
#pragma unroll
        for (int ft = 0; ft < 2; ++ft) {
            const int f0 = fh * 32 + ft * 16 + quad * 4;
#pragma unroll
            for (int et = 0; et < 4; ++et) {
                const int e = eg * 64 + et * 16 + l15;
                union { unsigned short u[4]; short4v v; } h, l;
#pragma unroll
                for (int r = 0; r < 4; ++r)
                    split2(fmaxf(acc[ft][et][r], 0.f), h.u[r], l.u[r]);
                *(short4v*)(pHhi + e * LDK + f0) = h.v;
                *(short4v*)(pHlo + e * LDK + f0) = l.v;
            }
        }
    }
    __syncthreads();

    // ===== e0 = h0 @ We2 + be2  -> pE planes
    {
        short8 w[2][2][2];
        load_wf64(wt + 0 * 8192, fh, l15, quad, w);
#pragma unroll
        for (int ft = 0; ft < 2; ++ft) {
            const int f0 = fh * 32 + ft * 16 + quad * 4;
            const float4 b4 = *(const float4*)(be2 + f0);
#pragma unroll
            for (int et = 0; et < 4; ++et) {
                acc[ft][et][0] = b4.x; acc[ft][et][1] = b4.y;
                acc[ft][et][2] = b4.z; acc[ft][et][3] = b4.w;
            }
        }
#pragma unroll
        for (int et = 0; et < 4; ++et) {
            const int e = eg * 64 + et * 16 + l15;
            const short8 bh0 = *(const short8*)(pHhi + e * LDK + quad * 8);
            const short8 bh1 = *(const short8*)(pHhi + e * LDK + 32 + quad * 8);
            const short8 bl0 = *(const short8*)(pHlo + e * LDK + quad * 8);
            const short8 bl1 = *(const short8*)(pHlo + e * LDK + 32 + quad * 8);
#pragma unroll
            for (int ft = 0; ft < 2; ++ft)
                acc[ft][et] = chain6(w[ft], bh0, bh1, bl0, bl1, acc[ft][et]);
        }
#pragma unroll
        for (int ft = 0; ft < 2; ++ft) {
            const int f0 = fh * 32 + ft * 16 + quad * 4;
#pragma unroll
            for (int et = 0; et < 4; ++et) {
                const int e = eg * 64 + et * 16 + l15;
                union { unsigned short u[4]; short4v v; } h, l;
#pragma unroll
                for (int r = 0; r < 4; ++r) split2(acc[ft][et][r], h.u[r], l.u[r]);
                *(short4v*)(pEhi + e * LDK + f0) = h.v;
                *(short4v*)(pElo + e * LDK + f0) = l.v;
            }
        }
    }
    __syncthreads();

    // ===== t1 = relu(e0 @ W1e + Ps[src] + Pd[dst] + pb1)  -> pH planes
    {
        short8 w[2][2][2];
        load_wf64(wt + 1 * 8192, fh, l15, quad, w);
#pragma unroll
        for (int ft = 0; ft < 2; ++ft)
#pragma unroll
            for (int et = 0; et < 4; ++et) acc[ft][et] = zz;
#pragma unroll
        for (int et = 0; et < 4; ++et) {
            const int e = eg * 64 + et * 16 + l15;
            const short8 bh0 = *(const short8*)(pEhi + e * LDK + quad * 8);
            const short8 bh1 = *(const short8*)(pEhi + e * LDK + 32 + quad * 8);
            const short8 bl0 = *(const short8*)(pElo + e * LDK + quad * 8);
            const short8 bl1 = *(const short8*)(pElo + e * LDK + 32 + quad * 8);
#pragma unroll
            for (int ft = 0; ft < 2; ++ft)
                acc[ft][et] = chain6(w[ft], bh0, bh1, bl0, bl1, acc[ft][et]);
        }
        // add gathers + bias, relu, split -> pH (pH free: its readers finished pre-barrier)
#pragma unroll
        for (int ft = 0; ft < 2; ++ft) {
            const int f0 = fh * 32 + ft * 16 + quad * 4;
            const float4 b4 = *(const float4*)(pb1 + f0);
#pragma unroll
            for (int et = 0; et < 4; ++et) {
                const int e = eg * 64 + et * 16 + l15;
                const float4 ps = *(const float4*)(Ps + (size_t)srcs[et] * HH + f0);
                const float4 pd = *(const float4*)(Pd + (size_t)dsts[et] * HH + f0);
                union { unsigned short u[4]; short4v v; } h, l;
                float v0 = fmaxf(acc[ft][et][0] + ps.x + pd.x + b4.x, 0.f);
                float v1 = fmaxf(acc[ft][et][1] + ps.y + pd.y + b4.y, 0.f);
                float v2 = fmaxf(acc[ft][et][2] + ps.z + pd.z + b4.z, 0.f);
                float v3 = fmaxf(acc[ft][et][3] + ps.w + pd.w + b4.w, 0.f);
                split2(v0, h.u[0], l.u[0]); split2(v1, h.u[1], l.u[1]);
                split2(v2, h.u[2], l.u[2]); split2(v3, h.u[3], l.u[3]);
                *(short4v*)(pHhi + e * LDK + f0) = h.v;
                *(short4v*)(pHlo + e * LDK + f0) = l.v;
            }
        }
    }
    __syncthreads();

    // ===== e1 = e0 + t1 @ W2e + pb2 -> pE planes (overwrite) -> global
    {
        short8 w[2][2][2];
        load_wf64(wt + 2 * 8192, fh, l15, quad, w);
#pragma unroll
        for (int ft = 0; ft < 2; ++ft)
#pragma unroll
            for (int et = 0; et < 4; ++et) acc[ft][et] = zz;
#pragma unroll
        for (int et = 0; et < 4; ++et) {
            const int e = eg * 64 + et * 16 + l15;
            const short8 bh0 = *(const short8*)(pHhi + e * LDK + quad * 8);
            const short8 bh1 = *(const short8*)(pHhi + e * LDK + 32 + quad * 8);
            const short8 bl0 = *(const short8*)(pHlo + e * LDK + quad * 8);
            const short8 bl1 = *(const short8*)(pHlo + e * LDK + 32 + quad * 8);
#pragma unroll
            for (int ft = 0; ft < 2; ++ft)
                acc[ft][et] = chain6(w[ft], bh0, bh1, bl0, bl1, acc[ft][et]);
        }
#pragma unroll
        for (int ft = 0; ft < 2; ++ft) {
            const int f0 = fh * 32 + ft * 16 + quad * 4;
            const float4 b4 = *(const float4*)(pb2 + f0);
#pragma unroll
            for (int et = 0; et < 4; ++et) {
                const int e = eg * 64 + et * 16 + l15;
                const short4v hv = *(const short4v*)(pEhi + e * LDK + f0);
                const short4v lv = *(const short4v*)(pElo + e * LDK + f0);
                float v[4];
                v[0] = acc[ft][et][0] + bf2f((unsigned short)hv[0]) + bf2f((unsigned short)lv[0]) + b4.x;
                v[1] = acc[ft][et][1] + bf2f((unsigned short)hv[1]) + bf2f((unsigned short)lv[1]) + b4.y;
                v[2] = acc[ft][et][2] + bf2f((unsigned short)hv[2]) + bf2f((unsigned short)lv[2]) + b4.z;
                v[3] = acc[ft][et][3] + bf2f((unsigned short)hv[3]) + bf2f((unsigned short)lv[3]) + b4.w;
                union { unsigned short u[4]; short4v v4; } h, l;
#pragma unroll
                for (int r = 0; r < 4; ++r) split2(v[r], h.u[r], l.u[r]);
                *(short4v*)(pEhi + e * LDK + f0) = h.v4;   // per-thread RMW of own cell
                *(short4v*)(pElo + e * LDK + f0) = l.v4;
            }
        }
    }
    __syncthreads();
    {
        const int row = t >> 1, ch = t & 1;
#pragma unroll
        for (int i = 0; i < 4; ++i) {
            const int lo_off = row * LDK + ch * 32 + i * 8;
            const long go = (eBase + row) * HH + ch * 32 + i * 8;
            *(uint4*)(ehi + go) = *(const uint4*)(pEhi + lo_off);
            *(uint4*)(elo + go) = *(const uint4*)(pElo + lo_off);
        }
    }
}

// ---------------- K4: layer-1 edge MLP (MFMA, atomic-free, planes in place) ----------------

__global__ __launch_bounds__(256, 2) void k_edge_l1(
    const int* __restrict__ eidx,
    const float* __restrict__ Ps, const float* __restrict__ Pd,
    const unsigned short* __restrict__ wt,
    const float* __restrict__ pb1, const float* __restrict__ pb2,
    unsigned short* __restrict__ ehi, unsigned short* __restrict__ elo)
{
    __shared__ unsigned short pEhi[EPB * LDK], pElo[EPB * LDK];
    __shared__ unsigned short pHhi[EPB * LDK], pHlo[EPB * LDK];

    const int t = threadIdx.x;
    const int lane = t & 63, wv = t >> 6;
    const int quad = lane >> 4, l15 = lane & 15;
    const int fh = wv >> 1, eg = wv & 1;
    const long eBase = (long)blockIdx.x * EPB;

    {
        const int row = t >> 1, ch = t & 1;
#pragma unroll
        for (int i = 0; i < 4; ++i) {
            const int lo_off = row * LDK + ch * 32 + i * 8;
            const long go = (eBase + row) * HH + ch * 32 + i * 8;
            *(uint4*)(pEhi + lo_off) = *(const uint4*)(ehi + go);
            *(uint4*)(pElo + lo_off) = *(const uint4*)(elo + go);
        }
    }

    int srcs[4], dsts[4];
#pragma unroll
    for (int et = 0; et < 4; ++et) {
        const long e = eBase + eg * 64 + et * 16 + l15;
        srcs[et] = eidx[e];
        dsts[et] = eidx[EE + e];
    }
    __syncthreads();

    f32x4 acc[2][4];
    const f32x4 zz = {0.f, 0.f, 0.f, 0.f};

    // ===== t1 = relu(e1 @ W1e + Ps[src] + Pd[dst] + pb1) -> pH
    {
        short8 w[2][2][2];
        load_wf64(wt + 3 * 8192, fh, l15, quad, w);
#pragma unroll
        for (int ft = 0; ft < 2; ++ft)
#pragma unroll
            for (int et = 0; et < 4; ++et) acc[ft][et] = zz;
#pragma unroll
        for (int et = 0; et < 4; ++et) {
            const int e = eg * 64 + et * 16 + l15;
            const short8 bh0 = *(const short8*)(pEhi + e * LDK + quad * 8);
            const short8 bh1 = *(const short8*)(pEhi + e * LDK + 32 + quad * 8);
            const short8 bl0 = *(const short8*)(pElo + e * LDK + quad * 8);
            const short8 bl1 = *(const short8*)(pElo + e * LDK + 32 + quad * 8);
#pragma unroll
            for (int ft = 0; ft < 2; ++ft)
                acc[ft][et] = chain6(w[ft], bh0, bh1, bl0, bl1, acc[ft][et]);
        }
#pragma unroll
        for (int ft = 0; ft < 2; ++ft) {
            const int f0 = fh * 32 + ft * 16 + quad * 4;
            const float4 b4 = *(const float4*)(pb1 + f0);
#pragma unroll
            for (int et = 0; et < 4; ++et) {
                const int e = eg * 64 + et * 16 + l15;
                const float4 ps = *(const float4*)(Ps + (size_t)srcs[et] * HH + f0);
                const float4 pd = *(const float4*)(Pd + (size_t)dsts[et] * HH + f0);
                union { unsigned short u[4]; short4v v; } h, l;
                float v0 = fmaxf(acc[ft][et][0] + ps.x + pd.x + b4.x, 0.f);
                float v1 = fmaxf(acc[ft][et][1] + ps.y + pd.y + b4.y, 0.f);
                float v2 = fmaxf(acc[ft][et][2] + ps.z + pd.z + b4.z, 0.f);
                float v3 = fmaxf(acc[ft][et][3] + ps.w + pd.w + b4.w, 0.f);
                split2(v0, h.u[0], l.u[0]); split2(v1, h.u[1], l.u[1]);
                split2(v2, h.u[2], l.u[2]); split2(v3, h.u[3], l.u[3]);
                *(short4v*)(pHhi + e * LDK + f0) = h.v;
                *(short4v*)(pHlo + e * LDK + f0) = l.v;
            }
        }
    }
    __syncthreads();

    // ===== e2 = e1 + t1 @ W2e + pb2 -> pE planes (overwrite) -> global (in place)
    {
        short8 w[2][2][2];
        load_wf64(wt + 4 * 8192, fh, l15, quad, w);
#pragma unroll
        for (int ft = 0; ft < 2; ++ft)
#pragma unroll
            for (int et = 0; et < 4; ++et) acc[ft][et] = zz;
#pragma unroll
        for (int et = 0; et < 4; ++et) {
            const int e = eg * 64 + et * 16 + l15;
            const short8 bh0 = *(const short8*)(pHhi + e * LDK + quad * 8);
            const short8 bh1 = *(const short8*)(pHhi + e * LDK + 32 + quad * 8);
            const short8 bl0 = *(const short8*)(pHlo + e * LDK + quad * 8);
            const short8 bl1 = *(const short8*)(pHlo + e * LDK + 32 + quad * 8);
#pragma unroll
            for (int ft = 0; ft < 2; ++ft)
                acc[ft][et] = chain6(w[ft], bh0, bh1, bl0, bl1, acc[ft][et]);
        }
#pragma unroll
        for (int ft = 0; ft < 2; ++ft) {
            const int f0 = fh * 32 + ft * 16 + quad * 4;
            const float4 b4 = *(const float4*)(pb2 + f0);
#pragma unroll
            for (int et = 0; et < 4; ++et) {
                const int e = eg * 64 + et * 16 + l15;
                const short4v hv = *(const short4v*)(pEhi + e * LDK + f0);
                const short4v lv = *(const short4v*)(pElo + e * LDK + f0);
                float v[4];
                v[0] = acc[ft][et][0] + bf2f((unsigned short)hv[0]) + bf2f((unsigned short)lv[0]) + b4.x;
                v[1] = acc[ft][et][1] + bf2f((unsigned short)hv[1]) + bf2f((unsigned short)lv[1]) + b4.y;
                v[2] = acc[ft][et][2] + bf2f((unsigned short)hv[2]) + bf2f((unsigned short)lv[2]) + b4.z;
                v[3] = acc[ft][et][3] + bf2f((unsigned short)hv[3]) + bf2f((unsigned short)lv[3]) + b4.w;
                union { unsigned short u[4]; short4v v4; } h, l;
#pragma unroll
                for (int r = 0; r < 4; ++r) split2(v[r], h.u[r], l.u[r]);
                *(short4v*)(pEhi + e * LDK + f0) = h.v4;
                *(short4v*)(pElo + e * LDK + f0) = l.v4;
            }
        }
    }
    __syncthreads();
    {
        const int row = t >> 1, ch = t & 1;
#pragma unroll
        for (int i = 0; i < 4; ++i) {
            const int lo_off = row * LDK + ch * 32 + i * 8;
            const long go = (eBase + row) * HH + ch * 32 + i * 8;
            *(uint4*)(ehi + go) = *(const uint4*)(pEhi + lo_off);
            *(uint4*)(elo + go) = *(const uint4*)(pElo + lo_off);
        }
    }
}

// ================= fp32 VALU node-side kernels =================

__device__ __forceinline__ void copy_w64(float* dst, const float* __restrict__ src, int t) {
    float4* d4 = (float4*)dst;
    const float4* s4 = (const float4*)src;
#pragma unroll
    for (int i = 0; i < 4; ++i) d4[t + 256 * i] = s4[t + 256 * i];
}

template <int KLEN>
__device__ __forceinline__ void gemm_tile(const float* A, const float* W,
                                          int r0, int c0, float (&acc)[4][4]) {
#pragma unroll 16
    for (int k = 0; k < KLEN; ++k) {
        const float4 a4 = *(const float4*)(A + k * LDA + r0);
        const float4 b4 = *(const float4*)(W + k * HH + c0);
        const float a[4] = {a4.x, a4.y, a4.z, a4.w};
        const float b[4] = {b4.x, b4.y, b4.z, b4.w};
#pragma unroll
        for (int i = 0; i < 4; ++i)
#pragma unroll
            for (int j = 0; j < 4; ++j)
                acc[i][j] = fmaf(a[i], b[j], acc[i][j]);
    }
}

__device__ __forceinline__ void init_acc_bias(float (&acc)[4][4], const float* __restrict__ b, int c0) {
    const float4 b4 = *(const float4*)(b + c0);
    const float bv[4] = {b4.x, b4.y, b4.z, b4.w};
#pragma unroll
    for (int i = 0; i < 4; ++i)
#pragma unroll
        for (int j = 0; j < 4; ++j) acc[i][j] = bv[j];
}

__device__ __forceinline__ void init_acc_zero(float (&acc)[4][4]) {
#pragma unroll
    for (int i = 0; i < 4; ++i)
#pragma unroll
        for (int j = 0; j < 4; ++j) acc[i][j] = 0.f;
}

__device__ __forceinline__ void relu_acc(float (&acc)[4][4]) {
#pragma unroll
    for (int i = 0; i < 4; ++i)
#pragma unroll
        for (int j = 0; j < 4; ++j) acc[i][j] = fmaxf(acc[i][j], 0.f);
}

__device__ __forceinline__ void store_T(float* lds, int r0, int c0, const float (&acc)[4][4]) {
#pragma unroll
    for (int j = 0; j < 4; ++j) {
        float4 v = make_float4(acc[0][j], acc[1][j], acc[2][j], acc[3][j]);
        *(float4*)(lds + (c0 + j) * LDA + r0) = v;
    }
}

__device__ __forceinline__ void stage_T64(float* lds, const float* g,
                                          long rowBase, int t, int nValid) {
    const int row = t >> 2, q = t & 3;
    const bool valid = row < nValid;
#pragma unroll
    for (int i = 0; i < 4; ++i) {
        const int col = i * 16 + q * 4;
        float4 v = make_float4(0.f, 0.f, 0.f, 0.f);
        if (valid) v = *(const float4*)(g + (size_t)(rowBase + row) * HH + col);
        lds[(col + 0) * LDA + row] = v.x;
        lds[(col + 1) * LDA + row] = v.y;
        lds[(col + 2) * LDA + row] = v.z;
        lds[(col + 3) * LDA + row] = v.w;
    }
}

__global__ __launch_bounds__(256, 3) void k_encode_nodes(
    const float* __restrict__ x,
    const float* __restrict__ wn1, const float* __restrict__ bn1,
    const float* __restrict__ wn2, const float* __restrict__ bn2,
    const float* __restrict__ w1s, const float* __restrict__ w1d,
    float* __restrict__ x_h, float* __restrict__ Ps, float* __restrict__ Pd)
{
    __shared__ float ldsA[HH * LDA];
    __shared__ float ldsT[HH * LDA];
    __shared__ float Wbuf[HH * HH];
    __shared__ float Wn1s[8 * HH];

    const int t = threadIdx.x;
    const int tc = t & 15, tr = t >> 4;
    const int r0 = tr * 4, c0 = tc * 4;
    const int nodeBase = blockIdx.x * 64;

    if (t < 64) {
        const int row = nodeBase + t;
        float4 a0 = make_float4(0.f, 0.f, 0.f, 0.f), a1 = a0;
        if (row < NN) {
            a0 = *(const float4*)(x + (size_t)row * 8);
            a1 = *(const float4*)(x + (size_t)row * 8 + 4);
        }
        ldsA[0 * LDA + t] = a0.x; ldsA[1 * LDA + t] = a0.y;
        ldsA[2 * LDA + t] = a0.z; ldsA[3 * LDA + t] = a0.w;
        ldsA[4 * LDA + t] = a1.x; ldsA[5 * LDA + t] = a1.y;
        ldsA[6 * LDA + t] = a1.z; ldsA[7 * LDA + t] = a1.w;
    }
    Wn1s[t] = wn1[t];
    Wn1s[t + 256] = wn1[t + 256];
    copy_w64(Wbuf, wn2, t);
    __syncthreads();

    float acc[4][4];
    init_acc_bias(acc, bn1, c0);
    gemm_tile<8>(ldsA, Wn1s, r0, c0, acc);
    relu_acc(acc);
    store_T(ldsT, r0, c0, acc);
    __syncthreads();

    init_acc_bias(acc, bn2, c0);
    gemm_tile<64>(ldsT, Wbuf, r0, c0, acc);
#pragma unroll
    for (int i = 0; i < 4; ++i) {
        if (nodeBase + r0 + i < NN) {
            float4 v = make_float4(acc[i][0], acc[i][1], acc[i][2], acc[i][3]);
            *(float4*)(x_h + (size_t)(nodeBase + r0 + i) * HH + c0) = v;
        }
    }
    store_T(ldsA, r0, c0, acc);
    __syncthreads();
    copy_w64(Wbuf, w1s, t);
    __syncthreads();

    init_acc_zero(acc);
    gemm_tile<64>(ldsA, Wbuf, r0, c0, acc);
#pragma unroll
    for (int i = 0; i < 4; ++i) {
        if (nodeBase + r0 + i < NN) {
            float4 v = make_float4(acc[i][0], acc[i][1], acc[i][2], acc[i][3]);
            *(float4*)(Ps + (size_t)(nodeBase + r0 + i) * HH + c0) = v;
        }
    }
    __syncthreads();
    copy_w64(Wbuf, w1d, t);
    __syncthreads();

    init_acc_zero(acc);
    gemm_tile<64>(ldsA, Wbuf, r0, c0, acc);
#pragma unroll
    for (int i = 0; i < 4; ++i) {
        if (nodeBase + r0 + i < NN) {
            float4 v = make_float4(acc[i][0], acc[i][1], acc[i][2], acc[i][3]);
            *(float4*)(Pd + (size_t)(nodeBase + r0 + i) * HH + c0) = v;
        }
    }
}

// NOTE: agg aliases Ps here. Safe: each block reads agg rows [base,base+64)
// into LDS before its first barrier, and writes Ps rows in the same range only
// after later barriers; no cross-block row sharing. __restrict__ dropped.
__global__ __launch_bounds__(256, 3) void k_node_l0(
    const float* agg,
    const float* __restrict__ w1nx, const float* __restrict__ w1na,
    const float* __restrict__ nb1,
    const float* __restrict__ w2n, const float* __restrict__ nb2,
    const float* __restrict__ w1s_next, const float* __restrict__ w1d_next,
    float* x_h, float* Ps, float* __restrict__ Pd)
{
    __shared__ float ldsA[HH * LDA];
    __shared__ float ldsB[HH * LDA];
    __shared__ float Wbuf[HH * HH];

    const int t = threadIdx.x;
    const int tc = t & 15, tr = t >> 4;
    const int r0 = tr * 4, c0 = tc * 4;
    const int nodeBase = blockIdx.x * 64;
    const int nValid = min(64, NN - nodeBase);

    stage_T64(ldsA, x_h, nodeBase, t, nValid);
    stage_T64(ldsB, agg, nodeBase, t, nValid);
    copy_w64(Wbuf, w1nx, t);
    __syncthreads();

    float acc[4][4];
    init_acc_bias(acc, nb1, c0);
    gemm_tile<64>(ldsA, Wbuf, r0, c0, acc);
    __syncthreads();
    copy_w64(Wbuf, w1na, t);
    __syncthreads();
    gemm_tile<64>(ldsB, Wbuf, r0, c0, acc);
    relu_acc(acc);
    __syncthreads();
    store_T(ldsB, r0, c0, acc);
    copy_w64(Wbuf, w2n, t);
    __syncthreads();

    {
        const float4 b4 = *(const float4*)(nb2 + c0);
        const float bv[4] = {b4.x, b4.y, b4.z, b4.w};
#pragma unroll
        for (int j = 0; j < 4; ++j) {
            const float4 xc = *(const float4*)(ldsA + (c0 + j) * LDA + r0);
            acc[0][j] = xc.x + bv[j];
            acc[1][j] = xc.y + bv[j];
            acc[2][j] = xc.z + bv[j];
            acc[3][j] = xc.w + bv[j];
        }
    }
    gemm_tile<64>(ldsB, Wbuf, r0, c0, acc);
#pragma unroll
    for (int i = 0; i < 4; ++i) {
        if (r0 + i < nValid) {
            float4 v = make_float4(acc[i][0], acc[i][1], acc[i][2], acc[i][3]);
            *(float4*)(x_h + (size_t)(nodeBase + r0 + i) * HH + c0) = v;
        }
    }
    __syncthreads();
    store_T(ldsA, r0, c0, acc);
    copy_w64(Wbuf, w1s_next, t);
    __syncthreads();

    init_acc_zero(acc);
    gemm_tile<64>(ldsA, Wbuf, r0, c0, acc);
#pragma unroll
    for (int i = 0; i < 4; ++i) {
        if (r0 + i < nValid) {
            float4 v = make_float4(acc[i][0], acc[i][1], acc[i][2], acc[i][3]);
            *(float4*)(Ps + (size_t)(nodeBase + r0 + i) * HH + c0) = v;
        }
    }
    __syncthreads();
    copy_w64(Wbuf, w1d_next, t);
    __syncthreads();

    init_acc_zero(acc);
    gemm_tile<64>(ldsA, Wbuf, r0, c0, acc);
#pragma unroll
    for (int i = 0; i < 4; ++i) {
        if (r0 + i < nValid) {
            float4 v = make_float4(acc[i][0], acc[i][1], acc[i][2], acc[i][3]);
            *(float4*)(Pd + (size_t)(nodeBase + r0 + i) * HH + c0) = v;
        }
    }
}

__global__ __launch_bounds__(256, 3) void k_node_l1_dec(
    const float* agg,   // aliases Ps buffer; read-only here
    const float* __restrict__ w1nx, const float* __restrict__ w1na,
    const float* __restrict__ nb1,
    const float* __restrict__ w2n, const float* __restrict__ nb2,
    const float* __restrict__ dw1, const float* __restrict__ db1,
    const float* __restrict__ dw2, const float* __restrict__ db2,
    const float* __restrict__ x_h, float* __restrict__ out)
{
    __shared__ float ldsA[HH * LDA];
    __shared__ float ldsB[HH * LDA];
    __shared__ float Wbuf[HH * HH];

    const int t = threadIdx.x;
    const int tc = t & 15, tr = t >> 4;
    const int r0 = tr * 4, c0 = tc * 4;
    const int nodeBase = blockIdx.x * 64;
    const int nValid = min(64, NN - nodeBase);

    stage_T64(ldsA, x_h, nodeBase, t, nValid);
    stage_T64(ldsB, agg, nodeBase, t, nValid);
    copy_w64(Wbuf, w1nx, t);
    __syncthreads();

    float acc[4][4];
    init_acc_bias(acc, nb1, c0);
    gemm_tile<64>(ldsA, Wbuf, r0, c0, acc);
    __syncthreads();
    copy_w64(Wbuf, w1na, t);
    __syncthreads();
    gemm_tile<64>(ldsB, Wbuf, r0, c0, acc);
    relu_acc(acc);
    __syncthreads();
    store_T(ldsB, r0, c0, acc);
    copy_w64(Wbuf, w2n, t);
    __syncthreads();

    {
        const float4 b4 = *(const float4*)(nb2 + c0);
        const float bv[4] = {b4.x, b4.y, b4.z, b4.w};
#pragma unroll
        for (int j = 0; j < 4; ++j) {
            const float4 xc = *(const float4*)(ldsA + (c0 + j) * LDA + r0);
            acc[0][j] = xc.x + bv[j];
            acc[1][j] = xc.y + bv[j];
            acc[2][j] = xc.z + bv[j];
            acc[3][j] = xc.w + bv[j];
        }
    }
    gemm_tile<64>(ldsB, Wbuf, r0, c0, acc);
    __syncthreads();
    store_T(ldsA, r0, c0, acc);
    copy_w64(Wbuf, dw1, t);
    __syncthreads();

    init_acc_bias(acc, db1, c0);
    gemm_tile<64>(ldsA, Wbuf, r0, c0, acc);
    relu_acc(acc);
    __syncthreads();
    store_T(ldsB, r0, c0, acc);
    if (t < 192) {
        Wbuf[t] = dw2[t];
        Wbuf[t + 192] = dw2[t + 192];
    }
    __syncthreads();

    if (t < 64) {
        float o[6];
#pragma unroll
        for (int c = 0; c < 6; ++c) o[c] = db2[c];
#pragma unroll 8
        for (int k = 0; k < 64; ++k) {
            const float a = ldsB[k * LDA + t];
#pragma unroll
            for (int c = 0; c < 6; ++c) o[c] = fmaf(a, Wbuf[k * 6 + c], o[c]);
        }
        if (t < nValid) {
            float* op = out + (size_t)(nodeBase + t) * 6;
#pragma unroll
            for (int c = 0; c < 6; ++c) op[c] = o[c];
        }
    }
}

// ---------------- launcher ----------------

extern "C" void kernel_launch(void* const* d_in, const int* in_sizes, int n_in,
                              void* d_out, int out_size, void* d_ws, size_t ws_size,
                              hipStream_t stream) {
    const float* x        = (const float*)d_in[0];
    const float* eattr    = (const float*)d_in[1];
    const int*   eidx     = (const int*)d_in[2];
    const float* enc_n_w1 = (const float*)d_in[3];
    const float* enc_n_b1 = (const float*)d_in[4];
    const float* enc_n_w2 = (const float*)d_in[5];
    const float* enc_n_b2 = (const float*)d_in[6];
    const float* enc_e_w1 = (const float*)d_in[7];
    const float* enc_e_b1 = (const float*)d_in[8];
    const float* enc_e_w2 = (const float*)d_in[9];
    const float* enc_e_b2 = (const float*)d_in[10];
    const float* pe_w1    = (const float*)d_in[11];  // [2,192,64]
    const float* pe_b1    = (const float*)d_in[12];  // [2,64]
    const float* pe_w2    = (const float*)d_in[13];  // [2,64,64]
    const float* pe_b2    = (const float*)d_in[14];  // [2,64]
    const float* pn_w1    = (const float*)d_in[15];  // [2,128,64]
    const float* pn_b1    = (const float*)d_in[16];
    const float* pn_w2    = (const float*)d_in[17];  // [2,64,64]
    const float* pn_b2    = (const float*)d_in[18];
    const float* dw1      = (const float*)d_in[19];
    const float* db1      = (const float*)d_in[20];
    const float* dw2      = (const float*)d_in[21];
    const float* db2      = (const float*)d_in[22];
    float* out = (float*)d_out;

    // ws layout: x_h | Ps (=agg, aliased) | Pd | ehi | elo | off | deg/cur | csr
    // 38.4MB + 204.8MB + 3.6MB = 246.8MB (fits the 256MB proven available)
    const size_t NNHH = (size_t)NN * HH;
    float* ws  = (float*)d_ws;
    float* x_h = ws;
    float* Ps  = ws + NNHH;
    float* agg = Ps;                       // aliased; see k_node_l0 note
    float* Pd  = ws + 2 * NNHH;
    unsigned short* ehi = (unsigned short*)(ws + 3 * NNHH);
    unsigned short* elo = ehi + (size_t)EE * HH;
    unsigned* off = (unsigned*)(elo + (size_t)EE * HH);   // NN+1
    unsigned* deg = off + (NN + 1);                       // NN, reused as cursor
    int* csr = (int*)(deg + NN);                          // EE

    // converted-weight scratch in d_out (overwritten by decoder at the end)
    unsigned short* wt = (unsigned short*)d_out;

    const int nodeBlocks = (NN + 63) / 64;   // 782
    const int edgeBlocks = EE / EPB;         // 6250
    const int eScal      = (EE + 255) / 256; // 3125

    hipMemsetAsync(deg, 0, (size_t)NN * sizeof(unsigned), stream);

    k_conv_w<<<88, 256, 0, stream>>>(
        enc_e_w2, pe_w1, pe_w2,
        pe_w1 + 192 * 64, pe_w2 + 64 * 64,
        enc_e_w1, wt);

    k_deg<<<eScal, 256, 0, stream>>>(eidx, deg);
    k_scan<<<1, 1024, 0, stream>>>(deg, off);
    k_fill<<<eScal, 256, 0, stream>>>(eidx, deg, csr);

    k_encode_nodes<<<nodeBlocks, 256, 0, stream>>>(
        x, enc_n_w1, enc_n_b1, enc_n_w2, enc_n_b2,
        pe_w1 + 64 * 64,        // W1s (l0)
        pe_w1 + 128 * 64,       // W1d (l0)
        x_h, Ps, Pd);

    k_edge_l0<<<edgeBlocks, 256, 0, stream>>>(
        eattr, eidx, Ps, Pd,
        enc_e_b1, enc_e_b2,
        wt, pe_b1, pe_b2,
        ehi, elo);

    k_agg<<<(NN + 3) / 4, 256, 0, stream>>>(off, csr, ehi, elo, agg);

    k_node_l0<<<nodeBlocks, 256, 0, stream>>>(
        agg,
        pn_w1, pn_w1 + 64 * 64, pn_b1,
        pn_w2, pn_b2,
        pe_w1 + 192 * 64 + 64 * 64,   // layer-1 W1s
        pe_w1 + 192 * 64 + 128 * 64,  // layer-1 W1d
        x_h, Ps, Pd);

    k_edge_l1<<<edgeBlocks, 256, 0, stream>>>(
        eidx, Ps, Pd,
        wt, pe_b1 + 64, pe_b2 + 64,
        ehi, elo);

    k_agg<<<(NN + 3) / 4, 256, 0, stream>>>(off, csr, ehi, elo, agg);

    k_node_l1_dec<<<nodeBlocks, 256, 0, stream>>>(
        agg,
        pn_w1 + 128 * 64, pn_w1 + 128 * 64 + 64 * 64, pn_b1 + 64,
        pn_w2 + 64 * 64, pn_b2 + 64,
        dw1, db1, dw2, db2,
        x_h, out);
}

// Round 4
// 809.063 us; speedup vs baseline: 2.0843x; 1.1001x over previous
//
#include <hip/hip_runtime.h>

// GNN: N=50000 nodes, E=800000 edges, H=64, L=2.
// R4: edge kernels were latency-bound at 21% occupancy (LDS 72KB -> 2 blocks/CU).
// EPB 64, wave-per-feature-tile, LDS 36KB -> 4 blocks/CU (50% occupancy).
// e0 residual in registers; eattr splits staged once; split2 shortened (trunc lo).
// CSR gather aggregation (R3) retained; node kernels fp32 VALU (R1) retained.

#define NN 50000
#define EE 800000
#define HH 64
#define LDA 68   // fp32 node-kernel LDS pad
#define LDK 72   // bf16 plane leading dim (144 B row: 16B-aligned, ~2-way banks)
#define EPB 64   // edges per block in MFMA edge kernels

typedef short short8 __attribute__((ext_vector_type(8)));
typedef short short4v __attribute__((ext_vector_type(4)));
typedef float f32x4 __attribute__((ext_vector_type(4)));

#define MFMA __builtin_amdgcn_mfma_f32_16x16x32_bf16

// ---------------- bf16 split helpers ----------------

__device__ __forceinline__ void split2(float x, unsigned short& h, unsigned short& l) {
    union { float f; unsigned u; } a, hf, b;
    a.f = x;
    const unsigned hb = (a.u + 0x7FFFu + ((a.u >> 16) & 1u)) >> 16;  // RNE hi
    hf.u = hb << 16;
    b.f = x - hf.f;                 // exact
    h = (unsigned short)hb;
    l = (unsigned short)(b.u >> 16); // truncated lo: err <= 2^-16 |x|
}

__device__ __forceinline__ float bf2f(unsigned short s) {
    union { unsigned u; float f; } a; a.u = ((unsigned)s) << 16; return a.f;
}

// A-frags for one 16-feature slice of a 64x64 weight: [chunk][plane]
__device__ __forceinline__ void load_wf(const unsigned short* __restrict__ wm,
                                        int ft, int l15, int quad, short8 (&w)[2][2]) {
#pragma unroll
    for (int c = 0; c < 2; ++c) {
        const int el = (ft * 16 + l15) * 64 + c * 32 + quad * 8;
        w[c][0] = *(const short8*)(wm + el);
        w[c][1] = *(const short8*)(wm + 4096 + el);
    }
}

// D += Ah*Bh + Al*Bh + Ah*Bl over K=64 (2 chunks)
__device__ __forceinline__ f32x4 chain6(const short8 (&w)[2][2],
                                        short8 bh0, short8 bh1,
                                        short8 bl0, short8 bl1, f32x4 a) {
    a = MFMA(w[0][0], bh0, a, 0, 0, 0);
    a = MFMA(w[1][0], bh1, a, 0, 0, 0);
    a = MFMA(w[0][1], bh0, a, 0, 0, 0);
    a = MFMA(w[1][1], bh1, a, 0, 0, 0);
    a = MFMA(w[0][0], bl0, a, 0, 0, 0);
    a = MFMA(w[1][0], bl1, a, 0, 0, 0);
    return a;
}

// ---------------- setup: split weights into bf16 hi/lo, transposed [f][k] ----------------

__global__ void k_conv_w(const float* __restrict__ w0, const float* __restrict__ w1,
                         const float* __restrict__ w2, const float* __restrict__ w3,
                         const float* __restrict__ w4, const float* __restrict__ we1,
                         unsigned short* __restrict__ wt)
{
    const int i = blockIdx.x * 256 + threadIdx.x;
    if (i < 5 * 4096) {
        const int m = i >> 12, r = i & 4095, f = r & 63;
        const int k = r >> 6;
        const float* W = m == 0 ? w0 : m == 1 ? w1 : m == 2 ? w2 : m == 3 ? w3 : w4;
        unsigned short h, l; split2(W[r], h, l);    // W[k*64+f]
        wt[m * 8192 + f * 64 + k] = h;
        wt[m * 8192 + 4096 + f * 64 + k] = l;
    } else if (i < 5 * 4096 + 2048) {
        const int r = i - 5 * 4096, f = r >> 5, k = r & 31;
        const float v = (k < 4) ? we1[k * 64 + f] : 0.f;
        unsigned short h, l; split2(v, h, l);
        wt[5 * 8192 + f * 32 + k] = h;
        wt[5 * 8192 + 2048 + f * 32 + k] = l;
    }
}

// ---------------- CSR build: deg -> scan -> fill ----------------

__global__ void k_deg(const int* __restrict__ eidx, unsigned* __restrict__ deg) {
    const int e = blockIdx.x * 256 + threadIdx.x;
    if (e < EE) atomicAdd(&deg[eidx[EE + e]], 1u);
}

__global__ __launch_bounds__(1024) void k_scan(unsigned* deg /* becomes cursor */,
                                               unsigned* __restrict__ off) {
    __shared__ unsigned part[1024];
    const int t = threadIdx.x;
    const int CH = (NN + 1023) / 1024;           // 49
    const int s = t * CH, e = s + CH < NN ? s + CH : NN;
    unsigned sum = 0;
    for (int i = s; i < e; ++i) sum += deg[i];
    part[t] = sum;
    __syncthreads();
    for (int d = 1; d < 1024; d <<= 1) {
        unsigned v = (t >= d) ? part[t - d] : 0u;
        __syncthreads();
        if (t >= d) part[t] += v;
        __syncthreads();
    }
    unsigned base = (t > 0) ? part[t - 1] : 0u;
    for (int i = s; i < e; ++i) {
        const unsigned d = deg[i];
        off[i] = base;
        deg[i] = base;          // reuse as fill cursor
        base += d;
    }
    if (t == 1023) off[NN] = part[1023];
}

__global__ void k_fill(const int* __restrict__ eidx, unsigned* __restrict__ cur,
                       int* __restrict__ csr) {
    const int e = blockIdx.x * 256 + threadIdx.x;
    if (e < EE) {
        const unsigned p = atomicAdd(&cur[eidx[EE + e]], 1u);
        csr[p] = e;
    }
}

// ---------------- aggregation: wave per node, lane per feature ----------------

__global__ __launch_bounds__(256, 8) void k_agg(
    const unsigned* __restrict__ off, const int* __restrict__ csr,
    const unsigned short* __restrict__ ehi, const unsigned short* __restrict__ elo,
    float* __restrict__ agg)
{
    const int wv = threadIdx.x >> 6, f = threadIdx.x & 63;
    const int n = blockIdx.x * 4 + wv;
    if (n >= NN) return;
    const unsigned s = off[n], e = off[n + 1];
    float acc = 0.f;
    unsigned j = s;
    if (j < e) {
        long eb = (long)csr[j] * HH + f;
        while (++j < e) {
            const long ebn = (long)csr[j] * HH + f;
            acc += bf2f(ehi[eb]) + bf2f(elo[eb]);
            eb = ebn;
        }
        acc += bf2f(ehi[eb]) + bf2f(elo[eb]);
    }
    agg[(size_t)n * HH + f] = acc;
}

// ---------------- K2: edge encoder + layer-0 edge MLP (MFMA) ----------------
// Plane roles: pH: eattr -> e0 -> e1 ; pE: h0 -> t1. e0 residual in registers.

__global__ __launch_bounds__(256, 4) void k_edge_l0(
    const float* __restrict__ eattr, const int* __restrict__ eidx,
    const float* __restrict__ Ps, const float* __restrict__ Pd,
    const float* __restrict__ be1, const float* __restrict__ be2,
    const unsigned short* __restrict__ wt,
    const float* __restrict__ pb1, const float* __restrict__ pb2,
    unsigned short* __restrict__ ehi, unsigned short* __restrict__ elo)
{
    __shared__ unsigned short pHhi[EPB * LDK], pHlo[EPB * LDK];
    __shared__ unsigned short pEhi[EPB * LDK], pElo[EPB * LDK];

    const int t = threadIdx.x;
    const int lane = t & 63, ft = t >> 6;     // wave owns features [ft*16, ft*16+16)
    const int quad = lane >> 4, l15 = lane & 15;
    const int f0 = ft * 16 + quad * 4;
    const long eBase = (long)blockIdx.x * EPB;

    // ---- stage eattr bf16-splits into pH (k 0..3 data, 4..31 zero)
    {
        const int row = t >> 2, q = t & 3;
        if (q == 0) {
            const float4 ea = *(const float4*)(eattr + (eBase + row) * 4);
            union { unsigned short u[8]; uint4 v; } H, L;
            split2(ea.x, H.u[0], L.u[0]); split2(ea.y, H.u[1], L.u[1]);
            split2(ea.z, H.u[2], L.u[2]); split2(ea.w, H.u[3], L.u[3]);
#pragma unroll
            for (int j = 4; j < 8; ++j) { H.u[j] = 0; L.u[j] = 0; }
            *(uint4*)(pHhi + row * LDK) = H.v;
            *(uint4*)(pHlo + row * LDK) = L.v;
        } else {
            const uint4 z = {0u, 0u, 0u, 0u};
            *(uint4*)(pHhi + row * LDK + q * 8) = z;
            *(uint4*)(pHlo + row * LDK + q * 8) = z;
        }
    }
    int srcs[4], dsts[4];
#pragma unroll
    for (int et = 0; et < 4; ++et) {
        const long e = eBase + et * 16 + l15;
        srcs[et] = eidx[e];
        dsts[et] = eidx[EE + e];
    }
    __syncthreads();

    f32x4 acc[4];
    const f32x4 zz = {0.f, 0.f, 0.f, 0.f};

    // ===== phase1: h0 = relu(eattr @ We1 + be1)  (K=32 padded) -> pE
    {
        short8 wa[2];
        const int el = (ft * 16 + l15) * 32 + quad * 8;
        wa[0] = *(const short8*)(wt + 5 * 8192 + el);
        wa[1] = *(const short8*)(wt + 5 * 8192 + 2048 + el);
        const float4 b4 = *(const float4*)(be1 + f0);
#pragma unroll
        for (int et = 0; et < 4; ++et) {
            acc[et][0] = b4.x; acc[et][1] = b4.y; acc[et][2] = b4.z; acc[et][3] = b4.w;
        }
#pragma unroll
        for (int et = 0; et < 4; ++et) {
            const int e = et * 16 + l15;
            const short8 bh0 = *(const short8*)(pHhi + e * LDK + quad * 8);
            const short8 bl0 = *(const short8*)(pHlo + e * LDK + quad * 8);
            f32x4 a = acc[et];
            a = MFMA(wa[0], bh0, a, 0, 0, 0);
            a = MFMA(wa[1], bh0, a, 0, 0, 0);
            a = MFMA(wa[0], bl0, a, 0, 0, 0);
            acc[et] = a;
        }
#pragma unroll
        for (int et = 0; et < 4; ++et) {
            const int e = et * 16 + l15;
            union { unsigned short u[4]; short4v v; } h, l;
#pragma unroll
            for (int r = 0; r < 4; ++r)
                split2(fmaxf(acc[et][r], 0.f), h.u[r], l.u[r]);
            *(short4v*)(pEhi + e * LDK + f0) = h.v;
            *(short4v*)(pElo + e * LDK + f0) = l.v;
        }
    }
    __syncthreads();

    // ===== phase2: e0 = h0 @ We2 + be2 (regs + splits -> pH)
    f32x4 e0s[4];
    {
        short8 w[2][2];
        load_wf(wt + 0 * 8192, ft, l15, quad, w);
        const float4 b4 = *(const float4*)(be2 + f0);
#pragma unroll
        for (int et = 0; et < 4; ++et) {
            acc[et][0] = b4.x; acc[et][1] = b4.y; acc[et][2] = b4.z; acc[et][3] = b4.w;
        }
#pragma unroll
        for (int et = 0; et < 4; ++et) {
            const int e = et * 16 + l15;
            const short8 bh0 = *(const short8*)(pEhi + e * LDK + quad * 8);
            const short8 bh1 = *(const short8*)(pEhi + e * LDK + 32 + quad * 8);
            const short8 bl0 = *(const short8*)(pElo + e * LDK + quad * 8);
            const short8 bl1 = *(const short8*)(pElo + e * LDK + 32 + quad * 8);
            acc[et] = chain6(w, bh0, bh1, bl0, bl1, acc[et]);
        }
#pragma unroll
        for (int et = 0; et < 4; ++et) {
            const int e = et * 16 + l15;
            e0s[et] = acc[et];
            union { unsigned short u[4]; short4v v; } h, l;
#pragma unroll
            for (int r = 0; r < 4; ++r) split2(acc[et][r], h.u[r], l.u[r]);
            *(short4v*)(pHhi + e * LDK + f0) = h.v;
            *(short4v*)(pHlo + e * LDK + f0) = l.v;
        }
    }
    __syncthreads();

    // ===== phase3: t1 = relu(e0 @ W1e + Ps[src] + Pd[dst] + pb1) -> pE
    {
        short8 w[2][2];
        load_wf(wt + 1 * 8192, ft, l15, quad, w);
#pragma unroll
        for (int et = 0; et < 4; ++et) acc[et] = zz;
#pragma unroll
        for (int et = 0; et < 4; ++et) {
            const int e = et * 16 + l15;
            const short8 bh0 = *(const short8*)(pHhi + e * LDK + quad * 8);
            const short8 bh1 = *(const short8*)(pHhi + e * LDK + 32 + quad * 8);
            const short8 bl0 = *(const short8*)(pHlo + e * LDK + quad * 8);
            const short8 bl1 = *(const short8*)(pHlo + e * LDK + 32 + quad * 8);
            acc[et] = chain6(w, bh0, bh1, bl0, bl1, acc[et]);
        }
        const float4 b4 = *(const float4*)(pb1 + f0);
#pragma unroll
        for (int et = 0; et < 4; ++et) {
            const int e = et * 16 + l15;
            const float4 ps = *(const float4*)(Ps + (size_t)srcs[et] * HH + f0);
            const float4 pd = *(const float4*)(Pd + (size_t)dsts[et] * HH + f0);
            union { unsigned short u[4]; short4v v; } h, l;
            split2(fmaxf(acc[et][0] + ps.x + pd.x + b4.x, 0.f), h.u[0], l.u[0]);
            split2(fmaxf(acc[et][1] + ps.y + pd.y + b4.y, 0.f), h.u[1], l.u[1]);
            split2(fmaxf(acc[et][2] + ps.z + pd.z + b4.z, 0.f), h.u[2], l.u[2]);
            split2(fmaxf(acc[et][3] + ps.w + pd.w + b4.w, 0.f), h.u[3], l.u[3]);
            *(short4v*)(pEhi + e * LDK + f0) = h.v;
            *(short4v*)(pElo + e * LDK + f0) = l.v;
        }
    }
    __syncthreads();

    // ===== phase4: e1 = e0(regs) + t1 @ W2e + pb2 -> pH
    {
        short8 w[2][2];
        load_wf(wt + 2 * 8192, ft, l15, quad, w);
#pragma unroll
        for (int et = 0; et < 4; ++et) acc[et] = zz;
#pragma unroll
        for (int et = 0; et < 4; ++et) {
            const int e = et * 16 + l15;
            const short8 bh0 = *(const short8*)(pEhi + e * LDK + quad * 8);
            const short8 bh1 = *(const short8*)(pEhi + e * LDK + 32 + quad * 8);
            const short8 bl0 = *(const short8*)(pElo + e * LDK + quad * 8);
            const short8 bl1 = *(const short8*)(pElo + e * LDK + 32 + quad * 8);
            acc[et] = chain6(w, bh0, bh1, bl0, bl1, acc[et]);
        }
        const float4 b4 = *(const float4*)(pb2 + f0);
#pragma unroll
        for (int et = 0; et < 4; ++et) {
            const int e = et * 16 + l15;
            union { unsigned short u[4]; short4v v; } h, l;
            split2(acc[et][0] + e0s[et][0] + b4.x, h.u[0], l.u[0]);
            split2(acc[et][1] + e0s[et][1] + b4.y, h.u[1], l.u[1]);
            split2(acc[et][2] + e0s[et][2] + b4.z, h.u[2], l.u[2]);
            split2(acc[et][3] + e0s[et][3] + b4.w, h.u[3], l.u[3]);
            *(short4v*)(pHhi + e * LDK + f0) = h.v;
            *(short4v*)(pHlo + e * LDK + f0) = l.v;
        }
    }
    __syncthreads();

    // ---- store pH -> global planes
    {
        const int row = t >> 2, q = t & 3;
        const long go = (eBase + row) * HH + q * 8;
        const int lo = row * LDK + q * 8;
        *(uint4*)(ehi + go)      = *(const uint4*)(pHhi + lo);
        *(uint4*)(ehi + go + 32) = *(const uint4*)(pHhi + lo + 32);
        *(uint4*)(elo + go)      = *(const uint4*)(pHlo + lo);
        *(uint4*)(elo + go + 32) = *(const uint4*)(pHlo + lo + 32);
    }
}

// ---------------- K4: layer-1 edge MLP (MFMA, planes updated in place) ----------------

__global__ __launch_bounds__(256, 4) void k_edge_l1(
    const int* __restrict__ eidx,
    const float* __restrict__ Ps, const float* __restrict__ Pd,
    const unsigned short* __restrict__ wt,
    const float* __restrict__ pb1, const float* __restrict__ pb2,
    unsigned short* __restrict__ ehi, unsigned short* __restrict__ elo)
{
    __shared__ unsigned short pEhi[EPB * LDK], pElo[EPB * LDK];
    __shared__ unsigned short pHhi[EPB * LDK], pHlo[EPB * LDK];

    const int t = threadIdx.x;
    const int lane = t & 63, ft = t >> 6;
    const int quad = lane >> 4, l15 = lane & 15;
    const int f0 = ft * 16 + quad * 4;
    const long eBase = (long)blockIdx.x * EPB;

    {
        const int row = t >> 2, q = t & 3;
        const long go = (eBase + row) * HH + q * 8;
        const int lo = row * LDK + q * 8;
        *(uint4*)(pEhi + lo)      = *(const uint4*)(ehi + go);
        *(uint4*)(pEhi + lo + 32) = *(const uint4*)(ehi + go + 32);
        *(uint4*)(pElo + lo)      = *(const uint4*)(elo + go);
        *(uint4*)(pElo + lo + 32) = *(const uint4*)(elo + go + 32);
    }
    int srcs[4], dsts[4];
#pragma unroll
    for (int et = 0; et < 4; ++et) {
        const long e = eBase + et * 16 + l15;
        srcs[et] = eidx[e];
        dsts[et] = eidx[EE + e];
    }
    __syncthreads();

    f32x4 acc[4];
    const f32x4 zz = {0.f, 0.f, 0.f, 0.f};

    // ===== t1 = relu(e1 @ W1e + Ps[src] + Pd[dst] + pb1) -> pH
    {
        short8 w[2][2];
        load_wf(wt + 3 * 8192, ft, l15, quad, w);
#pragma unroll
        for (int et = 0; et < 4; ++et) acc[et] = zz;
#pragma unroll
        for (int et = 0; et < 4; ++et) {
            const int e = et * 16 + l15;
            const short8 bh0 = *(const short8*)(pEhi + e * LDK + quad * 8);
            const short8 bh1 = *(const short8*)(pEhi + e * LDK + 32 + quad * 8);
            const short8 bl0 = *(const short8*)(pElo + e * LDK + quad * 8);
            const short8 bl1 = *(const short8*)(pElo + e * LDK + 32 + quad * 8);
            acc[et] = chain6(w, bh0, bh1, bl0, bl1, acc[et]);
        }
        const float4 b4 = *(const float4*)(pb1 + f0);
#pragma unroll
        for (int et = 0; et < 4; ++et) {
            const int e = et * 16 + l15;
            const float4 ps = *(const float4*)(Ps + (size_t)srcs[et] * HH + f0);
            const float4 pd = *(const float4*)(Pd + (size_t)dsts[et] * HH + f0);
            union { unsigned short u[4]; short4v v; } h, l;
            split2(fmaxf(acc[et][0] + ps.x + pd.x + b4.x, 0.f), h.u[0], l.u[0]);
            split2(fmaxf(acc[et][1] + ps.y + pd.y + b4.y, 0.f), h.u[1], l.u[1]);
            split2(fmaxf(acc[et][2] + ps.z + pd.z + b4.z, 0.f), h.u[2], l.u[2]);
            split2(fmaxf(acc[et][3] + ps.w + pd.w + b4.w, 0.f), h.u[3], l.u[3]);
            *(short4v*)(pHhi + e * LDK + f0) = h.v;
            *(short4v*)(pHlo + e * LDK + f0) = l.v;
        }
    }
    __syncthreads();

    // ===== e2 = e1(pE residual, own cells) + t1 @ W2e + pb2 -> pE in place
    {
        short8 w[2][2];
        load_wf(wt + 4 * 8192, ft, l15, quad, w);
#pragma unroll
        for (int et = 0; et < 4; ++et) acc[et] = zz;
#pragma unroll
        for (int et = 0; et < 4; ++et) {
            const int e = et * 16 + l15;
            const short8 bh0 = *(const short8*)(pHhi + e * LDK + quad * 8);
            const short8 bh1 = *(const short8*)(pHhi + e * LDK + 32 + quad * 8);
            const short8 bl0 = *(const short8*)(pHlo + e * LDK + quad * 8);
            const short8 bl1 = *(const short8*)(pHlo + e * LDK + 32 + quad * 8);
            acc[et] = chain6(w, bh0, bh1, bl0, bl1, acc[et]);
        }
        const float4 b4 = *(const float4*)(pb2 + f0);
#pragma unroll
        for (int et = 0; et < 4; ++et) {
            const int e = et * 16 + l15;
            const short4v hv = *(const short4v*)(pEhi + e * LDK + f0);
            const short4v lv = *(const short4v*)(pElo + e * LDK + f0);
            float v[4];
            v[0] = acc[et][0] + bf2f((unsigned short)hv[0]) + bf2f((unsigned short)lv[0]) + b4.x;
            v[1] = acc[et][1] + bf2f((unsigned short)hv[1]) + bf2f((unsigned short)lv[1]) + b4.y;
            v[2] = acc[et][2] + bf2f((unsigned short)hv[2]) + bf2f((unsigned short)lv[2]) + b4.z;
            v[3] = acc[et][3] + bf2f((unsigned short)hv[3]) + bf2f((unsigned short)lv[3]) + b4.w;
            union { unsigned short u[4]; short4v v4; } h, l;
#pragma unroll
            for (int r = 0; r < 4; ++r) split2(v[r], h.u[r], l.u[r]);
            *(short4v*)(pEhi + e * LDK + f0) = h.v4;   // same thread read these cells above
            *(short4v*)(pElo + e * LDK + f0) = l.v4;
        }
    }
    __syncthreads();
    {
        const int row = t >> 2, q = t & 3;
        const long go = (eBase + row) * HH + q * 8;
        const int lo = row * LDK + q * 8;
        *(uint4*)(ehi + go)      = *(const uint4*)(pEhi + lo);
        *(uint4*)(ehi + go + 32) = *(const uint4*)(pEhi + lo + 32);
        *(uint4*)(elo + go)      = *(const uint4*)(pElo + lo);
        *(uint4*)(elo + go + 32) = *(const uint4*)(pElo + lo + 32);
    }
}

// ================= fp32 VALU node-side kernels =================

__device__ __forceinline__ void copy_w64(float* dst, const float* __restrict__ src, int t) {
    float4* d4 = (float4*)dst;
    const float4* s4 = (const float4*)src;
#pragma unroll
    for (int i = 0; i < 4; ++i) d4[t + 256 * i] = s4[t + 256 * i];
}

template <int KLEN>
__device__ __forceinline__ void gemm_tile(const float* A, const float* W,
                                          int r0, int c0, float (&acc)[4][4]) {
#pragma unroll 16
    for (int k = 0; k < KLEN; ++k) {
        const float4 a4 = *(const float4*)(A + k * LDA + r0);
        const float4 b4 = *(const float4*)(W + k * HH + c0);
        const float a[4] = {a4.x, a4.y, a4.z, a4.w};
        const float b[4] = {b4.x, b4.y, b4.z, b4.w};
#pragma unroll
        for (int i = 0; i < 4; ++i)
#pragma unroll
            for (int j = 0; j < 4; ++j)
                acc[i][j] = fmaf(a[i], b[j], acc[i][j]);
    }
}

__device__ __forceinline__ void init_acc_bias(float (&acc)[4][4], const float* __restrict__ b, int c0) {
    const float4 b4 = *(const float4*)(b + c0);
    const float bv[4] = {b4.x, b4.y, b4.z, b4.w};
#pragma unroll
    for (int i = 0; i < 4; ++i)
#pragma unroll
        for (int j = 0; j < 4; ++j) acc[i][j] = bv[j];
}

__device__ __forceinline__ void init_acc_zero(float (&acc)[4][4]) {
#pragma unroll
    for (int i = 0; i < 4; ++i)
#pragma unroll
        for (int j = 0; j < 4; ++j) acc[i][j] = 0.f;
}

__device__ __forceinline__ void relu_acc(float (&acc)[4][4]) {
#pragma unroll
    for (int i = 0; i < 4; ++i)
#pragma unroll
        for (int j = 0; j < 4; ++j) acc[i][j] = fmaxf(acc[i][j], 0.f);
}

__device__ __forceinline__ void store_T(float* lds, int r0, int c0, const float (&acc)[4][4]) {
#pragma unroll
    for (int j = 0; j < 4; ++j) {
        float4 v = make_float4(acc[0][j], acc[1][j], acc[2][j], acc[3][j]);
        *(float4*)(lds + (c0 + j) * LDA + r0) = v;
    }
}

__device__ __forceinline__ void stage_T64(float* lds, const float* g,
                                          long rowBase, int t, int nValid) {
    const int row = t >> 2, q = t & 3;
    const bool valid = row < nValid;
#pragma unroll
    for (int i = 0; i < 4; ++i) {
        const int col = i * 16 + q * 4;
        float4 v = make_float4(0.f, 0.f, 0.f, 0.f);
        if (valid) v = *(const float4*)(g + (size_t)(rowBase + row) * HH + col);
        lds[(col + 0) * LDA + row] = v.x;
        lds[(col + 1) * LDA + row] = v.y;
        lds[(col + 2) * LDA + row] = v.z;
        lds[(col + 3) * LDA + row] = v.w;
    }
}

__global__ __launch_bounds__(256, 3) void k_encode_nodes(
    const float* __restrict__ x,
    const float* __restrict__ wn1, const float* __restrict__ bn1,
    const float* __restrict__ wn2, const float* __restrict__ bn2,
    const float* __restrict__ w1s, const float* __restrict__ w1d,
    float* __restrict__ x_h, float* __restrict__ Ps, float* __restrict__ Pd)
{
    __shared__ float ldsA[HH * LDA];
    __shared__ float ldsT[HH * LDA];
    __shared__ float Wbuf[HH * HH];
    __shared__ float Wn1s[8 * HH];

    const int t = threadIdx.x;
    const int tc = t & 15, tr = t >> 4;
    const int r0 = tr * 4, c0 = tc * 4;
    const int nodeBase = blockIdx.x * 64;

    if (t < 64) {
        const int row = nodeBase + t;
        float4 a0 = make_float4(0.f, 0.f, 0.f, 0.f), a1 = a0;
        if (row < NN) {
            a0 = *(const float4*)(x + (size_t)row * 8);
            a1 = *(const float4*)(x + (size_t)row * 8 + 4);
        }
        ldsA[0 * LDA + t] = a0.x; ldsA[1 * LDA + t] = a0.y;
        ldsA[2 * LDA + t] = a0.z; ldsA[3 * LDA + t] = a0.w;
        ldsA[4 * LDA + t] = a1.x; ldsA[5 * LDA + t] = a1.y;
        ldsA[6 * LDA + t] = a1.z; ldsA[7 * LDA + t] = a1.w;
    }
    Wn1s[t] = wn1[t];
    Wn1s[t + 256] = wn1[t + 256];
    copy_w64(Wbuf, wn2, t);
    __syncthreads();

    float acc[4][4];
    init_acc_bias(acc, bn1, c0);
    gemm_tile<8>(ldsA, Wn1s, r0, c0, acc);
    relu_acc(acc);
    store_T(ldsT, r0, c0, acc);
    __syncthreads();

    init_acc_bias(acc, bn2, c0);
    gemm_tile<64>(ldsT, Wbuf, r0, c0, acc);
#pragma unroll
    for (int i = 0; i < 4; ++i) {
        if (nodeBase + r0 + i < NN) {
            float4 v = make_float4(acc[i][0], acc[i][1], acc[i][2], acc[i][3]);
            *(float4*)(x_h + (size_t)(nodeBase + r0 + i) * HH + c0) = v;
        }
    }
    store_T(ldsA, r0, c0, acc);
    __syncthreads();
    copy_w64(Wbuf, w1s, t);
    __syncthreads();

    init_acc_zero(acc);
    gemm_tile<64>(ldsA, Wbuf, r0, c0, acc);
#pragma unroll
    for (int i = 0; i < 4; ++i) {
        if (nodeBase + r0 + i < NN) {
            float4 v = make_float4(acc[i][0], acc[i][1], acc[i][2], acc[i][3]);
            *(float4*)(Ps + (size_t)(nodeBase + r0 + i) * HH + c0) = v;
        }
    }
    __syncthreads();
    copy_w64(Wbuf, w1d, t);
    __syncthreads();

    init_acc_zero(acc);
    gemm_tile<64>(ldsA, Wbuf, r0, c0, acc);
#pragma unroll
    for (int i = 0; i < 4; ++i) {
        if (nodeBase + r0 + i < NN) {
            float4 v = make_float4(acc[i][0], acc[i][1], acc[i][2], acc[i][3]);
            *(float4*)(Pd + (size_t)(nodeBase + r0 + i) * HH + c0) = v;
        }
    }
}

// NOTE: agg aliases Ps. Safe: each block reads agg rows [base,base+64) into LDS
// before its first barrier; writes Ps rows in same range only later. No
// cross-block row sharing. __restrict__ dropped on aliased pointers.
__global__ __launch_bounds__(256, 3) void k_node_l0(
    const float* agg,
    const float* __restrict__ w1nx, const float* __restrict__ w1na,
    const float* __restrict__ nb1,
    const float* __restrict__ w2n, const float* __restrict__ nb2,
    const float* __restrict__ w1s_next, const float* __restrict__ w1d_next,
    float* x_h, float* Ps, float* __restrict__ Pd)
{
    __shared__ float ldsA[HH * LDA];
    __shared__ float ldsB[HH * LDA];
    __shared__ float Wbuf[HH * HH];

    const int t = threadIdx.x;
    const int tc = t & 15, tr = t >> 4;
    const int r0 = tr * 4, c0 = tc * 4;
    const int nodeBase = blockIdx.x * 64;
    const int nValid = min(64, NN - nodeBase);

    stage_T64(ldsA, x_h, nodeBase, t, nValid);
    stage_T64(ldsB, agg, nodeBase, t, nValid);
    copy_w64(Wbuf, w1nx, t);
    __syncthreads();

    float acc[4][4];
    init_acc_bias(acc, nb1, c0);
    gemm_tile<64>(ldsA, Wbuf, r0, c0, acc);
    __syncthreads();
    copy_w64(Wbuf, w1na, t);
    __syncthreads();
    gemm_tile<64>(ldsB, Wbuf, r0, c0, acc);
    relu_acc(acc);
    __syncthreads();
    store_T(ldsB, r0, c0, acc);
    copy_w64(Wbuf, w2n, t);
    __syncthreads();

    {
        const float4 b4 = *(const float4*)(nb2 + c0);
        const float bv[4] = {b4.x, b4.y, b4.z, b4.w};
#pragma unroll
        for (int j = 0; j < 4; ++j) {
            const float4 xc = *(const float4*)(ldsA + (c0 + j) * LDA + r0);
            acc[0][j] = xc.x + bv[j];
            acc[1][j] = xc.y + bv[j];
            acc[2][j] = xc.z + bv[j];
            acc[3][j] = xc.w + bv[j];
        }
    }
    gemm_tile<64>(ldsB, Wbuf, r0, c0, acc);
#pragma unroll
    for (int i = 0; i < 4; ++i) {
        if (r0 + i < nValid) {
            float4 v = make_float4(acc[i][0], acc[i][1], acc[i][2], acc[i][3]);
            *(float4*)(x_h + (size_t)(nodeBase + r0 + i) * HH + c0) = v;
        }
    }
    __syncthreads();
    store_T(ldsA, r0, c0, acc);
    copy_w64(Wbuf, w1s_next, t);
    __syncthreads();

    init_acc_zero(acc);
    gemm_tile<64>(ldsA, Wbuf, r0, c0, acc);
#pragma unroll
    for (int i = 0; i < 4; ++i) {
        if (r0 + i < nValid) {
            float4 v = make_float4(acc[i][0], acc[i][1], acc[i][2], acc[i][3]);
            *(float4*)(Ps + (size_t)(nodeBase + r0 + i) * HH + c0) = v;
        }
    }
    __syncthreads();
    copy_w64(Wbuf, w1d_next, t);
    __syncthreads();

    init_acc_zero(acc);
    gemm_tile<64>(ldsA, Wbuf, r0, c0, acc);
#pragma unroll
    for (int i = 0; i < 4; ++i) {
        if (r0 + i < nValid) {
            float4 v = make_float4(acc[i][0], acc[i][1], acc[i][2], acc[i][3]);
            *(float4*)(Pd + (size_t)(nodeBase + r0 + i) * HH + c0) = v;
        }
    }
}

__global__ __launch_bounds__(256, 3) void k_node_l1_dec(
    const float* agg,   // aliases Ps buffer; read-only here
    const float* __restrict__ w1nx, const float* __restrict__ w1na,
    const float* __restrict__ nb1,
    const float* __restrict__ w2n, const float* __restrict__ nb2,
    const float* __restrict__ dw1, const float* __restrict__ db1,
    const float* __restrict__ dw2, const float* __restrict__ db2,
    const float* __restrict__ x_h, float* __restrict__ out)
{
    __shared__ float ldsA[HH * LDA];
    __shared__ float ldsB[HH * LDA];
    __shared__ float Wbuf[HH * HH];

    const int t = threadIdx.x;
    const int tc = t & 15, tr = t >> 4;
    const int r0 = tr * 4, c0 = tc * 4;
    const int nodeBase = blockIdx.x * 64;
    const int nValid = min(64, NN - nodeBase);

    stage_T64(ldsA, x_h, nodeBase, t, nValid);
    stage_T64(ldsB, agg, nodeBase, t, nValid);
    copy_w64(Wbuf, w1nx, t);
    __syncthreads();

    float acc[4][4];
    init_acc_bias(acc, nb1, c0);
    gemm_tile<64>(ldsA, Wbuf, r0, c0, acc);
    __syncthreads();
    copy_w64(Wbuf, w1na, t);
    __syncthreads();
    gemm_tile<64>(ldsB, Wbuf, r0, c0, acc);
    relu_acc(acc);
    __syncthreads();
    store_T(ldsB, r0, c0, acc);
    copy_w64(Wbuf, w2n, t);
    __syncthreads();

    {
        const float4 b4 = *(const float4*)(nb2 + c0);
        const float bv[4] = {b4.x, b4.y, b4.z, b4.w};
#pragma unroll
        for (int j = 0; j < 4; ++j) {
            const float4 xc = *(const float4*)(ldsA + (c0 + j) * LDA + r0);
            acc[0][j] = xc.x + bv[j];
            acc[1][j] = xc.y + bv[j];
            acc[2][j] = xc.z + bv[j];
            acc[3][j] = xc.w + bv[j];
        }
    }
    gemm_tile<64>(ldsB, Wbuf, r0, c0, acc);
    __syncthreads();
    store_T(ldsA, r0, c0, acc);
    copy_w64(Wbuf, dw1, t);
    __syncthreads();

    init_acc_bias(acc, db1, c0);
    gemm_tile<64>(ldsA, Wbuf, r0, c0, acc);
    relu_acc(acc);
    __syncthreads();
    store_T(ldsB, r0, c0, acc);
    if (t < 192) {
        Wbuf[t] = dw2[t];
        Wbuf[t + 192] = dw2[t + 192];
    }
    __syncthreads();

    if (t < 64) {
        float o[6];
#pragma unroll
        for (int c = 0; c < 6; ++c) o[c] = db2[c];
#pragma unroll 8
        for (int k = 0; k < 64; ++k) {
            const float a = ldsB[k * LDA + t];
#pragma unroll
            for (int c = 0; c < 6; ++c) o[c] = fmaf(a, Wbuf[k * 6 + c], o[c]);
        }
        if (t < nValid) {
            float* op = out + (size_t)(nodeBase + t) * 6;
#pragma unroll
            for (int c = 0; c < 6; ++c) op[c] = o[c];
        }
    }
}

// ---------------- launcher ----------------

extern "C" void kernel_launch(void* const* d_in, const int* in_sizes, int n_in,
                              void* d_out, int out_size, void* d_ws, size_t ws_size,
                              hipStream_t stream) {
    const float* x        = (const float*)d_in[0];
    const float* eattr    = (const float*)d_in[1];
    const int*   eidx     = (const int*)d_in[2];
    const float* enc_n_w1 = (const float*)d_in[3];
    const float* enc_n_b1 = (const float*)d_in[4];
    const float* enc_n_w2 = (const float*)d_in[5];
    const float* enc_n_b2 = (const float*)d_in[6];
    const float* enc_e_w1 = (const float*)d_in[7];
    const float* enc_e_b1 = (const float*)d_in[8];
    const float* enc_e_w2 = (const float*)d_in[9];
    const float* enc_e_b2 = (const float*)d_in[10];
    const float* pe_w1    = (const float*)d_in[11];  // [2,192,64]
    const float* pe_b1    = (const float*)d_in[12];  // [2,64]
    const float* pe_w2    = (const float*)d_in[13];  // [2,64,64]
    const float* pe_b2    = (const float*)d_in[14];  // [2,64]
    const float* pn_w1    = (const float*)d_in[15];  // [2,128,64]
    const float* pn_b1    = (const float*)d_in[16];
    const float* pn_w2    = (const float*)d_in[17];  // [2,64,64]
    const float* pn_b2    = (const float*)d_in[18];
    const float* dw1      = (const float*)d_in[19];
    const float* db1      = (const float*)d_in[20];
    const float* dw2      = (const float*)d_in[21];
    const float* db2      = (const float*)d_in[22];
    float* out = (float*)d_out;

    // ws layout: x_h | Ps (=agg, aliased) | Pd | ehi | elo | off | deg/cur | csr
    const size_t NNHH = (size_t)NN * HH;
    float* ws  = (float*)d_ws;
    float* x_h = ws;
    float* Ps  = ws + NNHH;
    float* agg = Ps;                       // aliased; see k_node_l0 note
    float* Pd  = ws + 2 * NNHH;
    unsigned short* ehi = (unsigned short*)(ws + 3 * NNHH);
    unsigned short* elo = ehi + (size_t)EE * HH;
    unsigned* off = (unsigned*)(elo + (size_t)EE * HH);   // NN+1
    unsigned* deg = off + (NN + 1);                       // NN, reused as cursor
    int* csr = (int*)(deg + NN);                          // EE

    // converted-weight scratch in d_out (overwritten by decoder at the end)
    unsigned short* wt = (unsigned short*)d_out;

    const int nodeBlocks = (NN + 63) / 64;   // 782
    const int edgeBlocks = EE / EPB;         // 12500
    const int eScal      = (EE + 255) / 256; // 3125

    hipMemsetAsync(deg, 0, (size_t)NN * sizeof(unsigned), stream);

    k_conv_w<<<88, 256, 0, stream>>>(
        enc_e_w2, pe_w1, pe_w2,
        pe_w1 + 192 * 64, pe_w2 + 64 * 64,
        enc_e_w1, wt);

    k_deg<<<eScal, 256, 0, stream>>>(eidx, deg);
    k_scan<<<1, 1024, 0, stream>>>(deg, off);
    k_fill<<<eScal, 256, 0, stream>>>(eidx, deg, csr);

    k_encode_nodes<<<nodeBlocks, 256, 0, stream>>>(
        x, enc_n_w1, enc_n_b1, enc_n_w2, enc_n_b2,
        pe_w1 + 64 * 64,        // W1s (l0)
        pe_w1 + 128 * 64,       // W1d (l0)
        x_h, Ps, Pd);

    k_edge_l0<<<edgeBlocks, 256, 0, stream>>>(
        eattr, eidx, Ps, Pd,
        enc_e_b1, enc_e_b2,
        wt, pe_b1, pe_b2,
        ehi, elo);

    k_agg<<<(NN + 3) / 4, 256, 0, stream>>>(off, csr, ehi, elo, agg);

    k_node_l0<<<nodeBlocks, 256, 0, stream>>>(
        agg,
        pn_w1, pn_w1 + 64 * 64, pn_b1,
        pn_w2, pn_b2,
        pe_w1 + 192 * 64 + 64 * 64,   // layer-1 W1s
        pe_w1 + 192 * 64 + 128 * 64,  // layer-1 W1d
        x_h, Ps, Pd);

    k_edge_l1<<<edgeBlocks, 256, 0, stream>>>(
        eidx, Ps, Pd,
        wt, pe_b1 + 64, pe_b2 + 64,
        ehi, elo);

    k_agg<<<(NN + 3) / 4, 256, 0, stream>>>(off, csr, ehi, elo, agg);

    k_node_l1_dec<<<nodeBlocks, 256, 0, stream>>>(
        agg,
        pn_w1 + 128 * 64, pn_w1 + 128 * 64 + 64 * 64, pn_b1 + 64,
        pn_w2 + 64 * 64, pn_b2 + 64,
        dw1, db1, dw2, db2,
        x_h, out);
}

// Round 5
// 745.302 us; speedup vs baseline: 2.2626x; 1.0856x over previous
//
#include <hip/hip_runtime.h>

// GNN: N=50000 nodes, E=800000 edges, H=64, L=2.
// R5: k_agg was ~260us combined due to RANDOM plane-row reads (csr scatter).
// Fix: process edges in dst-sorted order everywhere. Edge kernels gather
// eattr/src/dst via the sorted permutation and write planes at SORTED
// positions -> k_agg reads each node's rows CONTIGUOUSLY (streaming, BW-bound).
// Bonus: Pd gathers in edge kernels become block-local (few distinct dst).
// Edge GEMMs: MFMA split-bf16 (R4). Node kernels: fp32 VALU (R1).

#define NN 50000
#define EE 800000
#define HH 64
#define LDA 68   // fp32 node-kernel LDS pad
#define LDK 72   // bf16 plane leading dim (144 B row)
#define EPB 64   // edges per block in MFMA edge kernels

typedef short short8 __attribute__((ext_vector_type(8)));
typedef short short4v __attribute__((ext_vector_type(4)));
typedef float f32x4 __attribute__((ext_vector_type(4)));

#define MFMA __builtin_amdgcn_mfma_f32_16x16x32_bf16

// ---------------- bf16 split helpers ----------------

__device__ __forceinline__ void split2(float x, unsigned short& h, unsigned short& l) {
    union { float f; unsigned u; } a, hf, b;
    a.f = x;
    const unsigned hb = (a.u + 0x7FFFu + ((a.u >> 16) & 1u)) >> 16;  // RNE hi
    hf.u = hb << 16;
    b.f = x - hf.f;                  // exact
    h = (unsigned short)hb;
    l = (unsigned short)(b.u >> 16); // truncated lo: err <= 2^-16 |x|
}

__device__ __forceinline__ float bf2f(unsigned short s) {
    union { unsigned u; float f; } a; a.u = ((unsigned)s) << 16; return a.f;
}

// A-frags for one 16-feature slice of a 64x64 weight: [chunk][plane]
__device__ __forceinline__ void load_wf(const unsigned short* __restrict__ wm,
                                        int ft, int l15, int quad, short8 (&w)[2][2]) {
#pragma unroll
    for (int c = 0; c < 2; ++c) {
        const int el = (ft * 16 + l15) * 64 + c * 32 + quad * 8;
        w[c][0] = *(const short8*)(wm + el);
        w[c][1] = *(const short8*)(wm + 4096 + el);
    }
}

// D += Ah*Bh + Al*Bh + Ah*Bl over K=64 (2 chunks)
__device__ __forceinline__ f32x4 chain6(const short8 (&w)[2][2],
                                        short8 bh0, short8 bh1,
                                        short8 bl0, short8 bl1, f32x4 a) {
    a = MFMA(w[0][0], bh0, a, 0, 0, 0);
    a = MFMA(w[1][0], bh1, a, 0, 0, 0);
    a = MFMA(w[0][1], bh0, a, 0, 0, 0);
    a = MFMA(w[1][1], bh1, a, 0, 0, 0);
    a = MFMA(w[0][0], bl0, a, 0, 0, 0);
    a = MFMA(w[1][0], bl1, a, 0, 0, 0);
    return a;
}

// ---------------- setup: split weights into bf16 hi/lo, transposed [f][k] ----------------

__global__ void k_conv_w(const float* __restrict__ w0, const float* __restrict__ w1,
                         const float* __restrict__ w2, const float* __restrict__ w3,
                         const float* __restrict__ w4, const float* __restrict__ we1,
                         unsigned short* __restrict__ wt)
{
    const int i = blockIdx.x * 256 + threadIdx.x;
    if (i < 5 * 4096) {
        const int m = i >> 12, r = i & 4095, f = r & 63;
        const int k = r >> 6;
        const float* W = m == 0 ? w0 : m == 1 ? w1 : m == 2 ? w2 : m == 3 ? w3 : w4;
        unsigned short h, l; split2(W[r], h, l);    // W[k*64+f]
        wt[m * 8192 + f * 64 + k] = h;
        wt[m * 8192 + 4096 + f * 64 + k] = l;
    } else if (i < 5 * 4096 + 2048) {
        const int r = i - 5 * 4096, f = r >> 5, k = r & 31;
        const float v = (k < 4) ? we1[k * 64 + f] : 0.f;
        unsigned short h, l; split2(v, h, l);
        wt[5 * 8192 + f * 32 + k] = h;
        wt[5 * 8192 + 2048 + f * 32 + k] = l;
    }
}

// ---------------- CSR build: deg -> scan -> fill (+ pre-gathered src/dst) ----------------

__global__ void k_deg(const int* __restrict__ eidx, unsigned* __restrict__ deg) {
    const int e = blockIdx.x * 256 + threadIdx.x;
    if (e < EE) atomicAdd(&deg[eidx[EE + e]], 1u);
}

__global__ __launch_bounds__(1024) void k_scan(unsigned* deg /* becomes cursor */,
                                               unsigned* __restrict__ off) {
    __shared__ unsigned part[1024];
    const int t = threadIdx.x;
    const int CH = (NN + 1023) / 1024;           // 49
    const int s = t * CH, e = s + CH < NN ? s + CH : NN;
    unsigned sum = 0;
    for (int i = s; i < e; ++i) sum += deg[i];
    part[t] = sum;
    __syncthreads();
    for (int d = 1; d < 1024; d <<= 1) {
        unsigned v = (t >= d) ? part[t - d] : 0u;
        __syncthreads();
        if (t >= d) part[t] += v;
        __syncthreads();
    }
    unsigned base = (t > 0) ? part[t - 1] : 0u;
    for (int i = s; i < e; ++i) {
        const unsigned d = deg[i];
        off[i] = base;
        deg[i] = base;          // reuse as fill cursor
        base += d;
    }
    if (t == 1023) off[NN] = part[1023];
}

__global__ void k_fill(const int* __restrict__ eidx, unsigned* __restrict__ cur,
                       int* __restrict__ csr, int* __restrict__ srcs_s,
                       int* __restrict__ dsts_s) {
    const int e = blockIdx.x * 256 + threadIdx.x;
    if (e < EE) {
        const int d = eidx[EE + e];
        const unsigned p = atomicAdd(&cur[d], 1u);
        csr[p] = e;
        srcs_s[p] = eidx[e];
        dsts_s[p] = d;
    }
}

// ---------------- aggregation: wave per node, lane per feature ----------------
// Planes are stored in dst-sorted order: node n's rows are [off[n], off[n+1]).

__global__ __launch_bounds__(256, 8) void k_agg(
    const unsigned* __restrict__ off,
    const unsigned short* __restrict__ ehi, const unsigned short* __restrict__ elo,
    float* __restrict__ agg)
{
    const int wv = threadIdx.x >> 6, f = threadIdx.x & 63;
    const int n = blockIdx.x * 4 + wv;
    if (n >= NN) return;
    const unsigned s = off[n], e = off[n + 1];
    float acc = 0.f;
    unsigned j = s;
    for (; j + 4 <= e; j += 4) {                  // 8 independent loads in flight
        const size_t b = (size_t)j * HH + f;
        const float a0 = bf2f(ehi[b])       + bf2f(elo[b]);
        const float a1 = bf2f(ehi[b + 64])  + bf2f(elo[b + 64]);
        const float a2 = bf2f(ehi[b + 128]) + bf2f(elo[b + 128]);
        const float a3 = bf2f(ehi[b + 192]) + bf2f(elo[b + 192]);
        acc += (a0 + a1) + (a2 + a3);
    }
    for (; j < e; ++j) {
        const size_t b = (size_t)j * HH + f;
        acc += bf2f(ehi[b]) + bf2f(elo[b]);
    }
    agg[(size_t)n * HH + f] = acc;
}

// ---------------- K2: edge encoder + layer-0 edge MLP (MFMA, sorted order) ----------------
// Plane roles: pH: eattr -> e0 -> e1 ; pE: h0 -> t1. e0 residual in registers.

__global__ __launch_bounds__(256, 4) void k_edge_l0(
    const float* __restrict__ eattr, const int* __restrict__ csr,
    const int* __restrict__ srcs_s, const int* __restrict__ dsts_s,
    const float* __restrict__ Ps, const float* __restrict__ Pd,
    const float* __restrict__ be1, const float* __restrict__ be2,
    const unsigned short* __restrict__ wt,
    const float* __restrict__ pb1, const float* __restrict__ pb2,
    unsigned short* __restrict__ ehi, unsigned short* __restrict__ elo)
{
    __shared__ unsigned short pHhi[EPB * LDK], pHlo[EPB * LDK];
    __shared__ unsigned short pEhi[EPB * LDK], pElo[EPB * LDK];

    const int t = threadIdx.x;
    const int lane = t & 63, ft = t >> 6;     // wave owns features [ft*16, ft*16+16)
    const int quad = lane >> 4, l15 = lane & 15;
    const int f0 = ft * 16 + quad * 4;
    const long eBase = (long)blockIdx.x * EPB;

    // ---- stage eattr (gathered via csr) bf16-splits into pH (k 0..3 data, 4..31 zero)
    {
        const int row = t >> 2, q = t & 3;
        if (q == 0) {
            const int eid = csr[eBase + row];
            const float4 ea = *(const float4*)(eattr + (size_t)eid * 4);
            union { unsigned short u[8]; uint4 v; } H, L;
            split2(ea.x, H.u[0], L.u[0]); split2(ea.y, H.u[1], L.u[1]);
            split2(ea.z, H.u[2], L.u[2]); split2(ea.w, H.u[3], L.u[3]);
#pragma unroll
            for (int j = 4; j < 8; ++j) { H.u[j] = 0; L.u[j] = 0; }
            *(uint4*)(pHhi + row * LDK) = H.v;
            *(uint4*)(pHlo + row * LDK) = L.v;
        } else {
            const uint4 z = {0u, 0u, 0u, 0u};
            *(uint4*)(pHhi + row * LDK + q * 8) = z;
            *(uint4*)(pHlo + row * LDK + q * 8) = z;
        }
    }
    int srcs[4], dsts[4];
#pragma unroll
    for (int et = 0; et < 4; ++et) {
        const long p = eBase + et * 16 + l15;
        srcs[et] = srcs_s[p];
        dsts[et] = dsts_s[p];      // near-constant within block (sorted) -> L1 hits
    }
    __syncthreads();

    f32x4 acc[4];
    const f32x4 zz = {0.f, 0.f, 0.f, 0.f};

    // ===== phase1: h0 = relu(eattr @ We1 + be1)  (K=32 padded) -> pE
    {
        short8 wa[2];
        const int el = (ft * 16 + l15) * 32 + quad * 8;
        wa[0] = *(const short8*)(wt + 5 * 8192 + el);
        wa[1] = *(const short8*)(wt + 5 * 8192 + 2048 + el);
        const float4 b4 = *(const float4*)(be1 + f0);
#pragma unroll
        for (int et = 0; et < 4; ++et) {
            acc[et][0] = b4.x; acc[et][1] = b4.y; acc[et][2] = b4.z; acc[et][3] = b4.w;
        }
#pragma unroll
        for (int et = 0; et < 4; ++et) {
            const int e = et * 16 + l15;
            const short8 bh0 = *(const short8*)(pHhi + e * LDK + quad * 8);
            const short8 bl0 = *(const short8*)(pHlo + e * LDK + quad * 8);
            f32x4 a = acc[et];
            a = MFMA(wa[0], bh0, a, 0, 0, 0);
            a = MFMA(wa[1], bh0, a, 0, 0, 0);
            a = MFMA(wa[0], bl0, a, 0, 0, 0);
            acc[et] = a;
        }
#pragma unroll
        for (int et = 0; et < 4; ++et) {
            const int e = et * 16 + l15;
            union { unsigned short u[4]; short4v v; } h, l;
#pragma unroll
            for (int r = 0; r < 4; ++r)
                split2(fmaxf(acc[et][r], 0.f), h.u[r], l.u[r]);
            *(short4v*)(pEhi + e * LDK + f0) = h.v;
            *(short4v*)(pElo + e * LDK + f0) = l.v;
        }
    }
    __syncthreads();

    // ===== phase2: e0 = h0 @ We2 + be2 (regs + splits -> pH)
    f32x4 e0s[4];
    {
        short8 w[2][2];
        load_wf(wt + 0 * 8192, ft, l15, quad, w);
        const float4 b4 = *(const float4*)(be2 + f0);
#pragma unroll
        for (int et = 0; et < 4; ++et) {
            acc[et][0] = b4.x; acc[et][1] = b4.y; acc[et][2] = b4.z; acc[et][3] = b4.w;
        }
#pragma unroll
        for (int et = 0; et < 4; ++et) {
            const int e = et * 16 + l15;
            const short8 bh0 = *(const short8*)(pEhi + e * LDK + quad * 8);
            const short8 bh1 = *(const short8*)(pEhi + e * LDK + 32 + quad * 8);
            const short8 bl0 = *(const short8*)(pElo + e * LDK + quad * 8);
            const short8 bl1 = *(const short8*)(pElo + e * LDK + 32 + quad * 8);
            acc[et] = chain6(w, bh0, bh1, bl0, bl1, acc[et]);
        }
#pragma unroll
        for (int et = 0; et < 4; ++et) {
            const int e = et * 16 + l15;
            e0s[et] = acc[et];
            union { unsigned short u[4]; short4v v; } h, l;
#pragma unroll
            for (int r = 0; r < 4; ++r) split2(acc[et][r], h.u[r], l.u[r]);
            *(short4v*)(pHhi + e * LDK + f0) = h.v;
            *(short4v*)(pHlo + e * LDK + f0) = l.v;
        }
    }
    __syncthreads();

    // ===== phase3: t1 = relu(e0 @ W1e + Ps[src] + Pd[dst] + pb1) -> pE
    {
        short8 w[2][2];
        load_wf(wt + 1 * 8192, ft, l15, quad, w);
#pragma unroll
        for (int et = 0; et < 4; ++et) acc[et] = zz;
#pragma unroll
        for (int et = 0; et < 4; ++et) {
            const int e = et * 16 + l15;
            const short8 bh0 = *(const short8*)(pHhi + e * LDK + quad * 8);
            const short8 bh1 = *(const short8*)(pHhi + e * LDK + 32 + quad * 8);
            const short8 bl0 = *(const short8*)(pHlo + e * LDK + quad * 8);
            const short8 bl1 = *(const short8*)(pHlo + e * LDK + 32 + quad * 8);
            acc[et] = chain6(w, bh0, bh1, bl0, bl1, acc[et]);
        }
        const float4 b4 = *(const float4*)(pb1 + f0);
#pragma unroll
        for (int et = 0; et < 4; ++et) {
            const int e = et * 16 + l15;
            const float4 ps = *(const float4*)(Ps + (size_t)srcs[et] * HH + f0);
            const float4 pd = *(const float4*)(Pd + (size_t)dsts[et] * HH + f0);
            union { unsigned short u[4]; short4v v; } h, l;
            split2(fmaxf(acc[et][0] + ps.x + pd.x + b4.x, 0.f), h.u[0], l.u[0]);
            split2(fmaxf(acc[et][1] + ps.y + pd.y + b4.y, 0.f), h.u[1], l.u[1]);
            split2(fmaxf(acc[et][2] + ps.z + pd.z + b4.z, 0.f), h.u[2], l.u[2]);
            split2(fmaxf(acc[et][3] + ps.w + pd.w + b4.w, 0.f), h.u[3], l.u[3]);
            *(short4v*)(pEhi + e * LDK + f0) = h.v;
            *(short4v*)(pElo + e * LDK + f0) = l.v;
        }
    }
    __syncthreads();

    // ===== phase4: e1 = e0(regs) + t1 @ W2e + pb2 -> pH
    {
        short8 w[2][2];
        load_wf(wt + 2 * 8192, ft, l15, quad, w);
#pragma unroll
        for (int et = 0; et < 4; ++et) acc[et] = zz;
#pragma unroll
        for (int et = 0; et < 4; ++et) {
            const int e = et * 16 + l15;
            const short8 bh0 = *(const short8*)(pEhi + e * LDK + quad * 8);
            const short8 bh1 = *(const short8*)(pEhi + e * LDK + 32 + quad * 8);
            const short8 bl0 = *(const short8*)(pElo + e * LDK + quad * 8);
            const short8 bl1 = *(const short8*)(pElo + e * LDK + 32 + quad * 8);
            acc[et] = chain6(w, bh0, bh1, bl0, bl1, acc[et]);
        }
        const float4 b4 = *(const float4*)(pb2 + f0);
#pragma unroll
        for (int et = 0; et < 4; ++et) {
            const int e = et * 16 + l15;
            union { unsigned short u[4]; short4v v; } h, l;
            split2(acc[et][0] + e0s[et][0] + b4.x, h.u[0], l.u[0]);
            split2(acc[et][1] + e0s[et][1] + b4.y, h.u[1], l.u[1]);
            split2(acc[et][2] + e0s[et][2] + b4.z, h.u[2], l.u[2]);
            split2(acc[et][3] + e0s[et][3] + b4.w, h.u[3], l.u[3]);
            *(short4v*)(pHhi + e * LDK + f0) = h.v;
            *(short4v*)(pHlo + e * LDK + f0) = l.v;
        }
    }
    __syncthreads();

    // ---- store pH -> global planes at SORTED positions
    {
        const int row = t >> 2, q = t & 3;
        const long go = (eBase + row) * HH + q * 8;
        const int lo = row * LDK + q * 8;
        *(uint4*)(ehi + go)      = *(const uint4*)(pHhi + lo);
        *(uint4*)(ehi + go + 32) = *(const uint4*)(pHhi + lo + 32);
        *(uint4*)(elo + go)      = *(const uint4*)(pHlo + lo);
        *(uint4*)(elo + go + 32) = *(const uint4*)(pHlo + lo + 32);
    }
}

// ---------------- K4: layer-1 edge MLP (MFMA, sorted, planes in place) ----------------

__global__ __launch_bounds__(256, 4) void k_edge_l1(
    const int* __restrict__ srcs_s, const int* __restrict__ dsts_s,
    const float* __restrict__ Ps, const float* __restrict__ Pd,
    const unsigned short* __restrict__ wt,
    const float* __restrict__ pb1, const float* __restrict__ pb2,
    unsigned short* __restrict__ ehi, unsigned short* __restrict__ elo)
{
    __shared__ unsigned short pEhi[EPB * LDK], pElo[EPB * LDK];
    __shared__ unsigned short pHhi[EPB * LDK], pHlo[EPB * LDK];

    const int t = threadIdx.x;
    const int lane = t & 63, ft = t >> 6;
    const int quad = lane >> 4, l15 = lane & 15;
    const int f0 = ft * 16 + quad * 4;
    const long eBase = (long)blockIdx.x * EPB;

    {
        const int row = t >> 2, q = t & 3;
        const long go = (eBase + row) * HH + q * 8;
        const int lo = row * LDK + q * 8;
        *(uint4*)(pEhi + lo)      = *(const uint4*)(ehi + go);
        *(uint4*)(pEhi + lo + 32) = *(const uint4*)(ehi + go + 32);
        *(uint4*)(pElo + lo)      = *(const uint4*)(elo + go);
        *(uint4*)(pElo + lo + 32) = *(const uint4*)(elo + go + 32);
    }
    int srcs[4], dsts[4];
#pragma unroll
    for (int et = 0; et < 4; ++et) {
        const long p = eBase + et * 16 + l15;
        srcs[et] = srcs_s[p];
        dsts[et] = dsts_s[p];
    }
    __syncthreads();

    f32x4 acc[4];
    const f32x4 zz = {0.f, 0.f, 0.f, 0.f};

    // ===== t1 = relu(e1 @ W1e + Ps[src] + Pd[dst] + pb1) -> pH
    {
        short8 w[2][2];
        load_wf(wt + 3 * 8192, ft, l15, quad, w);
#pragma unroll
        for (int et = 0; et < 4; ++et) acc[et] = zz;
#pragma unroll
        for (int et = 0; et < 4; ++et) {
            const int e = et * 16 + l15;
            const short8 bh0 = *(const short8*)(pEhi + e * LDK + quad * 8);
            const short8 bh1 = *(const short8*)(pEhi + e * LDK + 32 + quad * 8);
            const short8 bl0 = *(const short8*)(pElo + e * LDK + quad * 8);
            const short8 bl1 = *(const short8*)(pElo + e * LDK + 32 + quad * 8);
            acc[et] = chain6(w, bh0, bh1, bl0, bl1, acc[et]);
        }
        const float4 b4 = *(const float4*)(pb1 + f0);
#pragma unroll
        for (int et = 0; et < 4; ++et) {
            const int e = et * 16 + l15;
            const float4 ps = *(const float4*)(Ps + (size_t)srcs[et] * HH + f0);
            const float4 pd = *(const float4*)(Pd + (size_t)dsts[et] * HH + f0);
            union { unsigned short u[4]; short4v v; } h, l;
            split2(fmaxf(acc[et][0] + ps.x + pd.x + b4.x, 0.f), h.u[0], l.u[0]);
            split2(fmaxf(acc[et][1] + ps.y + pd.y + b4.y, 0.f), h.u[1], l.u[1]);
            split2(fmaxf(acc[et][2] + ps.z + pd.z + b4.z, 0.f), h.u[2], l.u[2]);
            split2(fmaxf(acc[et][3] + ps.w + pd.w + b4.w, 0.f), h.u[3], l.u[3]);
            *(short4v*)(pHhi + e * LDK + f0) = h.v;
            *(short4v*)(pHlo + e * LDK + f0) = l.v;
        }
    }
    __syncthreads();

    // ===== e2 = e1(pE residual, own cells) + t1 @ W2e + pb2 -> pE in place
    {
        short8 w[2][2];
        load_wf(wt + 4 * 8192, ft, l15, quad, w);
#pragma unroll
        for (int et = 0; et < 4; ++et) acc[et] = zz;
#pragma unroll
        for (int et = 0; et < 4; ++et) {
            const int e = et * 16 + l15;
            const short8 bh0 = *(const short8*)(pHhi + e * LDK + quad * 8);
            const short8 bh1 = *(const short8*)(pHhi + e * LDK + 32 + quad * 8);
            const short8 bl0 = *(const short8*)(pHlo + e * LDK + quad * 8);
            const short8 bl1 = *(const short8*)(pHlo + e * LDK + 32 + quad * 8);
            acc[et] = chain6(w, bh0, bh1, bl0, bl1, acc[et]);
        }
        const float4 b4 = *(const float4*)(pb2 + f0);
#pragma unroll
        for (int et = 0; et < 4; ++et) {
            const int e = et * 16 + l15;
            const short4v hv = *(const short4v*)(pEhi + e * LDK + f0);
            const short4v lv = *(const short4v*)(pElo + e * LDK + f0);
            float v[4];
            v[0] = acc[et][0] + bf2f((unsigned short)hv[0]) + bf2f((unsigned short)lv[0]) + b4.x;
            v[1] = acc[et][1] + bf2f((unsigned short)hv[1]) + bf2f((unsigned short)lv[1]) + b4.y;
            v[2] = acc[et][2] + bf2f((unsigned short)hv[2]) + bf2f((unsigned short)lv[2]) + b4.z;
            v[3] = acc[et][3] + bf2f((unsigned short)hv[3]) + bf2f((unsigned short)lv[3]) + b4.w;
            union { unsigned short u[4]; short4v v4; } h, l;
#pragma unroll
            for (int r = 0; r < 4; ++r) split2(v[r], h.u[r], l.u[r]);
            *(short4v*)(pEhi + e * LDK + f0) = h.v4;   // same thread read these cells above
            *(short4v*)(pElo + e * LDK + f0) = l.v4;
        }
    }
    __syncthreads();
    {
        const int row = t >> 2, q = t & 3;
        const long go = (eBase + row) * HH + q * 8;
        const int lo = row * LDK + q * 8;
        *(uint4*)(ehi + go)      = *(const uint4*)(pEhi + lo);
        *(uint4*)(ehi + go + 32) = *(const uint4*)(pEhi + lo + 32);
        *(uint4*)(elo + go)      = *(const uint4*)(pElo + lo);
        *(uint4*)(elo + go + 32) = *(const uint4*)(pElo + lo + 32);
    }
}

// ================= fp32 VALU node-side kernels =================

__device__ __forceinline__ void copy_w64(float* dst, const float* __restrict__ src, int t) {
    float4* d4 = (float4*)dst;
    const float4* s4 = (const float4*)src;
#pragma unroll
    for (int i = 0; i < 4; ++i) d4[t + 256 * i] = s4[t + 256 * i];
}

template <int KLEN>
__device__ __forceinline__ void gemm_tile(const float* A, const float* W,
                                          int r0, int c0, float (&acc)[4][4]) {
#pragma unroll 16
    for (int k = 0; k < KLEN; ++k) {
        const float4 a4 = *(const float4*)(A + k * LDA + r0);
        const float4 b4 = *(const float4*)(W + k * HH + c0);
        const float a[4] = {a4.x, a4.y, a4.z, a4.w};
        const float b[4] = {b4.x, b4.y, b4.z, b4.w};
#pragma unroll
        for (int i = 0; i < 4; ++i)
#pragma unroll
            for (int j = 0; j < 4; ++j)
                acc[i][j] = fmaf(a[i], b[j], acc[i][j]);
    }
}

__device__ __forceinline__ void init_acc_bias(float (&acc)[4][4], const float* __restrict__ b, int c0) {
    const float4 b4 = *(const float4*)(b + c0);
    const float bv[4] = {b4.x, b4.y, b4.z, b4.w};
#pragma unroll
    for (int i = 0; i < 4; ++i)
#pragma unroll
        for (int j = 0; j < 4; ++j) acc[i][j] = bv[j];
}

__device__ __forceinline__ void init_acc_zero(float (&acc)[4][4]) {
#pragma unroll
    for (int i = 0; i < 4; ++i)
#pragma unroll
        for (int j = 0; j < 4; ++j) acc[i][j] = 0.f;
}

__device__ __forceinline__ void relu_acc(float (&acc)[4][4]) {
#pragma unroll
    for (int i = 0; i < 4; ++i)
#pragma unroll
        for (int j = 0; j < 4; ++j) acc[i][j] = fmaxf(acc[i][j], 0.f);
}

__device__ __forceinline__ void store_T(float* lds, int r0, int c0, const float (&acc)[4][4]) {
#pragma unroll
    for (int j = 0; j < 4; ++j) {
        float4 v = make_float4(acc[0][j], acc[1][j], acc[2][j], acc[3][j]);
        *(float4*)(lds + (c0 + j) * LDA + r0) = v;
    }
}

__device__ __forceinline__ void stage_T64(float* lds, const float* g,
                                          long rowBase, int t, int nValid) {
    const int row = t >> 2, q = t & 3;
    const bool valid = row < nValid;
#pragma unroll
    for (int i = 0; i < 4; ++i) {
        const int col = i * 16 + q * 4;
        float4 v = make_float4(0.f, 0.f, 0.f, 0.f);
        if (valid) v = *(const float4*)(g + (size_t)(rowBase + row) * HH + col);
        lds[(col + 0) * LDA + row] = v.x;
        lds[(col + 1) * LDA + row] = v.y;
        lds[(col + 2) * LDA + row] = v.z;
        lds[(col + 3) * LDA + row] = v.w;
    }
}

__global__ __launch_bounds__(256, 3) void k_encode_nodes(
    const float* __restrict__ x,
    const float* __restrict__ wn1, const float* __restrict__ bn1,
    const float* __restrict__ wn2, const float* __restrict__ bn2,
    const float* __restrict__ w1s, const float* __restrict__ w1d,
    float* __restrict__ x_h, float* __restrict__ Ps, float* __restrict__ Pd)
{
    __shared__ float ldsA[HH * LDA];
    __shared__ float ldsT[HH * LDA];
    __shared__ float Wbuf[HH * HH];
    __shared__ float Wn1s[8 * HH];

    const int t = threadIdx.x;
    const int tc = t & 15, tr = t >> 4;
    const int r0 = tr * 4, c0 = tc * 4;
    const int nodeBase = blockIdx.x * 64;

    if (t < 64) {
        const int row = nodeBase + t;
        float4 a0 = make_float4(0.f, 0.f, 0.f, 0.f), a1 = a0;
        if (row < NN) {
            a0 = *(const float4*)(x + (size_t)row * 8);
            a1 = *(const float4*)(x + (size_t)row * 8 + 4);
        }
        ldsA[0 * LDA + t] = a0.x; ldsA[1 * LDA + t] = a0.y;
        ldsA[2 * LDA + t] = a0.z; ldsA[3 * LDA + t] = a0.w;
        ldsA[4 * LDA + t] = a1.x; ldsA[5 * LDA + t] = a1.y;
        ldsA[6 * LDA + t] = a1.z; ldsA[7 * LDA + t] = a1.w;
    }
    Wn1s[t] = wn1[t];
    Wn1s[t + 256] = wn1[t + 256];
    copy_w64(Wbuf, wn2, t);
    __syncthreads();

    float acc[4][4];
    init_acc_bias(acc, bn1, c0);
    gemm_tile<8>(ldsA, Wn1s, r0, c0, acc);
    relu_acc(acc);
    store_T(ldsT, r0, c0, acc);
    __syncthreads();

    init_acc_bias(acc, bn2, c0);
    gemm_tile<64>(ldsT, Wbuf, r0, c0, acc);
#pragma unroll
    for (int i = 0; i < 4; ++i) {
        if (nodeBase + r0 + i < NN) {
            float4 v = make_float4(acc[i][0], acc[i][1], acc[i][2], acc[i][3]);
            *(float4*)(x_h + (size_t)(nodeBase + r0 + i) * HH + c0) = v;
        }
    }
    store_T(ldsA, r0, c0, acc);
    __syncthreads();
    copy_w64(Wbuf, w1s, t);
    __syncthreads();

    init_acc_zero(acc);
    gemm_tile<64>(ldsA, Wbuf, r0, c0, acc);
#pragma unroll
    for (int i = 0; i < 4; ++i) {
        if (nodeBase + r0 + i < NN) {
            float4 v = make_float4(acc[i][0], acc[i][1], acc[i][2], acc[i][3]);
            *(float4*)(Ps + (size_t)(nodeBase + r0 + i) * HH + c0) = v;
        }
    }
    __syncthreads();
    copy_w64(Wbuf, w1d, t);
    __syncthreads();

    init_acc_zero(acc);
    gemm_tile<64>(ldsA, Wbuf, r0, c0, acc);
#pragma unroll
    for (int i = 0; i < 4; ++i) {
        if (nodeBase + r0 + i < NN) {
            float4 v = make_float4(acc[i][0], acc[i][1], acc[i][2], acc[i][3]);
            *(float4*)(Pd + (size_t)(nodeBase + r0 + i) * HH + c0) = v;
        }
    }
}

// NOTE: agg aliases Ps. Safe: each block reads agg rows [base,base+64) into LDS
// before its first barrier; writes Ps rows in same range only later. No
// cross-block row sharing. __restrict__ dropped on aliased pointers.
__global__ __launch_bounds__(256, 3) void k_node_l0(
    const float* agg,
    const float* __restrict__ w1nx, const float* __restrict__ w1na,
    const float* __restrict__ nb1,
    const float* __restrict__ w2n, const float* __restrict__ nb2,
    const float* __restrict__ w1s_next, const float* __restrict__ w1d_next,
    float* x_h, float* Ps, float* __restrict__ Pd)
{
    __shared__ float ldsA[HH * LDA];
    __shared__ float ldsB[HH * LDA];
    __shared__ float Wbuf[HH * HH];

    const int t = threadIdx.x;
    const int tc = t & 15, tr = t >> 4;
    const int r0 = tr * 4, c0 = tc * 4;
    const int nodeBase = blockIdx.x * 64;
    const int nValid = min(64, NN - nodeBase);

    stage_T64(ldsA, x_h, nodeBase, t, nValid);
    stage_T64(ldsB, agg, nodeBase, t, nValid);
    copy_w64(Wbuf, w1nx, t);
    __syncthreads();

    float acc[4][4];
    init_acc_bias(acc, nb1, c0);
    gemm_tile<64>(ldsA, Wbuf, r0, c0, acc);
    __syncthreads();
    copy_w64(Wbuf, w1na, t);
    __syncthreads();
    gemm_tile<64>(ldsB, Wbuf, r0, c0, acc);
    relu_acc(acc);
    __syncthreads();
    store_T(ldsB, r0, c0, acc);
    copy_w64(Wbuf, w2n, t);
    __syncthreads();

    {
        const float4 b4 = *(const float4*)(nb2 + c0);
        const float bv[4] = {b4.x, b4.y, b4.z, b4.w};
#pragma unroll
        for (int j = 0; j < 4; ++j) {
            const float4 xc = *(const float4*)(ldsA + (c0 + j) * LDA + r0);
            acc[0][j] = xc.x + bv[j];
            acc[1][j] = xc.y + bv[j];
            acc[2][j] = xc.z + bv[j];
            acc[3][j] = xc.w + bv[j];
        }
    }
    gemm_tile<64>(ldsB, Wbuf, r0, c0, acc);
#pragma unroll
    for (int i = 0; i < 4; ++i) {
        if (r0 + i < nValid) {
            float4 v = make_float4(acc[i][0], acc[i][1], acc[i][2], acc[i][3]);
            *(float4*)(x_h + (size_t)(nodeBase + r0 + i) * HH + c0) = v;
        }
    }
    __syncthreads();
    store_T(ldsA, r0, c0, acc);
    copy_w64(Wbuf, w1s_next, t);
    __syncthreads();

    init_acc_zero(acc);
    gemm_tile<64>(ldsA, Wbuf, r0, c0, acc);
#pragma unroll
    for (int i = 0; i < 4; ++i) {
        if (r0 + i < nValid) {
            float4 v = make_float4(acc[i][0], acc[i][1], acc[i][2], acc[i][3]);
            *(float4*)(Ps + (size_t)(nodeBase + r0 + i) * HH + c0) = v;
        }
    }
    __syncthreads();
    copy_w64(Wbuf, w1d_next, t);
    __syncthreads();

    init_acc_zero(acc);
    gemm_tile<64>(ldsA, Wbuf, r0, c0, acc);
#pragma unroll
    for (int i = 0; i < 4; ++i) {
        if (r0 + i < nValid) {
            float4 v = make_float4(acc[i][0], acc[i][1], acc[i][2], acc[i][3]);
            *(float4*)(Pd + (size_t)(nodeBase + r0 + i) * HH + c0) = v;
        }
    }
}

__global__ __launch_bounds__(256, 3) void k_node_l1_dec(
    const float* agg,   // aliases Ps buffer; read-only here
    const float* __restrict__ w1nx, const float* __restrict__ w1na,
    const float* __restrict__ nb1,
    const float* __restrict__ w2n, const float* __restrict__ nb2,
    const float* __restrict__ dw1, const float* __restrict__ db1,
    const float* __restrict__ dw2, const float* __restrict__ db2,
    const float* __restrict__ x_h, float* __restrict__ out)
{
    __shared__ float ldsA[HH * LDA];
    __shared__ float ldsB[HH * LDA];
    __shared__ float Wbuf[HH * HH];

    const int t = threadIdx.x;
    const int tc = t & 15, tr = t >> 4;
    const int r0 = tr * 4, c0 = tc * 4;
    const int nodeBase = blockIdx.x * 64;
    const int nValid = min(64, NN - nodeBase);

    stage_T64(ldsA, x_h, nodeBase, t, nValid);
    stage_T64(ldsB, agg, nodeBase, t, nValid);
    copy_w64(Wbuf, w1nx, t);
    __syncthreads();

    float acc[4][4];
    init_acc_bias(acc, nb1, c0);
    gemm_tile<64>(ldsA, Wbuf, r0, c0, acc);
    __syncthreads();
    copy_w64(Wbuf, w1na, t);
    __syncthreads();
    gemm_tile<64>(ldsB, Wbuf, r0, c0, acc);
    relu_acc(acc);
    __syncthreads();
    store_T(ldsB, r0, c0, acc);
    copy_w64(Wbuf, w2n, t);
    __syncthreads();

    {
        const float4 b4 = *(const float4*)(nb2 + c0);
        const float bv[4] = {b4.x, b4.y, b4.z, b4.w};
#pragma unroll
        for (int j = 0; j < 4; ++j) {
            const float4 xc = *(const float4*)(ldsA + (c0 + j) * LDA + r0);
            acc[0][j] = xc.x + bv[j];
            acc[1][j] = xc.y + bv[j];
            acc[2][j] = xc.z + bv[j];
            acc[3][j] = xc.w + bv[j];
        }
    }
    gemm_tile<64>(ldsB, Wbuf, r0, c0, acc);
    __syncthreads();
    store_T(ldsA, r0, c0, acc);
    copy_w64(Wbuf, dw1, t);
    __syncthreads();

    init_acc_bias(acc, db1, c0);
    gemm_tile<64>(ldsA, Wbuf, r0, c0, acc);
    relu_acc(acc);
    __syncthreads();
    store_T(ldsB, r0, c0, acc);
    if (t < 192) {
        Wbuf[t] = dw2[t];
        Wbuf[t + 192] = dw2[t + 192];
    }
    __syncthreads();

    if (t < 64) {
        float o[6];
#pragma unroll
        for (int c = 0; c < 6; ++c) o[c] = db2[c];
#pragma unroll 8
        for (int k = 0; k < 64; ++k) {
            const float a = ldsB[k * LDA + t];
#pragma unroll
            for (int c = 0; c < 6; ++c) o[c] = fmaf(a, Wbuf[k * 6 + c], o[c]);
        }
        if (t < nValid) {
            float* op = out + (size_t)(nodeBase + t) * 6;
#pragma unroll
            for (int c = 0; c < 6; ++c) op[c] = o[c];
        }
    }
}

// ---------------- launcher ----------------

extern "C" void kernel_launch(void* const* d_in, const int* in_sizes, int n_in,
                              void* d_out, int out_size, void* d_ws, size_t ws_size,
                              hipStream_t stream) {
    const float* x        = (const float*)d_in[0];
    const float* eattr    = (const float*)d_in[1];
    const int*   eidx     = (const int*)d_in[2];
    const float* enc_n_w1 = (const float*)d_in[3];
    const float* enc_n_b1 = (const float*)d_in[4];
    const float* enc_n_w2 = (const float*)d_in[5];
    const float* enc_n_b2 = (const float*)d_in[6];
    const float* enc_e_w1 = (const float*)d_in[7];
    const float* enc_e_b1 = (const float*)d_in[8];
    const float* enc_e_w2 = (const float*)d_in[9];
    const float* enc_e_b2 = (const float*)d_in[10];
    const float* pe_w1    = (const float*)d_in[11];  // [2,192,64]
    const float* pe_b1    = (const float*)d_in[12];  // [2,64]
    const float* pe_w2    = (const float*)d_in[13];  // [2,64,64]
    const float* pe_b2    = (const float*)d_in[14];  // [2,64]
    const float* pn_w1    = (const float*)d_in[15];  // [2,128,64]
    const float* pn_b1    = (const float*)d_in[16];
    const float* pn_w2    = (const float*)d_in[17];  // [2,64,64]
    const float* pn_b2    = (const float*)d_in[18];
    const float* dw1      = (const float*)d_in[19];
    const float* db1      = (const float*)d_in[20];
    const float* dw2      = (const float*)d_in[21];
    const float* db2      = (const float*)d_in[22];
    float* out = (float*)d_out;

    // ws layout: x_h | Ps(=agg) | Pd | ehi | elo | off | deg/cur | csr | srcs_s | dsts_s
    // 38.4 + 204.8 + 0.4 + 3.2 + 3.2 + 3.2 = 253.2MB (<= 256MB proven available)
    const size_t NNHH = (size_t)NN * HH;
    float* ws  = (float*)d_ws;
    float* x_h = ws;
    float* Ps  = ws + NNHH;
    float* agg = Ps;                       // aliased; see k_node_l0 note
    float* Pd  = ws + 2 * NNHH;
    unsigned short* ehi = (unsigned short*)(ws + 3 * NNHH);
    unsigned short* elo = ehi + (size_t)EE * HH;
    unsigned* off = (unsigned*)(elo + (size_t)EE * HH);   // NN+1
    unsigned* deg = off + (NN + 1);                       // NN, reused as cursor
    int* csr    = (int*)(deg + NN);                       // EE
    int* srcs_s = csr + EE;                               // EE
    int* dsts_s = srcs_s + EE;                            // EE

    // converted-weight scratch in d_out (overwritten by decoder at the end)
    unsigned short* wt = (unsigned short*)d_out;

    const int nodeBlocks = (NN + 63) / 64;   // 782
    const int edgeBlocks = EE / EPB;         // 12500
    const int eScal      = (EE + 255) / 256; // 3125

    hipMemsetAsync(deg, 0, (size_t)NN * sizeof(unsigned), stream);

    k_conv_w<<<88, 256, 0, stream>>>(
        enc_e_w2, pe_w1, pe_w2,
        pe_w1 + 192 * 64, pe_w2 + 64 * 64,
        enc_e_w1, wt);

    k_deg<<<eScal, 256, 0, stream>>>(eidx, deg);
    k_scan<<<1, 1024, 0, stream>>>(deg, off);
    k_fill<<<eScal, 256, 0, stream>>>(eidx, deg, csr, srcs_s, dsts_s);

    k_encode_nodes<<<nodeBlocks, 256, 0, stream>>>(
        x, enc_n_w1, enc_n_b1, enc_n_w2, enc_n_b2,
        pe_w1 + 64 * 64,        // W1s (l0)
        pe_w1 + 128 * 64,       // W1d (l0)
        x_h, Ps, Pd);

    k_edge_l0<<<edgeBlocks, 256, 0, stream>>>(
        eattr, csr, srcs_s, dsts_s, Ps, Pd,
        enc_e_b1, enc_e_b2,
        wt, pe_b1, pe_b2,
        ehi, elo);

    k_agg<<<(NN + 3) / 4, 256, 0, stream>>>(off, ehi, elo, agg);

    k_node_l0<<<nodeBlocks, 256, 0, stream>>>(
        agg,
        pn_w1, pn_w1 + 64 * 64, pn_b1,
        pn_w2, pn_b2,
        pe_w1 + 192 * 64 + 64 * 64,   // layer-1 W1s
        pe_w1 + 192 * 64 + 128 * 64,  // layer-1 W1d
        x_h, Ps, Pd);

    k_edge_l1<<<edgeBlocks, 256, 0, stream>>>(
        srcs_s, dsts_s, Ps, Pd,
        wt, pe_b1 + 64, pe_b2 + 64,
        ehi, elo);

    k_agg<<<(NN + 3) / 4, 256, 0, stream>>>(off, ehi, elo, agg);

    k_node_l1_dec<<<nodeBlocks, 256, 0, stream>>>(
        agg,
        pn_w1 + 128 * 64, pn_w1 + 128 * 64 + 64 * 64, pn_b1 + 64,
        pn_w2 + 64 * 64, pn_b2 + 64,
        dw1, db1, dw2, db2,
        x_h, out);
}

// Round 6
// 694.715 us; speedup vs baseline: 2.4274x; 1.0728x over previous
//
#include <hip/hip_runtime.h>

// GNN: N=50000 nodes, E=800000 edges, H=64, L=2.
// R6: node-side kernels ported to MFMA split-bf16 (same machinery as edges);
// e-planes packed as uint (hi<<16|lo) -> k_agg 1 dword load/lane, edge_l1
// plane load halved. wt moved to ws (d_out raced with decoder).
// Pipeline: conv_w | CSR(deg/scan/fill) | encode | edge_l0 | agg | node_l0 |
//           edge_l1 | agg | node_l1+dec.

#define NN 50000
#define EE 800000
#define HH 64
#define LDK 72   // bf16 plane leading dim (144 B row)
#define EPB 64   // rows (edges or nodes) per block

typedef short short8 __attribute__((ext_vector_type(8)));
typedef short short4v __attribute__((ext_vector_type(4)));
typedef float f32x4 __attribute__((ext_vector_type(4)));

#define MFMA __builtin_amdgcn_mfma_f32_16x16x32_bf16

// wt slots (each 8192 ushorts: 4096 hi + 4096 lo, layout [f][k])
#define S_WE2   0
#define S_W1E0  1
#define S_W2E0  2
#define S_W1E1  3
#define S_W2E1  4
#define S_WN2   5
#define S_W1S0  6
#define S_W1D0  7
#define S_W1S1  8
#define S_W1D1  9
#define S_W1NX0 10
#define S_W1NA0 11
#define S_W2N0  12
#define S_W1NX1 13
#define S_W1NA1 14
#define S_W2N1  15
#define S_DW1   16
#define OFF_WE1 (17*8192)          // [f][32], K=4 padded
#define OFF_WN1 (17*8192+4096)     // [f][32], K=8 padded
#define WT_USHORTS (17*8192+8192)

// ---------------- bf16 helpers ----------------

__device__ __forceinline__ void split2(float x, unsigned short& h, unsigned short& l) {
    union { float f; unsigned u; } a, hf, b;
    a.f = x;
    const unsigned hb = (a.u + 0x7FFFu + ((a.u >> 16) & 1u)) >> 16;  // RNE hi
    hf.u = hb << 16;
    b.f = x - hf.f;                  // exact
    h = (unsigned short)hb;
    l = (unsigned short)(b.u >> 16); // truncated lo: err <= 2^-16 |x|
}

__device__ __forceinline__ float bf2f(unsigned short s) {
    union { unsigned u; float f; } a; a.u = ((unsigned)s) << 16; return a.f;
}

__device__ __forceinline__ float uph(unsigned u) {
    union { unsigned x; float f; } a; a.x = u & 0xFFFF0000u; return a.f;
}
__device__ __forceinline__ float upl(unsigned u) {
    union { unsigned x; float f; } a; a.x = u << 16; return a.f;
}

// A-frags for one 16-feature slice of a 64x64 weight: [chunk][plane]
__device__ __forceinline__ void load_wf(const unsigned short* __restrict__ wm,
                                        int ft, int l15, int quad, short8 (&w)[2][2]) {
#pragma unroll
    for (int c = 0; c < 2; ++c) {
        const int el = (ft * 16 + l15) * 64 + c * 32 + quad * 8;
        w[c][0] = *(const short8*)(wm + el);
        w[c][1] = *(const short8*)(wm + 4096 + el);
    }
}

// D += Ah*Bh + Al*Bh + Ah*Bl over K=64 (2 chunks)
__device__ __forceinline__ f32x4 chain6(const short8 (&w)[2][2],
                                        short8 bh0, short8 bh1,
                                        short8 bl0, short8 bl1, f32x4 a) {
    a = MFMA(w[0][0], bh0, a, 0, 0, 0);
    a = MFMA(w[1][0], bh1, a, 0, 0, 0);
    a = MFMA(w[0][1], bh0, a, 0, 0, 0);
    a = MFMA(w[1][1], bh1, a, 0, 0, 0);
    a = MFMA(w[0][0], bl0, a, 0, 0, 0);
    a = MFMA(w[1][0], bl1, a, 0, 0, 0);
    return a;
}

// acc[et] += W @ planes (K=64), B from LDS planes
__device__ __forceinline__ void gemm_planes(const unsigned short* pHi, const unsigned short* pLo,
                                            const short8 (&w)[2][2], int l15, int quad,
                                            f32x4 (&acc)[4]) {
#pragma unroll
    for (int et = 0; et < 4; ++et) {
        const int e = et * 16 + l15;
        const short8 bh0 = *(const short8*)(pHi + e * LDK + quad * 8);
        const short8 bh1 = *(const short8*)(pHi + e * LDK + 32 + quad * 8);
        const short8 bl0 = *(const short8*)(pLo + e * LDK + quad * 8);
        const short8 bl1 = *(const short8*)(pLo + e * LDK + 32 + quad * 8);
        acc[et] = chain6(w, bh0, bh1, bl0, bl1, acc[et]);
    }
}

__device__ __forceinline__ void set_bias(f32x4 (&acc)[4], const float* __restrict__ b, int f0) {
    const float4 b4 = *(const float4*)(b + f0);
#pragma unroll
    for (int et = 0; et < 4; ++et) {
        acc[et][0] = b4.x; acc[et][1] = b4.y; acc[et][2] = b4.z; acc[et][3] = b4.w;
    }
}

__device__ __forceinline__ void set_zero(f32x4 (&acc)[4]) {
#pragma unroll
    for (int et = 0; et < 4; ++et)
#pragma unroll
        for (int r = 0; r < 4; ++r) acc[et][r] = 0.f;
}

__device__ __forceinline__ void relu4(f32x4 (&acc)[4]) {
#pragma unroll
    for (int et = 0; et < 4; ++et)
#pragma unroll
        for (int r = 0; r < 4; ++r) acc[et][r] = fmaxf(acc[et][r], 0.f);
}

__device__ __forceinline__ void store_split_planes(unsigned short* pHi, unsigned short* pLo,
                                                   const f32x4 (&acc)[4], int l15, int f0) {
#pragma unroll
    for (int et = 0; et < 4; ++et) {
        const int e = et * 16 + l15;
        union { unsigned short u[4]; short4v v; } h, l;
#pragma unroll
        for (int r = 0; r < 4; ++r) split2(acc[et][r], h.u[r], l.u[r]);
        *(short4v*)(pHi + e * LDK + f0) = h.v;
        *(short4v*)(pLo + e * LDK + f0) = l.v;
    }
}

// stage fp32 [64][64] tile -> split hi/lo planes; invalid rows zero
__device__ __forceinline__ void stage_split64(unsigned short* pHi, unsigned short* pLo,
                                              const float* g, long rowBase, int t, int nValid) {
    const int row = t >> 2, q = t & 3;
    const bool valid = row < nValid;
#pragma unroll
    for (int i = 0; i < 4; ++i) {
        const int col = q * 16 + i * 4;
        float4 v = make_float4(0.f, 0.f, 0.f, 0.f);
        if (valid) v = *(const float4*)(g + (size_t)(rowBase + row) * HH + col);
        union { unsigned short u[4]; short4v s; } h, l;
        split2(v.x, h.u[0], l.u[0]); split2(v.y, h.u[1], l.u[1]);
        split2(v.z, h.u[2], l.u[2]); split2(v.w, h.u[3], l.u[3]);
        *(short4v*)(pHi + row * LDK + col) = h.s;
        *(short4v*)(pLo + row * LDK + col) = l.s;
    }
}

// ---------------- setup: split all weights, transposed [f][k] ----------------

__global__ void k_conv_w(const float* __restrict__ enc_n_w1, const float* __restrict__ enc_n_w2,
                         const float* __restrict__ enc_e_w1, const float* __restrict__ enc_e_w2,
                         const float* __restrict__ pe_w1, const float* __restrict__ pe_w2,
                         const float* __restrict__ pn_w1, const float* __restrict__ pn_w2,
                         const float* __restrict__ dw1, unsigned short* __restrict__ wt)
{
    const int i = blockIdx.x * 256 + threadIdx.x;
    if (i < 17 * 4096) {
        const int m = i >> 12, r = i & 4095;
        const int f = r & 63, k = r >> 6;
        const float* W;
        switch (m) {
            case S_WE2:   W = enc_e_w2; break;
            case S_W1E0:  W = pe_w1; break;
            case S_W2E0:  W = pe_w2; break;
            case S_W1E1:  W = pe_w1 + 192 * 64; break;
            case S_W2E1:  W = pe_w2 + 64 * 64; break;
            case S_WN2:   W = enc_n_w2; break;
            case S_W1S0:  W = pe_w1 + 64 * 64; break;
            case S_W1D0:  W = pe_w1 + 128 * 64; break;
            case S_W1S1:  W = pe_w1 + 192 * 64 + 64 * 64; break;
            case S_W1D1:  W = pe_w1 + 192 * 64 + 128 * 64; break;
            case S_W1NX0: W = pn_w1; break;
            case S_W1NA0: W = pn_w1 + 64 * 64; break;
            case S_W2N0:  W = pn_w2; break;
            case S_W1NX1: W = pn_w1 + 128 * 64; break;
            case S_W1NA1: W = pn_w1 + 128 * 64 + 64 * 64; break;
            case S_W2N1:  W = pn_w2 + 64 * 64; break;
            default:      W = dw1; break;
        }
        unsigned short h, l; split2(W[r], h, l);    // W[k*64+f]
        wt[m * 8192 + f * 64 + k] = h;
        wt[m * 8192 + 4096 + f * 64 + k] = l;
    } else if (i < 17 * 4096 + 2048) {
        const int r = i - 17 * 4096, f = r >> 5, k = r & 31;
        const float v = (k < 4) ? enc_e_w1[k * 64 + f] : 0.f;
        unsigned short h, l; split2(v, h, l);
        wt[OFF_WE1 + f * 32 + k] = h;
        wt[OFF_WE1 + 2048 + f * 32 + k] = l;
    } else if (i < 17 * 4096 + 4096) {
        const int r = i - 17 * 4096 - 2048, f = r >> 5, k = r & 31;
        const float v = (k < 8) ? enc_n_w1[k * 64 + f] : 0.f;
        unsigned short h, l; split2(v, h, l);
        wt[OFF_WN1 + f * 32 + k] = h;
        wt[OFF_WN1 + 2048 + f * 32 + k] = l;
    }
}

// ---------------- CSR build ----------------

__global__ void k_deg(const int* __restrict__ eidx, unsigned* __restrict__ deg) {
    const int e = blockIdx.x * 256 + threadIdx.x;
    if (e < EE) atomicAdd(&deg[eidx[EE + e]], 1u);
}

__global__ __launch_bounds__(1024) void k_scan(unsigned* deg, unsigned* __restrict__ off) {
    __shared__ unsigned part[1024];
    const int t = threadIdx.x;
    const int CH = (NN + 1023) / 1024;
    const int s = t * CH, e = s + CH < NN ? s + CH : NN;
    unsigned sum = 0;
    for (int i = s; i < e; ++i) sum += deg[i];
    part[t] = sum;
    __syncthreads();
    for (int d = 1; d < 1024; d <<= 1) {
        unsigned v = (t >= d) ? part[t - d] : 0u;
        __syncthreads();
        if (t >= d) part[t] += v;
        __syncthreads();
    }
    unsigned base = (t > 0) ? part[t - 1] : 0u;
    for (int i = s; i < e; ++i) {
        const unsigned d = deg[i];
        off[i] = base;
        deg[i] = base;          // reuse as fill cursor
        base += d;
    }
    if (t == 1023) off[NN] = part[1023];
}

__global__ void k_fill(const int* __restrict__ eidx, unsigned* __restrict__ cur,
                       int* __restrict__ csr, int* __restrict__ srcs_s,
                       int* __restrict__ dsts_s) {
    const int e = blockIdx.x * 256 + threadIdx.x;
    if (e < EE) {
        const int d = eidx[EE + e];
        const unsigned p = atomicAdd(&cur[d], 1u);
        csr[p] = e;
        srcs_s[p] = eidx[e];
        dsts_s[p] = d;
    }
}

// ---------------- aggregation: sorted planes -> streaming ----------------

__global__ __launch_bounds__(256, 8) void k_agg(
    const unsigned* __restrict__ off, const unsigned* __restrict__ epk,
    float* __restrict__ agg)
{
    const int wv = threadIdx.x >> 6, f = threadIdx.x & 63;
    const int n = blockIdx.x * 4 + wv;
    if (n >= NN) return;
    const unsigned s = off[n], e = off[n + 1];
    float acc = 0.f;
    unsigned j = s;
    for (; j + 4 <= e; j += 4) {
        const size_t b = (size_t)j * HH + f;
        const unsigned u0 = epk[b], u1 = epk[b + 64], u2 = epk[b + 128], u3 = epk[b + 192];
        acc += (uph(u0) + upl(u0)) + (uph(u1) + upl(u1))
             + (uph(u2) + upl(u2)) + (uph(u3) + upl(u3));
    }
    for (; j < e; ++j) {
        const unsigned u = epk[(size_t)j * HH + f];
        acc += uph(u) + upl(u);
    }
    agg[(size_t)n * HH + f] = acc;
}

// ---------------- K2: edge encoder + layer-0 edge MLP ----------------

__global__ __launch_bounds__(256, 4) void k_edge_l0(
    const float* __restrict__ eattr, const int* __restrict__ csr,
    const int* __restrict__ srcs_s, const int* __restrict__ dsts_s,
    const float* __restrict__ Ps, const float* __restrict__ Pd,
    const float* __restrict__ be1, const float* __restrict__ be2,
    const unsigned short* __restrict__ wt,
    const float* __restrict__ pb1, const float* __restrict__ pb2,
    unsigned* __restrict__ epk)
{
    __shared__ unsigned short pHhi[EPB * LDK], pHlo[EPB * LDK];
    __shared__ unsigned short pEhi[EPB * LDK], pElo[EPB * LDK];

    const int t = threadIdx.x;
    const int lane = t & 63, ft = t >> 6;
    const int quad = lane >> 4, l15 = lane & 15;
    const int f0 = ft * 16 + quad * 4;
    const long eBase = (long)blockIdx.x * EPB;

    // stage eattr (gathered via csr): k 0..3 data, 4..31 zero
    {
        const int row = t >> 2, q = t & 3;
        if (q == 0) {
            const int eid = csr[eBase + row];
            const float4 ea = *(const float4*)(eattr + (size_t)eid * 4);
            union { unsigned short u[8]; uint4 v; } H, L;
            split2(ea.x, H.u[0], L.u[0]); split2(ea.y, H.u[1], L.u[1]);
            split2(ea.z, H.u[2], L.u[2]); split2(ea.w, H.u[3], L.u[3]);
#pragma unroll
            for (int j = 4; j < 8; ++j) { H.u[j] = 0; L.u[j] = 0; }
            *(uint4*)(pHhi + row * LDK) = H.v;
            *(uint4*)(pHlo + row * LDK) = L.v;
        } else {
            const uint4 z = {0u, 0u, 0u, 0u};
            *(uint4*)(pHhi + row * LDK + q * 8) = z;
            *(uint4*)(pHlo + row * LDK + q * 8) = z;
        }
    }
    int srcs[4], dsts[4];
#pragma unroll
    for (int et = 0; et < 4; ++et) {
        const long p = eBase + et * 16 + l15;
        srcs[et] = srcs_s[p];
        dsts[et] = dsts_s[p];
    }
    __syncthreads();

    f32x4 acc[4];

    // phase1: h0 = relu(eattr @ We1 + be1) -> pE
    {
        short8 wa[2];
        const int el = (ft * 16 + l15) * 32 + quad * 8;
        wa[0] = *(const short8*)(wt + OFF_WE1 + el);
        wa[1] = *(const short8*)(wt + OFF_WE1 + 2048 + el);
        set_bias(acc, be1, f0);
#pragma unroll
        for (int et = 0; et < 4; ++et) {
            const int e = et * 16 + l15;
            const short8 bh0 = *(const short8*)(pHhi + e * LDK + quad * 8);
            const short8 bl0 = *(const short8*)(pHlo + e * LDK + quad * 8);
            f32x4 a = acc[et];
            a = MFMA(wa[0], bh0, a, 0, 0, 0);
            a = MFMA(wa[1], bh0, a, 0, 0, 0);
            a = MFMA(wa[0], bl0, a, 0, 0, 0);
            acc[et] = a;
        }
        relu4(acc);
        store_split_planes(pEhi, pElo, acc, l15, f0);
    }
    __syncthreads();

    // phase2: e0 = h0 @ We2 + be2 (regs) -> pH
    f32x4 e0s[4];
    {
        short8 w[2][2];
        load_wf(wt + S_WE2 * 8192, ft, l15, quad, w);
        set_bias(acc, be2, f0);
        gemm_planes(pEhi, pElo, w, l15, quad, acc);
#pragma unroll
        for (int et = 0; et < 4; ++et) e0s[et] = acc[et];
        store_split_planes(pHhi, pHlo, acc, l15, f0);
    }
    __syncthreads();

    // phase3: t1 = relu(e0 @ W1e + Ps[src] + Pd[dst] + pb1) -> pE
    {
        short8 w[2][2];
        load_wf(wt + S_W1E0 * 8192, ft, l15, quad, w);
        set_zero(acc);
        gemm_planes(pHhi, pHlo, w, l15, quad, acc);
        const float4 b4 = *(const float4*)(pb1 + f0);
#pragma unroll
        for (int et = 0; et < 4; ++et) {
            const float4 ps = *(const float4*)(Ps + (size_t)srcs[et] * HH + f0);
            const float4 pd = *(const float4*)(Pd + (size_t)dsts[et] * HH + f0);
            acc[et][0] = fmaxf(acc[et][0] + ps.x + pd.x + b4.x, 0.f);
            acc[et][1] = fmaxf(acc[et][1] + ps.y + pd.y + b4.y, 0.f);
            acc[et][2] = fmaxf(acc[et][2] + ps.z + pd.z + b4.z, 0.f);
            acc[et][3] = fmaxf(acc[et][3] + ps.w + pd.w + b4.w, 0.f);
        }
        store_split_planes(pEhi, pElo, acc, l15, f0);
    }
    __syncthreads();

    // phase4: e1 = e0(regs) + t1 @ W2e + pb2 -> pH
    {
        short8 w[2][2];
        load_wf(wt + S_W2E0 * 8192, ft, l15, quad, w);
        set_zero(acc);
        gemm_planes(pEhi, pElo, w, l15, quad, acc);
        const float4 b4 = *(const float4*)(pb2 + f0);
#pragma unroll
        for (int et = 0; et < 4; ++et) {
            acc[et][0] += e0s[et][0] + b4.x;
            acc[et][1] += e0s[et][1] + b4.y;
            acc[et][2] += e0s[et][2] + b4.z;
            acc[et][3] += e0s[et][3] + b4.w;
        }
        store_split_planes(pHhi, pHlo, acc, l15, f0);
    }
    __syncthreads();

    // pack pH -> epk (sorted positions)
    {
        const int row = t >> 2, q = t & 3;
#pragma unroll
        for (int half = 0; half < 2; ++half) {
            const int lo = row * LDK + q * 8 + half * 32;
            const long go = (eBase + row) * HH + q * 8 + half * 32;
            union { unsigned short u[8]; uint4 v; } H, L;
            H.v = *(const uint4*)(pHhi + lo);
            L.v = *(const uint4*)(pHlo + lo);
            union { unsigned u[8]; uint4 v[2]; } o;
#pragma unroll
            for (int i = 0; i < 8; ++i) o.u[i] = ((unsigned)H.u[i] << 16) | L.u[i];
            *(uint4*)(epk + go) = o.v[0];
            *(uint4*)(epk + go + 4) = o.v[1];
        }
    }
}

// ---------------- K4: layer-1 edge MLP ----------------

__global__ __launch_bounds__(256, 4) void k_edge_l1(
    const int* __restrict__ srcs_s, const int* __restrict__ dsts_s,
    const float* __restrict__ Ps, const float* __restrict__ Pd,
    const unsigned short* __restrict__ wt,
    const float* __restrict__ pb1, const float* __restrict__ pb2,
    unsigned* __restrict__ epk)
{
    __shared__ unsigned short pEhi[EPB * LDK], pElo[EPB * LDK];
    __shared__ unsigned short pHhi[EPB * LDK], pHlo[EPB * LDK];

    const int t = threadIdx.x;
    const int lane = t & 63, ft = t >> 6;
    const int quad = lane >> 4, l15 = lane & 15;
    const int f0 = ft * 16 + quad * 4;
    const long eBase = (long)blockIdx.x * EPB;

    // load epk -> deinterleave -> pE
    {
        const int row = t >> 2, q = t & 3;
#pragma unroll
        for (int half = 0; half < 2; ++half) {
            const int lo = row * LDK + q * 8 + half * 32;
            const long go = (eBase + row) * HH + q * 8 + half * 32;
            union { unsigned u[8]; uint4 v[2]; } in;
            in.v[0] = *(const uint4*)(epk + go);
            in.v[1] = *(const uint4*)(epk + go + 4);
            union { unsigned short u[8]; uint4 v; } H, L;
#pragma unroll
            for (int i = 0; i < 8; ++i) {
                H.u[i] = (unsigned short)(in.u[i] >> 16);
                L.u[i] = (unsigned short)(in.u[i] & 0xFFFFu);
            }
            *(uint4*)(pEhi + lo) = H.v;
            *(uint4*)(pElo + lo) = L.v;
        }
    }
    int srcs[4], dsts[4];
#pragma unroll
    for (int et = 0; et < 4; ++et) {
        const long p = eBase + et * 16 + l15;
        srcs[et] = srcs_s[p];
        dsts[et] = dsts_s[p];
    }
    __syncthreads();

    f32x4 acc[4];

    // t1 = relu(e1 @ W1e + Ps[src] + Pd[dst] + pb1) -> pH
    {
        short8 w[2][2];
        load_wf(wt + S_W1E1 * 8192, ft, l15, quad, w);
        set_zero(acc);
        gemm_planes(pEhi, pElo, w, l15, quad, acc);
        const float4 b4 = *(const float4*)(pb1 + f0);
#pragma unroll
        for (int et = 0; et < 4; ++et) {
            const float4 ps = *(const float4*)(Ps + (size_t)srcs[et] * HH + f0);
            const float4 pd = *(const float4*)(Pd + (size_t)dsts[et] * HH + f0);
            acc[et][0] = fmaxf(acc[et][0] + ps.x + pd.x + b4.x, 0.f);
            acc[et][1] = fmaxf(acc[et][1] + ps.y + pd.y + b4.y, 0.f);
            acc[et][2] = fmaxf(acc[et][2] + ps.z + pd.z + b4.z, 0.f);
            acc[et][3] = fmaxf(acc[et][3] + ps.w + pd.w + b4.w, 0.f);
        }
        store_split_planes(pHhi, pHlo, acc, l15, f0);
    }
    __syncthreads();

    // e2 = e1(pE residual, own cells) + t1 @ W2e + pb2 -> pE
    {
        short8 w[2][2];
        load_wf(wt + S_W2E1 * 8192, ft, l15, quad, w);
        set_zero(acc);
        gemm_planes(pHhi, pHlo, w, l15, quad, acc);
        const float4 b4 = *(const float4*)(pb2 + f0);
#pragma unroll
        for (int et = 0; et < 4; ++et) {
            const int e = et * 16 + l15;
            const short4v hv = *(const short4v*)(pEhi + e * LDK + f0);
            const short4v lv = *(const short4v*)(pElo + e * LDK + f0);
            acc[et][0] += bf2f((unsigned short)hv[0]) + bf2f((unsigned short)lv[0]) + b4.x;
            acc[et][1] += bf2f((unsigned short)hv[1]) + bf2f((unsigned short)lv[1]) + b4.y;
            acc[et][2] += bf2f((unsigned short)hv[2]) + bf2f((unsigned short)lv[2]) + b4.z;
            acc[et][3] += bf2f((unsigned short)hv[3]) + bf2f((unsigned short)lv[3]) + b4.w;
        }
        store_split_planes(pEhi, pElo, acc, l15, f0);   // own cells, same thread
    }
    __syncthreads();

    // pack pE -> epk
    {
        const int row = t >> 2, q = t & 3;
#pragma unroll
        for (int half = 0; half < 2; ++half) {
            const int lo = row * LDK + q * 8 + half * 32;
            const long go = (eBase + row) * HH + q * 8 + half * 32;
            union { unsigned short u[8]; uint4 v; } H, L;
            H.v = *(const uint4*)(pEhi + lo);
            L.v = *(const uint4*)(pElo + lo);
            union { unsigned u[8]; uint4 v[2]; } o;
#pragma unroll
            for (int i = 0; i < 8; ++i) o.u[i] = ((unsigned)H.u[i] << 16) | L.u[i];
            *(uint4*)(epk + go) = o.v[0];
            *(uint4*)(epk + go + 4) = o.v[1];
        }
    }
}

// ---------------- K1: node encoder + layer-0 projections (MFMA) ----------------

__global__ __launch_bounds__(256, 4) void k_encode_nodes(
    const float* __restrict__ x, const unsigned short* __restrict__ wt,
    const float* __restrict__ bn1, const float* __restrict__ bn2,
    float* __restrict__ x_h, float* __restrict__ Ps, float* __restrict__ Pd)
{
    __shared__ unsigned short pXhi[EPB * LDK], pXlo[EPB * LDK];
    __shared__ unsigned short pHhi[EPB * LDK], pHlo[EPB * LDK];

    const int t = threadIdx.x;
    const int lane = t & 63, ft = t >> 6;
    const int quad = lane >> 4, l15 = lane & 15;
    const int f0 = ft * 16 + quad * 4;
    const int nodeBase = blockIdx.x * 64;
    const int nValid = min(64, NN - nodeBase);

    // stage x (8 cols) padded to 32
    {
        const int row = t >> 2, q = t & 3;
        if (q == 0) {
            float4 a0 = make_float4(0.f, 0.f, 0.f, 0.f), a1 = a0;
            if (row < nValid) {
                a0 = *(const float4*)(x + (size_t)(nodeBase + row) * 8);
                a1 = *(const float4*)(x + (size_t)(nodeBase + row) * 8 + 4);
            }
            union { unsigned short u[8]; uint4 v; } H, L;
            split2(a0.x, H.u[0], L.u[0]); split2(a0.y, H.u[1], L.u[1]);
            split2(a0.z, H.u[2], L.u[2]); split2(a0.w, H.u[3], L.u[3]);
            split2(a1.x, H.u[4], L.u[4]); split2(a1.y, H.u[5], L.u[5]);
            split2(a1.z, H.u[6], L.u[6]); split2(a1.w, H.u[7], L.u[7]);
            *(uint4*)(pXhi + row * LDK) = H.v;
            *(uint4*)(pXlo + row * LDK) = L.v;
        } else {
            const uint4 z = {0u, 0u, 0u, 0u};
            *(uint4*)(pXhi + row * LDK + q * 8) = z;
            *(uint4*)(pXlo + row * LDK + q * 8) = z;
        }
    }
    __syncthreads();

    f32x4 acc[4];

    // phase1: h1 = relu(x @ wn1 + bn1) -> pH
    {
        short8 wa[2];
        const int el = (ft * 16 + l15) * 32 + quad * 8;
        wa[0] = *(const short8*)(wt + OFF_WN1 + el);
        wa[1] = *(const short8*)(wt + OFF_WN1 + 2048 + el);
        set_bias(acc, bn1, f0);
#pragma unroll
        for (int et = 0; et < 4; ++et) {
            const int e = et * 16 + l15;
            const short8 bh0 = *(const short8*)(pXhi + e * LDK + quad * 8);
            const short8 bl0 = *(const short8*)(pXlo + e * LDK + quad * 8);
            f32x4 a = acc[et];
            a = MFMA(wa[0], bh0, a, 0, 0, 0);
            a = MFMA(wa[1], bh0, a, 0, 0, 0);
            a = MFMA(wa[0], bl0, a, 0, 0, 0);
            acc[et] = a;
        }
        relu4(acc);
        store_split_planes(pHhi, pHlo, acc, l15, f0);
    }
    __syncthreads();

    // phase2: x_h = h1 @ wn2 + bn2 -> global + pX
    {
        short8 w[2][2];
        load_wf(wt + S_WN2 * 8192, ft, l15, quad, w);
        set_bias(acc, bn2, f0);
        gemm_planes(pHhi, pHlo, w, l15, quad, acc);
#pragma unroll
        for (int et = 0; et < 4; ++et) {
            const int r = et * 16 + l15;
            if (r < nValid) {
                float4 v = make_float4(acc[et][0], acc[et][1], acc[et][2], acc[et][3]);
                *(float4*)(x_h + (size_t)(nodeBase + r) * HH + f0) = v;
            }
        }
        store_split_planes(pXhi, pXlo, acc, l15, f0);
    }
    __syncthreads();

    // phase3: Ps = x_h @ W1s(l0)
    {
        short8 w[2][2];
        load_wf(wt + S_W1S0 * 8192, ft, l15, quad, w);
        set_zero(acc);
        gemm_planes(pXhi, pXlo, w, l15, quad, acc);
#pragma unroll
        for (int et = 0; et < 4; ++et) {
            const int r = et * 16 + l15;
            if (r < nValid) {
                float4 v = make_float4(acc[et][0], acc[et][1], acc[et][2], acc[et][3]);
                *(float4*)(Ps + (size_t)(nodeBase + r) * HH + f0) = v;
            }
        }
    }
    // phase4: Pd = x_h @ W1d(l0)  (read-only on planes, no barrier needed)
    {
        short8 w[2][2];
        load_wf(wt + S_W1D0 * 8192, ft, l15, quad, w);
        set_zero(acc);
        gemm_planes(pXhi, pXlo, w, l15, quad, acc);
#pragma unroll
        for (int et = 0; et < 4; ++et) {
            const int r = et * 16 + l15;
            if (r < nValid) {
                float4 v = make_float4(acc[et][0], acc[et][1], acc[et][2], acc[et][3]);
                *(float4*)(Pd + (size_t)(nodeBase + r) * HH + f0) = v;
            }
        }
    }
}

// ---------------- K3: node update l0 + layer-1 projections (MFMA) ----------------
// agg aliases Ps: stage reads agg rows before first barrier; Ps written later.

__global__ __launch_bounds__(256, 4) void k_node_l0(
    float* x_h, const float* agg, const unsigned short* __restrict__ wt,
    const float* __restrict__ nb1, const float* __restrict__ nb2,
    float* Ps, float* __restrict__ Pd)
{
    __shared__ unsigned short pXhi[EPB * LDK], pXlo[EPB * LDK];
    __shared__ unsigned short pAhi[EPB * LDK], pAlo[EPB * LDK];

    const int t = threadIdx.x;
    const int lane = t & 63, ft = t >> 6;
    const int quad = lane >> 4, l15 = lane & 15;
    const int f0 = ft * 16 + quad * 4;
    const int nodeBase = blockIdx.x * 64;
    const int nValid = min(64, NN - nodeBase);

    stage_split64(pXhi, pXlo, x_h, nodeBase, t, nValid);
    stage_split64(pAhi, pAlo, agg, nodeBase, t, nValid);
    __syncthreads();

    f32x4 acc[4];

    // t1 = relu(x_h @ W1x + agg @ W1a + nb1)
    {
        short8 w[2][2];
        load_wf(wt + S_W1NX0 * 8192, ft, l15, quad, w);
        set_bias(acc, nb1, f0);
        gemm_planes(pXhi, pXlo, w, l15, quad, acc);
        load_wf(wt + S_W1NA0 * 8192, ft, l15, quad, w);
        gemm_planes(pAhi, pAlo, w, l15, quad, acc);
        relu4(acc);
    }
    __syncthreads();                       // pA reads complete
    store_split_planes(pAhi, pAlo, acc, l15, f0);   // t1 -> pA
    __syncthreads();

    // x_h1 = x_h + t1 @ W2n + nb2 -> global + pX
    {
        short8 w[2][2];
        load_wf(wt + S_W2N0 * 8192, ft, l15, quad, w);
        set_bias(acc, nb2, f0);
        gemm_planes(pAhi, pAlo, w, l15, quad, acc);
#pragma unroll
        for (int et = 0; et < 4; ++et) {
            const int r = et * 16 + l15;
            if (r < nValid) {
                const size_t gi = (size_t)(nodeBase + r) * HH + f0;
                const float4 xr = *(const float4*)(x_h + gi);
                acc[et][0] += xr.x; acc[et][1] += xr.y;
                acc[et][2] += xr.z; acc[et][3] += xr.w;
                float4 v = make_float4(acc[et][0], acc[et][1], acc[et][2], acc[et][3]);
                *(float4*)(x_h + gi) = v;
            }
        }
        store_split_planes(pXhi, pXlo, acc, l15, f0);
    }
    __syncthreads();

    // Ps1 = x_h1 @ W1s(l1)
    {
        short8 w[2][2];
        load_wf(wt + S_W1S1 * 8192, ft, l15, quad, w);
        set_zero(acc);
        gemm_planes(pXhi, pXlo, w, l15, quad, acc);
#pragma unroll
        for (int et = 0; et < 4; ++et) {
            const int r = et * 16 + l15;
            if (r < nValid) {
                float4 v = make_float4(acc[et][0], acc[et][1], acc[et][2], acc[et][3]);
                *(float4*)(Ps + (size_t)(nodeBase + r) * HH + f0) = v;
            }
        }
    }
    // Pd1 = x_h1 @ W1d(l1)
    {
        short8 w[2][2];
        load_wf(wt + S_W1D1 * 8192, ft, l15, quad, w);
        set_zero(acc);
        gemm_planes(pXhi, pXlo, w, l15, quad, acc);
#pragma unroll
        for (int et = 0; et < 4; ++et) {
            const int r = et * 16 + l15;
            if (r < nValid) {
                float4 v = make_float4(acc[et][0], acc[et][1], acc[et][2], acc[et][3]);
                *(float4*)(Pd + (size_t)(nodeBase + r) * HH + f0) = v;
            }
        }
    }
}

// ---------------- K5: node update l1 + decoder (MFMA) ----------------

__global__ __launch_bounds__(256, 4) void k_node_l1_dec(
    const float* x_h, const float* agg, const unsigned short* __restrict__ wt,
    const float* __restrict__ nb1, const float* __restrict__ nb2,
    const float* __restrict__ db1, const float* __restrict__ dw2,
    const float* __restrict__ db2, float* __restrict__ out)
{
    __shared__ unsigned short pXhi[EPB * LDK], pXlo[EPB * LDK];
    __shared__ unsigned short pAhi[EPB * LDK], pAlo[EPB * LDK];
    __shared__ float sW2[64 * 6];

    const int t = threadIdx.x;
    const int lane = t & 63, ft = t >> 6;
    const int quad = lane >> 4, l15 = lane & 15;
    const int f0 = ft * 16 + quad * 4;
    const int nodeBase = blockIdx.x * 64;
    const int nValid = min(64, NN - nodeBase);

    stage_split64(pXhi, pXlo, x_h, nodeBase, t, nValid);
    stage_split64(pAhi, pAlo, agg, nodeBase, t, nValid);
    if (t < 192) {
        sW2[t] = dw2[t];
        sW2[t + 192] = dw2[t + 192];
    }
    __syncthreads();

    f32x4 acc[4];

    // t1 = relu(x_h @ W1x + agg @ W1a + nb1)
    {
        short8 w[2][2];
        load_wf(wt + S_W1NX1 * 8192, ft, l15, quad, w);
        set_bias(acc, nb1, f0);
        gemm_planes(pXhi, pXlo, w, l15, quad, acc);
        load_wf(wt + S_W1NA1 * 8192, ft, l15, quad, w);
        gemm_planes(pAhi, pAlo, w, l15, quad, acc);
        relu4(acc);
    }
    __syncthreads();
    store_split_planes(pAhi, pAlo, acc, l15, f0);   // t1 -> pA
    __syncthreads();

    // x_h2 = x_h + t1 @ W2n + nb2 -> pX (no global writeback needed)
    {
        short8 w[2][2];
        load_wf(wt + S_W2N1 * 8192, ft, l15, quad, w);
        set_bias(acc, nb2, f0);
        gemm_planes(pAhi, pAlo, w, l15, quad, acc);
#pragma unroll
        for (int et = 0; et < 4; ++et) {
            const int r = et * 16 + l15;
            if (r < nValid) {
                const float4 xr = *(const float4*)(x_h + (size_t)(nodeBase + r) * HH + f0);
                acc[et][0] += xr.x; acc[et][1] += xr.y;
                acc[et][2] += xr.z; acc[et][3] += xr.w;
            }
        }
        store_split_planes(pXhi, pXlo, acc, l15, f0);
    }
    __syncthreads();

    // d1 = relu(x_h2 @ dec_w1 + db1) -> pA
    {
        short8 w[2][2];
        load_wf(wt + S_DW1 * 8192, ft, l15, quad, w);
        set_bias(acc, db1, f0);
        gemm_planes(pXhi, pXlo, w, l15, quad, acc);
        relu4(acc);
        store_split_planes(pAhi, pAlo, acc, l15, f0);
    }
    __syncthreads();

    // out = d1 @ dec_w2 + db2  (64 nodes x 6)
    if (t < 64 && t < nValid) {
        float o[6];
#pragma unroll
        for (int c = 0; c < 6; ++c) o[c] = db2[c];
#pragma unroll 8
        for (int k = 0; k < 64; ++k) {
            const float a = bf2f(pAhi[t * LDK + k]) + bf2f(pAlo[t * LDK + k]);
#pragma unroll
            for (int c = 0; c < 6; ++c) o[c] = fmaf(a, sW2[k * 6 + c], o[c]);
        }
        float* op = out + (size_t)(nodeBase + t) * 6;
#pragma unroll
        for (int c = 0; c < 6; ++c) op[c] = o[c];
    }
}

// ---------------- launcher ----------------

extern "C" void kernel_launch(void* const* d_in, const int* in_sizes, int n_in,
                              void* d_out, int out_size, void* d_ws, size_t ws_size,
                              hipStream_t stream) {
    const float* x        = (const float*)d_in[0];
    const float* eattr    = (const float*)d_in[1];
    const int*   eidx     = (const int*)d_in[2];
    const float* enc_n_w1 = (const float*)d_in[3];
    const float* enc_n_b1 = (const float*)d_in[4];
    const float* enc_n_w2 = (const float*)d_in[5];
    const float* enc_n_b2 = (const float*)d_in[6];
    const float* enc_e_w1 = (const float*)d_in[7];
    const float* enc_e_b1 = (const float*)d_in[8];
    const float* enc_e_w2 = (const float*)d_in[9];
    const float* enc_e_b2 = (const float*)d_in[10];
    const float* pe_w1    = (const float*)d_in[11];  // [2,192,64]
    const float* pe_b1    = (const float*)d_in[12];  // [2,64]
    const float* pe_w2    = (const float*)d_in[13];  // [2,64,64]
    const float* pe_b2    = (const float*)d_in[14];  // [2,64]
    const float* pn_w1    = (const float*)d_in[15];  // [2,128,64]
    const float* pn_b1    = (const float*)d_in[16];
    const float* pn_w2    = (const float*)d_in[17];  // [2,64,64]
    const float* pn_b2    = (const float*)d_in[18];
    const float* dw1      = (const float*)d_in[19];
    const float* db1      = (const float*)d_in[20];
    const float* dw2      = (const float*)d_in[21];
    const float* db2      = (const float*)d_in[22];
    float* out = (float*)d_out;

    // ws: x_h | Ps(=agg) | Pd | epk | off | deg | csr | srcs_s | dsts_s | wt
    // 38.4 + 204.8 + 0.4 + 9.6 + 0.3 = 253.5 MB
    const size_t NNHH = (size_t)NN * HH;
    float* ws  = (float*)d_ws;
    float* x_h = ws;
    float* Ps  = ws + NNHH;
    float* agg = Ps;                       // aliased
    float* Pd  = ws + 2 * NNHH;
    unsigned* epk = (unsigned*)(ws + 3 * NNHH);           // EE*HH uints
    unsigned* off = epk + (size_t)EE * HH;                // NN+1
    unsigned* deg = off + (NN + 1);                       // NN, reused as cursor
    int* csr    = (int*)(deg + NN);                       // EE
    int* srcs_s = csr + EE;                               // EE
    int* dsts_s = srcs_s + EE;                            // EE
    unsigned short* wt = (unsigned short*)(dsts_s + EE);  // WT_USHORTS

    const int nodeBlocks = (NN + 63) / 64;   // 782
    const int edgeBlocks = EE / EPB;         // 12500
    const int eScal      = (EE + 255) / 256; // 3125

    hipMemsetAsync(deg, 0, (size_t)NN * sizeof(unsigned), stream);

    k_conv_w<<<288, 256, 0, stream>>>(
        enc_n_w1, enc_n_w2, enc_e_w1, enc_e_w2,
        pe_w1, pe_w2, pn_w1, pn_w2, dw1, wt);

    k_deg<<<eScal, 256, 0, stream>>>(eidx, deg);
    k_scan<<<1, 1024, 0, stream>>>(deg, off);
    k_fill<<<eScal, 256, 0, stream>>>(eidx, deg, csr, srcs_s, dsts_s);

    k_encode_nodes<<<nodeBlocks, 256, 0, stream>>>(
        x, wt, enc_n_b1, enc_n_b2, x_h, Ps, Pd);

    k_edge_l0<<<edgeBlocks, 256, 0, stream>>>(
        eattr, csr, srcs_s, dsts_s, Ps, Pd,
        enc_e_b1, enc_e_b2, wt, pe_b1, pe_b2, epk);

    k_agg<<<(NN + 3) / 4, 256, 0, stream>>>(off, epk, agg);

    k_node_l0<<<nodeBlocks, 256, 0, stream>>>(
        x_h, agg, wt, pn_b1, pn_b2, Ps, Pd);

    k_edge_l1<<<edgeBlocks, 256, 0, stream>>>(
        srcs_s, dsts_s, Ps, Pd, wt, pe_b1 + 64, pe_b2 + 64, epk);

    k_agg<<<(NN + 3) / 4, 256, 0, stream>>>(off, epk, agg);

    k_node_l1_dec<<<nodeBlocks, 256, 0, stream>>>(
        x_h, agg, wt, pn_b1 + 64, pn_b2 + 64,
        db1, dw2, db2, out);
}